// Round 1
// baseline (1297.345 us; speedup 1.0000x reference)
//
#include <hip/hip_runtime.h>
#include <math.h>

#define B_SZ 2
#define T_LEN 1024
#define D_MODEL 1024
#define D_STATE 16
#define D_INNER 2048
#define DT_RANK 64
#define NTOK (B_SZ * T_LEN)             // 2048 tokens
#define XPROJ_OUT (DT_RANK + 2 * D_STATE) // 96

__device__ __forceinline__ float sigmoidf_(float x) { return 1.f / (1.f + __expf(-x)); }

// ---------------- RMSNorm: 2048 rows x 1024 ----------------
__global__ __launch_bounds__(256) void k_rmsnorm(const float* __restrict__ x,
                                                 const float* __restrict__ w,
                                                 float* __restrict__ xn) {
    int row = blockIdx.x;
    const float* xr = x + (size_t)row * D_MODEL;
    int i = threadIdx.x * 4;
    float4 xv = *(const float4*)(xr + i);
    float s = xv.x * xv.x + xv.y * xv.y + xv.z * xv.z + xv.w * xv.w;
#pragma unroll
    for (int m = 1; m <= 32; m <<= 1) s += __shfl_xor(s, m);
    __shared__ float red[4];
    if ((threadIdx.x & 63) == 0) red[threadIdx.x >> 6] = s;
    __syncthreads();
    float tot = red[0] + red[1] + red[2] + red[3];
    float scale = rsqrtf(tot * (1.f / D_MODEL) + 1.1920929e-07f);
    float4 wv = *(const float4*)(w + i);
    float4 o;
    o.x = xv.x * scale * wv.x;
    o.y = xv.y * scale * wv.y;
    o.z = xv.z * scale * wv.z;
    o.w = xv.w * scale * wv.w;
    *(float4*)(xn + (size_t)row * D_MODEL + i) = o;
}

// ---------------- Generic tiled f32 GEMM: C = A(MxK) * B(NxK)^T ----------------
// EPI: 0 = none, 1 = softplus(v + bias[n]), 2 = v + res[m*ldc+n]
// All M,N,K are multiples of the tile sizes for every call site (no guards).
template <int EPI>
__global__ __launch_bounds__(256) void gemm_nt(const float* __restrict__ A, int lda,
                                               const float* __restrict__ B, int ldb,
                                               float* __restrict__ C, int ldc,
                                               int K,
                                               const float* __restrict__ bias,
                                               const float* __restrict__ res) {
    constexpr int BM = 64, BN = 64, BK = 16, TM = 4, TN = 4;
    __shared__ float As[BK][BM];  // no pad: 2-way bank aliasing is free; keeps 16B alignment
    __shared__ float Bs[BK][BN];
    int tid = threadIdx.x;
    int tx = tid & 15, ty = tid >> 4;
    int m0 = blockIdx.x * BM, n0 = blockIdx.y * BN;
    float acc[TM][TN] = {};
    for (int k0 = 0; k0 < K; k0 += BK) {
#pragma unroll
        for (int i = 0; i < 4; ++i) {
            int idx = tid + i * 256;
            int m = idx >> 4;  // /BK
            int k = idx & 15;
            As[k][m] = A[(size_t)(m0 + m) * lda + k0 + k];
        }
#pragma unroll
        for (int i = 0; i < 4; ++i) {
            int idx = tid + i * 256;
            int n = idx >> 4;
            int k = idx & 15;
            Bs[k][n] = B[(size_t)(n0 + n) * ldb + k0 + k];
        }
        __syncthreads();
#pragma unroll
        for (int k = 0; k < BK; ++k) {
            float4 av = *(const float4*)&As[k][ty * TM];
            float4 bv = *(const float4*)&Bs[k][tx * TN];
            float a[TM] = {av.x, av.y, av.z, av.w};
            float b[TN] = {bv.x, bv.y, bv.z, bv.w};
#pragma unroll
            for (int i = 0; i < TM; ++i)
#pragma unroll
                for (int j = 0; j < TN; ++j) acc[i][j] = fmaf(a[i], b[j], acc[i][j]);
        }
        __syncthreads();
    }
#pragma unroll
    for (int i = 0; i < TM; ++i) {
        int m = m0 + ty * TM + i;
#pragma unroll
        for (int j = 0; j < TN; ++j) {
            int n = n0 + tx * TN + j;
            float v = acc[i][j];
            if (EPI == 1) {
                v = v + bias[n];
                v = (v > 20.f) ? v : log1pf(__expf(v));
            } else if (EPI == 2) {
                v += res[(size_t)m * ldc + n];
            }
            C[(size_t)m * ldc + n] = v;
        }
    }
}

// ---------------- depthwise causal conv (k=4) + SiLU ----------------
// x_s = xz[..., 0:2048]; u layout (b*T+t)*2048 + c
__global__ __launch_bounds__(256) void k_conv(const float* __restrict__ xz,
                                              const float* __restrict__ cw,
                                              const float* __restrict__ cb,
                                              float* __restrict__ u) {
    int idx = blockIdx.x * 256 + threadIdx.x;  // b*T*D_INNER total
    int c = idx & (D_INNER - 1);
    int t = (idx >> 11) & (T_LEN - 1);
    int b = idx >> 21;
    const float* xs = xz + (size_t)b * T_LEN * 2 * D_INNER + c;
    float4 wv = *(const float4*)(cw + c * 4);
    float s = cb[c];
    if (t >= 3) s = fmaf(xs[(size_t)(t - 3) * 2 * D_INNER], wv.x, s);
    if (t >= 2) s = fmaf(xs[(size_t)(t - 2) * 2 * D_INNER], wv.y, s);
    if (t >= 1) s = fmaf(xs[(size_t)(t - 1) * 2 * D_INNER], wv.z, s);
    s = fmaf(xs[(size_t)t * 2 * D_INNER], wv.w, s);
    u[idx] = s * sigmoidf_(s);
}

// ---------------- x_proj: dbc(2048x96) += u(2048x2048) @ x_proj_w(96x2048)^T, split-K ----------------
__global__ __launch_bounds__(128) void k_xproj(const float* __restrict__ u,
                                               const float* __restrict__ w,
                                               float* __restrict__ dbc) {
    __shared__ __align__(16) float su[512];
    int token = blockIdx.x;
    int kc = blockIdx.y;  // 0..3, chunks of 512
    const float* urow = u + (size_t)token * D_INNER + kc * 512;
    if (threadIdx.x < 128) ((float4*)su)[threadIdx.x] = ((const float4*)urow)[threadIdx.x];
    __syncthreads();
    int j = threadIdx.x;
    if (j < XPROJ_OUT) {
        const float* wr = w + (size_t)j * D_INNER + kc * 512;
        float s = 0.f;
#pragma unroll 4
        for (int k = 0; k < 512; k += 4) {
            float4 wv = *(const float4*)(wr + k);
            s = fmaf(su[k], wv.x, s);
            s = fmaf(su[k + 1], wv.y, s);
            s = fmaf(su[k + 2], wv.z, s);
            s = fmaf(su[k + 3], wv.w, s);
        }
        atomicAdd(&dbc[(size_t)token * XPROJ_OUT + j], s);
    }
}

// ---------------- selective scan ----------------
// lane = ci*16 + s; wave handles 4 channels. y written in-place over u.
__global__ __launch_bounds__(256) void k_scan(const float* __restrict__ delta,
                                              float* uy,  // u in, y out (in-place) — no restrict
                                              const float* __restrict__ dbc,
                                              const float* __restrict__ xz,
                                              const float* __restrict__ A_log,
                                              const float* __restrict__ Dp) {
    int lane = threadIdx.x & 63;
    int s = lane & 15, ci = lane >> 4;
    int wave = blockIdx.x * 4 + (threadIdx.x >> 6);
    int bc = wave * 4 + ci;  // 0..4095
    int b = bc >> 11, c = bc & (D_INNER - 1);
    float A = -__expf(A_log[c * D_STATE + s]);
    float Dc = Dp[c];
    const float* dptr = delta + (size_t)b * T_LEN * D_INNER + c;
    float* uptr = uy + (size_t)b * T_LEN * D_INNER + c;
    const float* bptr = dbc + (size_t)b * T_LEN * XPROJ_OUT + DT_RANK + s;
    const float* cptr = bptr + D_STATE;
    const float* zptr = xz + (size_t)b * T_LEN * 2 * D_INNER + D_INNER + c;
    float h = 0.f;
    float dv = dptr[0], uv = uptr[0], Bv = bptr[0], Cv = cptr[0], zv = zptr[0];
    for (int t = 0; t < T_LEN; ++t) {
        float dn = 0.f, un = 0.f, Bn = 0.f, Cn = 0.f, zn = 0.f;
        if (t + 1 < T_LEN) {  // distance-1 prefetch of next timestep
            int o = t + 1;
            dn = dptr[(size_t)o * D_INNER];
            un = uptr[(size_t)o * D_INNER];
            Bn = bptr[(size_t)o * XPROJ_OUT];
            Cn = cptr[(size_t)o * XPROJ_OUT];
            zn = zptr[(size_t)o * 2 * D_INNER];
        }
        float da = __expf(dv * A);
        h = fmaf(da, h, dv * uv * Bv);
        float p = h * Cv;
        p += __shfl_xor(p, 1);
        p += __shfl_xor(p, 2);
        p += __shfl_xor(p, 4);
        p += __shfl_xor(p, 8);
        if (s == 0) {
            float sz = zv * sigmoidf_(zv);
            uptr[(size_t)t * D_INNER] = (p + Dc * uv) * sz;
        }
        dv = dn; uv = un; Bv = Bn; Cv = Cn; zv = zn;
    }
}

extern "C" void kernel_launch(void* const* d_in, const int* in_sizes, int n_in,
                              void* d_out, int out_size, void* d_ws, size_t ws_size,
                              hipStream_t stream) {
    const float* x         = (const float*)d_in[0];
    const float* norm_w    = (const float*)d_in[1];
    const float* in_proj_w = (const float*)d_in[2];
    const float* conv_w    = (const float*)d_in[3];
    const float* conv_b    = (const float*)d_in[4];
    const float* x_proj_w  = (const float*)d_in[5];
    const float* dt_proj_w = (const float*)d_in[6];
    const float* dt_proj_b = (const float*)d_in[7];
    const float* A_log     = (const float*)d_in[8];
    const float* D_param   = (const float*)d_in[9];
    const float* out_proj_w= (const float*)d_in[10];
    float* out = (float*)d_out;

    // workspace layout (floats): total 19,070,976 floats = 76.3 MB
    float* ws    = (float*)d_ws;
    float* xn    = ws;              // 2048*1024
    float* xz    = ws + 2097152;    // 2048*4096
    float* u     = ws + 10485760;   // 2048*2048 (y overwrites in-place)
    float* dbc   = ws + 14680064;   // 2048*96
    float* delta = ws + 14876672;   // 2048*2048

    hipMemsetAsync(dbc, 0, (size_t)NTOK * XPROJ_OUT * sizeof(float), stream);

    // 1. RMSNorm
    k_rmsnorm<<<NTOK, 256, 0, stream>>>(x, norm_w, xn);
    // 2. xz = xn @ in_proj_w^T   (2048 x 4096 x 1024)
    gemm_nt<0><<<dim3(NTOK / 64, (2 * D_INNER) / 64), 256, 0, stream>>>(
        xn, D_MODEL, in_proj_w, D_MODEL, xz, 2 * D_INNER, D_MODEL, nullptr, nullptr);
    // 3. depthwise conv + SiLU -> u
    k_conv<<<(NTOK * D_INNER) / 256, 256, 0, stream>>>(xz, conv_w, conv_b, u);
    // 4. x_dbc = u @ x_proj_w^T  (2048 x 96 x 2048), split-K atomic
    k_xproj<<<dim3(NTOK, 4), 128, 0, stream>>>(u, x_proj_w, dbc);
    // 5. delta = softplus(dt_raw @ dt_proj_w^T + dt_proj_b)  (2048 x 2048 x 64)
    gemm_nt<1><<<dim3(NTOK / 64, D_INNER / 64), 256, 0, stream>>>(
        dbc, XPROJ_OUT, dt_proj_w, DT_RANK, delta, D_INNER, DT_RANK, dt_proj_b, nullptr);
    // 6. selective scan + D*u + silu(z) gate -> y (in-place over u)
    k_scan<<<256, 256, 0, stream>>>(delta, u, dbc, xz, A_log, D_param);
    // 7. out = y @ out_proj_w^T + x   (2048 x 1024 x 2048)
    gemm_nt<2><<<dim3(NTOK / 64, D_MODEL / 64), 256, 0, stream>>>(
        u, D_INNER, out_proj_w, D_INNER, out, D_MODEL, D_INNER, nullptr, x);

    (void)in_sizes; (void)n_in; (void)out_size; (void)ws_size;
}

// Round 2
// 764.890 us; speedup vs baseline: 1.6961x; 1.6961x over previous
//
#include <hip/hip_runtime.h>
#include <math.h>

#define B_SZ 2
#define T_LEN 1024
#define D_MODEL 1024
#define D_STATE 16
#define D_INNER 2048
#define DT_RANK 64
#define NTOK (B_SZ * T_LEN)               // 2048 tokens
#define XPROJ_OUT (DT_RANK + 2 * D_STATE) // 96

typedef __attribute__((ext_vector_type(8))) short bf16x8;
typedef __attribute__((ext_vector_type(4))) float f32x4;
typedef unsigned short ushort_t;

__device__ __forceinline__ float sigmoidf_(float x) { return 1.f / (1.f + __expf(-x)); }

__device__ __forceinline__ unsigned f2bf_u(float f) {  // RNE f32->bf16 bits
    unsigned u = __float_as_uint(f);
    return (u + 0x7FFFu + ((u >> 16) & 1u)) >> 16;
}

__device__ __forceinline__ void gload_lds16(const void* g, void* l) {
    __builtin_amdgcn_global_load_lds((const __attribute__((address_space(1))) unsigned*)g,
                                     (__attribute__((address_space(3))) unsigned*)l,
                                     16, 0, 0);
}

// ---------------- f32 -> bf16 cast (n multiple of 8) ----------------
__global__ __launch_bounds__(256) void k_cast(const float* __restrict__ in,
                                              unsigned* __restrict__ out) {
    int idx = blockIdx.x * 256 + threadIdx.x;
    float4 a = ((const float4*)in)[idx * 2];
    float4 b = ((const float4*)in)[idx * 2 + 1];
    uint4 o;
    o.x = f2bf_u(a.x) | (f2bf_u(a.y) << 16);
    o.y = f2bf_u(a.z) | (f2bf_u(a.w) << 16);
    o.z = f2bf_u(b.x) | (f2bf_u(b.y) << 16);
    o.w = f2bf_u(b.z) | (f2bf_u(b.w) << 16);
    ((uint4*)out)[idx] = o;
}

// ---------------- RMSNorm: 2048 rows x 1024, bf16 output ----------------
__global__ __launch_bounds__(256) void k_rmsnorm(const float* __restrict__ x,
                                                 const float* __restrict__ w,
                                                 unsigned short* __restrict__ xn) {
    int row = blockIdx.x;
    const float* xr = x + (size_t)row * D_MODEL;
    int i = threadIdx.x * 4;
    float4 xv = *(const float4*)(xr + i);
    float s = xv.x * xv.x + xv.y * xv.y + xv.z * xv.z + xv.w * xv.w;
#pragma unroll
    for (int m = 1; m <= 32; m <<= 1) s += __shfl_xor(s, m);
    __shared__ float red[4];
    if ((threadIdx.x & 63) == 0) red[threadIdx.x >> 6] = s;
    __syncthreads();
    float tot = red[0] + red[1] + red[2] + red[3];
    float scale = rsqrtf(tot * (1.f / D_MODEL) + 1.1920929e-07f);
    float4 wv = *(const float4*)(w + i);
    uint2 o;
    o.x = f2bf_u(xv.x * scale * wv.x) | (f2bf_u(xv.y * scale * wv.y) << 16);
    o.y = f2bf_u(xv.z * scale * wv.z) | (f2bf_u(xv.w * scale * wv.w) << 16);
    *(uint2*)(xn + (size_t)row * D_MODEL + i) = o;
}

// ---------------- bf16 MFMA GEMM: C(MxN,f32) = A(MxK) * B(NxK)^T ----------------
// BM=128 fixed. BN/CW templated. 256 threads = 4 waves, RW=4/CW x CW wave grid.
// EPI: 0 = none, 2 = + res[m*ldc+n]
template <int BN, int CW, int EPI>
__global__ __launch_bounds__(256) void gemm_bf16(const unsigned short* __restrict__ A,
                                                 const unsigned short* __restrict__ B,
                                                 float* __restrict__ C, int ldc, int K,
                                                 const float* __restrict__ res) {
    constexpr int RW = 4 / CW;
    constexpr int MI = (128 / RW) / 16;  // mfma tiles per wave in M
    constexpr int NJ = (BN / CW) / 16;   // mfma tiles per wave in N
    __shared__ __align__(16) unsigned short As[128 * 32];
    __shared__ __align__(16) unsigned short Bs[BN * 32];
    int tid = threadIdx.x;
    int lane = tid & 63, wv = tid >> 6;
    int wr = wv / CW, wc = wv % CW;
    int lm = lane & 15, q = lane >> 4;
    int m0 = blockIdx.x * 128, n0 = blockIdx.y * BN;
    f32x4 acc[MI][NJ] = {};
    for (int k0 = 0; k0 < K; k0 += 32) {
        // stage A tile: 128 rows x 32 cols bf16 = 512 x 16B chunks
#pragma unroll
        for (int it = 0; it < 2; ++it) {
            int chunk = it * 256 + tid;
            const unsigned short* g = A + (size_t)(m0 + (chunk >> 2)) * K + k0 + (chunk & 3) * 8;
            char* l = (char*)As + (it * 256 + wv * 64) * 16 + lane * 16;
            gload_lds16(g, l);
        }
        // stage B tile: BN rows x 32 cols = BN*4 chunks
#pragma unroll
        for (int it = 0; it < BN / 64; ++it) {
            int chunk = it * 256 + tid;
            const unsigned short* g = B + (size_t)(n0 + (chunk >> 2)) * K + k0 + (chunk & 3) * 8;
            char* l = (char*)Bs + (it * 256 + wv * 64) * 16 + lane * 16;
            gload_lds16(g, l);
        }
        __syncthreads();  // compiler inserts s_waitcnt vmcnt(0) before barrier
        bf16x8 af[MI], bfr[NJ];
#pragma unroll
        for (int i = 0; i < MI; ++i)
            af[i] = *(const bf16x8*)(As + (wr * MI * 16 + i * 16 + lm) * 32 + q * 8);
#pragma unroll
        for (int j = 0; j < NJ; ++j)
            bfr[j] = *(const bf16x8*)(Bs + (wc * NJ * 16 + j * 16 + lm) * 32 + q * 8);
#pragma unroll
        for (int i = 0; i < MI; ++i)
#pragma unroll
            for (int j = 0; j < NJ; ++j)
                acc[i][j] = __builtin_amdgcn_mfma_f32_16x16x32_bf16(af[i], bfr[j], acc[i][j], 0, 0, 0);
        __syncthreads();
    }
    // epilogue: C/D layout col=lane&15, row=q*4+r  [verified m89/m91]
#pragma unroll
    for (int i = 0; i < MI; ++i) {
#pragma unroll
        for (int j = 0; j < NJ; ++j) {
#pragma unroll
            for (int r = 0; r < 4; ++r) {
                int row = m0 + wr * MI * 16 + i * 16 + q * 4 + r;
                int col = n0 + wc * NJ * 16 + j * 16 + lm;
                float v = acc[i][j][r];
                if (EPI == 2) v += res[(size_t)row * ldc + col];
                C[(size_t)row * ldc + col] = v;
            }
        }
    }
}

// ---------------- f32 tiled GEMM (kept for dt_proj): C = A(MxK)*B(NxK)^T ----------------
// EPI1: softplus(v + bias[n])
__global__ __launch_bounds__(256) void gemm_nt_sp(const float* __restrict__ A, int lda,
                                                  const float* __restrict__ B, int ldb,
                                                  float* __restrict__ C, int ldc, int K,
                                                  const float* __restrict__ bias) {
    constexpr int BM = 64, BN = 64, BK = 16, TM = 4, TN = 4;
    __shared__ float As[BK][BM];
    __shared__ float Bs[BK][BN];
    int tid = threadIdx.x;
    int tx = tid & 15, ty = tid >> 4;
    int m0 = blockIdx.x * BM, n0 = blockIdx.y * BN;
    float acc[TM][TN] = {};
    for (int k0 = 0; k0 < K; k0 += BK) {
#pragma unroll
        for (int i = 0; i < 4; ++i) {
            int idx = tid + i * 256;
            As[idx & 15][idx >> 4] = A[(size_t)(m0 + (idx >> 4)) * lda + k0 + (idx & 15)];
        }
#pragma unroll
        for (int i = 0; i < 4; ++i) {
            int idx = tid + i * 256;
            Bs[idx & 15][idx >> 4] = B[(size_t)(n0 + (idx >> 4)) * ldb + k0 + (idx & 15)];
        }
        __syncthreads();
#pragma unroll
        for (int k = 0; k < BK; ++k) {
            float4 av = *(const float4*)&As[k][ty * TM];
            float4 bv = *(const float4*)&Bs[k][tx * TN];
            float a[TM] = {av.x, av.y, av.z, av.w};
            float b[TN] = {bv.x, bv.y, bv.z, bv.w};
#pragma unroll
            for (int i = 0; i < TM; ++i)
#pragma unroll
                for (int j = 0; j < TN; ++j) acc[i][j] = fmaf(a[i], b[j], acc[i][j]);
        }
        __syncthreads();
    }
#pragma unroll
    for (int i = 0; i < TM; ++i) {
        int m = m0 + ty * TM + i;
#pragma unroll
        for (int j = 0; j < TN; ++j) {
            int n = n0 + tx * TN + j;
            float v = acc[i][j] + bias[n];
            v = (v > 20.f) ? v : log1pf(__expf(v));
            C[(size_t)m * ldc + n] = v;
        }
    }
}

// ---------------- depthwise causal conv (k=4) + SiLU ----------------
__global__ __launch_bounds__(256) void k_conv(const float* __restrict__ xz,
                                              const float* __restrict__ cw,
                                              const float* __restrict__ cb,
                                              float* __restrict__ u) {
    int idx = blockIdx.x * 256 + threadIdx.x;
    int c = idx & (D_INNER - 1);
    int t = (idx >> 11) & (T_LEN - 1);
    int b = idx >> 21;
    const float* xs = xz + (size_t)b * T_LEN * 2 * D_INNER + c;
    float4 wv = *(const float4*)(cw + c * 4);
    float s = cb[c];
    if (t >= 3) s = fmaf(xs[(size_t)(t - 3) * 2 * D_INNER], wv.x, s);
    if (t >= 2) s = fmaf(xs[(size_t)(t - 2) * 2 * D_INNER], wv.y, s);
    if (t >= 1) s = fmaf(xs[(size_t)(t - 1) * 2 * D_INNER], wv.z, s);
    s = fmaf(xs[(size_t)t * 2 * D_INNER], wv.w, s);
    u[idx] = s * sigmoidf_(s);
}

// ---------------- x_proj: dbc(2048x96) += u(2048x2048) @ x_proj_w(96x2048)^T ----------------
__global__ __launch_bounds__(128) void k_xproj(const float* __restrict__ u,
                                               const float* __restrict__ w,
                                               float* __restrict__ dbc) {
    __shared__ __align__(16) float su[512];
    int token = blockIdx.x;
    int kc = blockIdx.y;
    const float* urow = u + (size_t)token * D_INNER + kc * 512;
    if (threadIdx.x < 128) ((float4*)su)[threadIdx.x] = ((const float4*)urow)[threadIdx.x];
    __syncthreads();
    int j = threadIdx.x;
    if (j < XPROJ_OUT) {
        const float* wr = w + (size_t)j * D_INNER + kc * 512;
        float s = 0.f;
#pragma unroll 4
        for (int k = 0; k < 512; k += 4) {
            float4 wv = *(const float4*)(wr + k);
            s = fmaf(su[k], wv.x, s);
            s = fmaf(su[k + 1], wv.y, s);
            s = fmaf(su[k + 2], wv.z, s);
            s = fmaf(su[k + 3], wv.w, s);
        }
        atomicAdd(&dbc[(size_t)token * XPROJ_OUT + j], s);
    }
}

// ---------------- selective scan: y (bf16) = gated SSM output ----------------
__global__ __launch_bounds__(256) void k_scan(const float* __restrict__ delta,
                                              const float* __restrict__ u,
                                              const float* __restrict__ dbc,
                                              const float* __restrict__ xz,
                                              const float* __restrict__ A_log,
                                              const float* __restrict__ Dp,
                                              unsigned short* __restrict__ yb) {
    int lane = threadIdx.x & 63;
    int s = lane & 15, ci = lane >> 4;
    int wave = blockIdx.x * 4 + (threadIdx.x >> 6);
    int bc = wave * 4 + ci;
    int b = bc >> 11, c = bc & (D_INNER - 1);
    float A = -__expf(A_log[c * D_STATE + s]);
    float Dc = Dp[c];
    const float* dptr = delta + (size_t)b * T_LEN * D_INNER + c;
    const float* uptr = u + (size_t)b * T_LEN * D_INNER + c;
    const float* bptr = dbc + (size_t)b * T_LEN * XPROJ_OUT + DT_RANK + s;
    const float* cptr = bptr + D_STATE;
    const float* zptr = xz + (size_t)b * T_LEN * 2 * D_INNER + D_INNER + c;
    unsigned short* yptr = yb + (size_t)b * T_LEN * D_INNER + c;
    float h = 0.f;
    float dv = dptr[0], uv = uptr[0], Bv = bptr[0], Cv = cptr[0], zv = zptr[0];
    for (int t = 0; t < T_LEN; ++t) {
        float dn = 0.f, un = 0.f, Bn = 0.f, Cn = 0.f, zn = 0.f;
        if (t + 1 < T_LEN) {
            int o = t + 1;
            dn = dptr[(size_t)o * D_INNER];
            un = uptr[(size_t)o * D_INNER];
            Bn = bptr[(size_t)o * XPROJ_OUT];
            Cn = cptr[(size_t)o * XPROJ_OUT];
            zn = zptr[(size_t)o * 2 * D_INNER];
        }
        float da = __expf(dv * A);
        h = fmaf(da, h, dv * uv * Bv);
        float p = h * Cv;
        p += __shfl_xor(p, 1);
        p += __shfl_xor(p, 2);
        p += __shfl_xor(p, 4);
        p += __shfl_xor(p, 8);
        if (s == 0) {
            float sz = zv * sigmoidf_(zv);
            yptr[(size_t)t * D_INNER] = (unsigned short)f2bf_u((p + Dc * uv) * sz);
        }
        dv = dn; uv = un; Bv = Bn; Cv = Cn; zv = zn;
    }
}

extern "C" void kernel_launch(void* const* d_in, const int* in_sizes, int n_in,
                              void* d_out, int out_size, void* d_ws, size_t ws_size,
                              hipStream_t stream) {
    const float* x         = (const float*)d_in[0];
    const float* norm_w    = (const float*)d_in[1];
    const float* in_proj_w = (const float*)d_in[2];
    const float* conv_w    = (const float*)d_in[3];
    const float* conv_b    = (const float*)d_in[4];
    const float* x_proj_w  = (const float*)d_in[5];
    const float* dt_proj_w = (const float*)d_in[6];
    const float* dt_proj_b = (const float*)d_in[7];
    const float* A_log     = (const float*)d_in[8];
    const float* D_param   = (const float*)d_in[9];
    const float* out_proj_w= (const float*)d_in[10];
    float* out = (float*)d_out;

    // workspace layout (float units)
    float* ws = (float*)d_ws;
    float*          xz    = ws;                   // 2048*4096 f32
    float*          u     = ws + 8388608;         // 2048*2048 f32
    float*          delta = ws + 12582912;        // 2048*2048 f32
    float*          dbc   = ws + 16777216;        // 2048*96 f32
    unsigned short* xnb   = (unsigned short*)(ws + 16973824); // 2048*1024 bf16
    unsigned short* wib   = (unsigned short*)(ws + 18022400); // 4096*1024 bf16
    unsigned short* wob   = (unsigned short*)(ws + 20119552); // 1024*2048 bf16
    unsigned short* yb    = (unsigned short*)(ws + 21168128); // 2048*2048 bf16
    // total: 23,265,280 floats = 93.1 MB

    hipMemsetAsync(dbc, 0, (size_t)NTOK * XPROJ_OUT * sizeof(float), stream);

    // 0. weight casts f32 -> bf16
    k_cast<<<(4096 * 1024) / 2048, 256, 0, stream>>>(in_proj_w, (unsigned*)wib);
    k_cast<<<(1024 * 2048) / 2048, 256, 0, stream>>>(out_proj_w, (unsigned*)wob);
    // 1. RMSNorm -> bf16
    k_rmsnorm<<<NTOK, 256, 0, stream>>>(x, norm_w, xnb);
    // 2. xz = xn @ in_proj_w^T  (2048 x 4096 x 1024), MFMA bf16
    gemm_bf16<128, 2, 0><<<dim3(NTOK / 128, 4096 / 128), 256, 0, stream>>>(
        xnb, wib, xz, 2 * D_INNER, D_MODEL, nullptr);
    // 3. depthwise conv + SiLU -> u
    k_conv<<<(NTOK * D_INNER) / 256, 256, 0, stream>>>(xz, conv_w, conv_b, u);
    // 4. x_dbc = u @ x_proj_w^T  (2048 x 96 x 2048)
    k_xproj<<<dim3(NTOK, 4), 128, 0, stream>>>(u, x_proj_w, dbc);
    // 5. delta = softplus(dt_raw @ dt_proj_w^T + b)  (2048 x 2048 x 64), f32
    gemm_nt_sp<<<dim3(NTOK / 64, D_INNER / 64), 256, 0, stream>>>(
        dbc, XPROJ_OUT, dt_proj_w, DT_RANK, delta, D_INNER, DT_RANK, dt_proj_b);
    // 6. selective scan -> yb (bf16)
    k_scan<<<256, 256, 0, stream>>>(delta, u, dbc, xz, A_log, D_param, yb);
    // 7. out = y @ out_proj_w^T + x  (2048 x 1024 x 2048), MFMA bf16, 128x64 tile
    gemm_bf16<64, 1, 2><<<dim3(NTOK / 128, 1024 / 64), 256, 0, stream>>>(
        yb, wob, out, D_MODEL, D_INNER, x);

    (void)in_sizes; (void)n_in; (void)out_size; (void)ws_size;
}

// Round 3
// 520.934 us; speedup vs baseline: 2.4904x; 1.4683x over previous
//
#include <hip/hip_runtime.h>
#include <math.h>

#define B_SZ 2
#define T_LEN 1024
#define D_MODEL 1024
#define D_STATE 16
#define D_INNER 2048
#define DT_RANK 64
#define NTOK (B_SZ * T_LEN)               // 2048 tokens
#define XPROJ_OUT (DT_RANK + 2 * D_STATE) // 96
#define NCHUNK 8
#define CHUNK_L (T_LEN / NCHUNK)          // 128

typedef __attribute__((ext_vector_type(8))) short bf16x8;
typedef __attribute__((ext_vector_type(4))) float f32x4;

__device__ __forceinline__ float sigmoidf_(float x) { return 1.f / (1.f + __expf(-x)); }

__device__ __forceinline__ unsigned f2bf_u(float f) {  // RNE f32->bf16 bits
    unsigned u = __float_as_uint(f);
    return (u + 0x7FFFu + ((u >> 16) & 1u)) >> 16;
}

__device__ __forceinline__ void gload_lds16(const void* g, void* l) {
    __builtin_amdgcn_global_load_lds((const __attribute__((address_space(1))) unsigned*)g,
                                     (__attribute__((address_space(3))) unsigned*)l,
                                     16, 0, 0);
}

// ---------------- f32 -> bf16 cast ----------------
__global__ __launch_bounds__(256) void k_cast(const float* __restrict__ in,
                                              unsigned* __restrict__ out) {
    int idx = blockIdx.x * 256 + threadIdx.x;
    float4 a = ((const float4*)in)[idx * 2];
    float4 b = ((const float4*)in)[idx * 2 + 1];
    uint4 o;
    o.x = f2bf_u(a.x) | (f2bf_u(a.y) << 16);
    o.y = f2bf_u(a.z) | (f2bf_u(a.w) << 16);
    o.z = f2bf_u(b.x) | (f2bf_u(b.y) << 16);
    o.w = f2bf_u(b.z) | (f2bf_u(b.w) << 16);
    ((uint4*)out)[idx] = o;
}

// ---------------- RMSNorm: 2048 rows x 1024, bf16 output ----------------
__global__ __launch_bounds__(256) void k_rmsnorm(const float* __restrict__ x,
                                                 const float* __restrict__ w,
                                                 unsigned short* __restrict__ xn) {
    int row = blockIdx.x;
    const float* xr = x + (size_t)row * D_MODEL;
    int i = threadIdx.x * 4;
    float4 xv = *(const float4*)(xr + i);
    float s = xv.x * xv.x + xv.y * xv.y + xv.z * xv.z + xv.w * xv.w;
#pragma unroll
    for (int m = 1; m <= 32; m <<= 1) s += __shfl_xor(s, m);
    __shared__ float red[4];
    if ((threadIdx.x & 63) == 0) red[threadIdx.x >> 6] = s;
    __syncthreads();
    float tot = red[0] + red[1] + red[2] + red[3];
    float scale = rsqrtf(tot * (1.f / D_MODEL) + 1.1920929e-07f);
    float4 wv = *(const float4*)(w + i);
    uint2 o;
    o.x = f2bf_u(xv.x * scale * wv.x) | (f2bf_u(xv.y * scale * wv.y) << 16);
    o.y = f2bf_u(xv.z * scale * wv.z) | (f2bf_u(xv.w * scale * wv.w) << 16);
    *(uint2*)(xn + (size_t)row * D_MODEL + i) = o;
}

// ---------------- bf16 MFMA GEMM: C(MxN,f32) = A(MxK) * B(NxK)^T ----------------
template <int BN, int CW, int EPI>
__global__ __launch_bounds__(256) void gemm_bf16(const unsigned short* __restrict__ A,
                                                 const unsigned short* __restrict__ B,
                                                 float* __restrict__ C, int ldc, int K,
                                                 const float* __restrict__ res) {
    constexpr int RW = 4 / CW;
    constexpr int MI = (128 / RW) / 16;
    constexpr int NJ = (BN / CW) / 16;
    __shared__ __align__(16) unsigned short As[128 * 32];
    __shared__ __align__(16) unsigned short Bs[BN * 32];
    int tid = threadIdx.x;
    int lane = tid & 63, wv = tid >> 6;
    int wr = wv / CW, wc = wv % CW;
    int lm = lane & 15, q = lane >> 4;
    int m0 = blockIdx.x * 128, n0 = blockIdx.y * BN;
    f32x4 acc[MI][NJ] = {};
    for (int k0 = 0; k0 < K; k0 += 32) {
#pragma unroll
        for (int it = 0; it < 2; ++it) {
            int chunk = it * 256 + tid;
            const unsigned short* g = A + (size_t)(m0 + (chunk >> 2)) * K + k0 + (chunk & 3) * 8;
            char* l = (char*)As + (it * 256 + wv * 64) * 16 + lane * 16;
            gload_lds16(g, l);
        }
#pragma unroll
        for (int it = 0; it < BN / 64; ++it) {
            int chunk = it * 256 + tid;
            const unsigned short* g = B + (size_t)(n0 + (chunk >> 2)) * K + k0 + (chunk & 3) * 8;
            char* l = (char*)Bs + (it * 256 + wv * 64) * 16 + lane * 16;
            gload_lds16(g, l);
        }
        __syncthreads();
        bf16x8 af[MI], bfr[NJ];
#pragma unroll
        for (int i = 0; i < MI; ++i)
            af[i] = *(const bf16x8*)(As + (wr * MI * 16 + i * 16 + lm) * 32 + q * 8);
#pragma unroll
        for (int j = 0; j < NJ; ++j)
            bfr[j] = *(const bf16x8*)(Bs + (wc * NJ * 16 + j * 16 + lm) * 32 + q * 8);
#pragma unroll
        for (int i = 0; i < MI; ++i)
#pragma unroll
            for (int j = 0; j < NJ; ++j)
                acc[i][j] = __builtin_amdgcn_mfma_f32_16x16x32_bf16(af[i], bfr[j], acc[i][j], 0, 0, 0);
        __syncthreads();
    }
#pragma unroll
    for (int i = 0; i < MI; ++i) {
#pragma unroll
        for (int j = 0; j < NJ; ++j) {
#pragma unroll
            for (int r = 0; r < 4; ++r) {
                int row = m0 + wr * MI * 16 + i * 16 + q * 4 + r;
                int col = n0 + wc * NJ * 16 + j * 16 + lm;
                float v = acc[i][j][r];
                if (EPI == 2) v += res[(size_t)row * ldc + col];
                C[(size_t)row * ldc + col] = v;
            }
        }
    }
}

// ---------------- f32 tiled GEMM (dt_proj): softplus(A*B^T + bias) ----------------
__global__ __launch_bounds__(256) void gemm_nt_sp(const float* __restrict__ A, int lda,
                                                  const float* __restrict__ B, int ldb,
                                                  float* __restrict__ C, int ldc, int K,
                                                  const float* __restrict__ bias) {
    constexpr int BM = 64, BN = 64, BK = 16, TM = 4, TN = 4;
    __shared__ float As[BK][BM];
    __shared__ float Bs[BK][BN];
    int tid = threadIdx.x;
    int tx = tid & 15, ty = tid >> 4;
    int m0 = blockIdx.x * BM, n0 = blockIdx.y * BN;
    float acc[TM][TN] = {};
    for (int k0 = 0; k0 < K; k0 += BK) {
#pragma unroll
        for (int i = 0; i < 4; ++i) {
            int idx = tid + i * 256;
            As[idx & 15][idx >> 4] = A[(size_t)(m0 + (idx >> 4)) * lda + k0 + (idx & 15)];
        }
#pragma unroll
        for (int i = 0; i < 4; ++i) {
            int idx = tid + i * 256;
            Bs[idx & 15][idx >> 4] = B[(size_t)(n0 + (idx >> 4)) * ldb + k0 + (idx & 15)];
        }
        __syncthreads();
#pragma unroll
        for (int k = 0; k < BK; ++k) {
            float4 av = *(const float4*)&As[k][ty * TM];
            float4 bv = *(const float4*)&Bs[k][tx * TN];
            float a[TM] = {av.x, av.y, av.z, av.w};
            float b[TN] = {bv.x, bv.y, bv.z, bv.w};
#pragma unroll
            for (int i = 0; i < TM; ++i)
#pragma unroll
                for (int j = 0; j < TN; ++j) acc[i][j] = fmaf(a[i], b[j], acc[i][j]);
        }
        __syncthreads();
    }
#pragma unroll
    for (int i = 0; i < TM; ++i) {
        int m = m0 + ty * TM + i;
#pragma unroll
        for (int j = 0; j < TN; ++j) {
            int n = n0 + tx * TN + j;
            float v = acc[i][j] + bias[n];
            v = (v > 20.f) ? v : log1pf(__expf(v));
            C[(size_t)m * ldc + n] = v;
        }
    }
}

// ---------------- depthwise causal conv (k=4) + SiLU ----------------
__global__ __launch_bounds__(256) void k_conv(const float* __restrict__ xz,
                                              const float* __restrict__ cw,
                                              const float* __restrict__ cb,
                                              float* __restrict__ u) {
    int idx = blockIdx.x * 256 + threadIdx.x;
    int c = idx & (D_INNER - 1);
    int t = (idx >> 11) & (T_LEN - 1);
    int b = idx >> 21;
    const float* xs = xz + (size_t)b * T_LEN * 2 * D_INNER + c;
    float4 wv = *(const float4*)(cw + c * 4);
    float s = cb[c];
    if (t >= 3) s = fmaf(xs[(size_t)(t - 3) * 2 * D_INNER], wv.x, s);
    if (t >= 2) s = fmaf(xs[(size_t)(t - 2) * 2 * D_INNER], wv.y, s);
    if (t >= 1) s = fmaf(xs[(size_t)(t - 1) * 2 * D_INNER], wv.z, s);
    s = fmaf(xs[(size_t)t * 2 * D_INNER], wv.w, s);
    u[idx] = s * sigmoidf_(s);
}

// ---------------- x_proj: dbc(2048x96) += u(2048x2048) @ x_proj_w(96x2048)^T ----------------
__global__ __launch_bounds__(128) void k_xproj(const float* __restrict__ u,
                                               const float* __restrict__ w,
                                               float* __restrict__ dbc) {
    __shared__ __align__(16) float su[512];
    int token = blockIdx.x;
    int kc = blockIdx.y;
    const float* urow = u + (size_t)token * D_INNER + kc * 512;
    if (threadIdx.x < 128) ((float4*)su)[threadIdx.x] = ((const float4*)urow)[threadIdx.x];
    __syncthreads();
    int j = threadIdx.x;
    if (j < XPROJ_OUT) {
        const float* wr = w + (size_t)j * D_INNER + kc * 512;
        float s = 0.f;
#pragma unroll 4
        for (int k = 0; k < 512; k += 4) {
            float4 wv = *(const float4*)(wr + k);
            s = fmaf(su[k], wv.x, s);
            s = fmaf(su[k + 1], wv.y, s);
            s = fmaf(su[k + 2], wv.z, s);
            s = fmaf(su[k + 3], wv.w, s);
        }
        atomicAdd(&dbc[(size_t)token * XPROJ_OUT + j], s);
    }
}

// ---------------- chunked selective scan ----------------
// unit = (b, chunk, c): unit = b*(NCHUNK*D_INNER) + chunk*D_INNER + c
// wave handles 4 consecutive c; lane = ci*16 + s.
// Pass 1: local scan from h=0, track P = prod(dA). Store P, h_local_end at [unit*16+s].
__global__ __launch_bounds__(256) void k_scan1(const float* __restrict__ delta,
                                               const float* __restrict__ u,
                                               const float* __restrict__ dbc,
                                               const float* __restrict__ A_log,
                                               float* __restrict__ Pbuf,
                                               float* __restrict__ Hbuf) {
    int lane = threadIdx.x & 63;
    int s = lane & 15, ci = lane >> 4;
    int unit = blockIdx.x * 16 + (threadIdx.x >> 6) * 4 + ci;  // 0..32767
    int c = unit & (D_INNER - 1);
    int chunk = (unit >> 11) & (NCHUNK - 1);
    int b = unit >> 14;
    int t0 = chunk * CHUNK_L;
    float A = -__expf(A_log[c * D_STATE + s]);
    const float* dptr = delta + ((size_t)b * T_LEN + t0) * D_INNER + c;
    const float* uptr = u + ((size_t)b * T_LEN + t0) * D_INNER + c;
    const float* bptr = dbc + ((size_t)b * T_LEN + t0) * XPROJ_OUT + DT_RANK + s;
    float h = 0.f, P = 1.f;
    float dv = dptr[0], uv = uptr[0], Bv = bptr[0];
    for (int t = 0; t < CHUNK_L; ++t) {
        float dn = 0.f, un = 0.f, Bn = 0.f;
        if (t + 1 < CHUNK_L) {
            dn = dptr[(size_t)(t + 1) * D_INNER];
            un = uptr[(size_t)(t + 1) * D_INNER];
            Bn = bptr[(size_t)(t + 1) * XPROJ_OUT];
        }
        float da = __expf(dv * A);
        P *= da;
        h = fmaf(da, h, dv * uv * Bv);
        dv = dn; uv = un; Bv = Bn;
    }
    size_t o = (size_t)unit * 16 + s;
    Pbuf[o] = P;
    Hbuf[o] = h;
}

// Pass 2: sequential over NCHUNK chunk summaries; Hbuf becomes h_start per chunk.
__global__ __launch_bounds__(256) void k_scan2(const float* __restrict__ Pbuf,
                                               float* __restrict__ Hbuf) {
    int idx = blockIdx.x * 256 + threadIdx.x;  // 0..65535 = (b, c, s)
    int b = idx >> 15, r = idx & 32767;
    size_t base = (size_t)b * NCHUNK * (D_INNER * 16) + r;
    float h = 0.f;
#pragma unroll
    for (int ch = 0; ch < NCHUNK; ++ch) {
        size_t o = base + (size_t)ch * (D_INNER * 16);
        float hl = Hbuf[o];
        float P = Pbuf[o];
        Hbuf[o] = h;  // h_start for this chunk
        h = fmaf(P, h, hl);
    }
}

// Pass 3: redo recurrence from exact h_start; fuse C-proj, D*u, silu(z); emit bf16 y.
__global__ __launch_bounds__(256) void k_scan3(const float* __restrict__ delta,
                                               const float* __restrict__ u,
                                               const float* __restrict__ dbc,
                                               const float* __restrict__ xz,
                                               const float* __restrict__ A_log,
                                               const float* __restrict__ Dp,
                                               const float* __restrict__ Hbuf,
                                               unsigned short* __restrict__ yb) {
    int lane = threadIdx.x & 63;
    int s = lane & 15, ci = lane >> 4;
    int unit = blockIdx.x * 16 + (threadIdx.x >> 6) * 4 + ci;
    int c = unit & (D_INNER - 1);
    int chunk = (unit >> 11) & (NCHUNK - 1);
    int b = unit >> 14;
    int t0 = chunk * CHUNK_L;
    float A = -__expf(A_log[c * D_STATE + s]);
    float Dc = Dp[c];
    const float* dptr = delta + ((size_t)b * T_LEN + t0) * D_INNER + c;
    const float* uptr = u + ((size_t)b * T_LEN + t0) * D_INNER + c;
    const float* bptr = dbc + ((size_t)b * T_LEN + t0) * XPROJ_OUT + DT_RANK + s;
    const float* cptr = bptr + D_STATE;
    const float* zptr = xz + ((size_t)b * T_LEN + t0) * 2 * D_INNER + D_INNER + c;
    unsigned short* yptr = yb + ((size_t)b * T_LEN + t0) * D_INNER + c;
    float h = Hbuf[(size_t)unit * 16 + s];
    float dv = dptr[0], uv = uptr[0], Bv = bptr[0], Cv = cptr[0], zv = zptr[0];
    for (int t = 0; t < CHUNK_L; ++t) {
        float dn = 0.f, un = 0.f, Bn = 0.f, Cn = 0.f, zn = 0.f;
        if (t + 1 < CHUNK_L) {
            int o = t + 1;
            dn = dptr[(size_t)o * D_INNER];
            un = uptr[(size_t)o * D_INNER];
            Bn = bptr[(size_t)o * XPROJ_OUT];
            Cn = cptr[(size_t)o * XPROJ_OUT];
            zn = zptr[(size_t)o * 2 * D_INNER];
        }
        float da = __expf(dv * A);
        h = fmaf(da, h, dv * uv * Bv);
        float p = h * Cv;
        p += __shfl_xor(p, 1);
        p += __shfl_xor(p, 2);
        p += __shfl_xor(p, 4);
        p += __shfl_xor(p, 8);
        if (s == 0) {
            float sz = zv * sigmoidf_(zv);
            yptr[(size_t)t * D_INNER] = (unsigned short)f2bf_u((p + Dc * uv) * sz);
        }
        dv = dn; uv = un; Bv = Bn; Cv = Cn; zv = zn;
    }
}

extern "C" void kernel_launch(void* const* d_in, const int* in_sizes, int n_in,
                              void* d_out, int out_size, void* d_ws, size_t ws_size,
                              hipStream_t stream) {
    const float* x         = (const float*)d_in[0];
    const float* norm_w    = (const float*)d_in[1];
    const float* in_proj_w = (const float*)d_in[2];
    const float* conv_w    = (const float*)d_in[3];
    const float* conv_b    = (const float*)d_in[4];
    const float* x_proj_w  = (const float*)d_in[5];
    const float* dt_proj_w = (const float*)d_in[6];
    const float* dt_proj_b = (const float*)d_in[7];
    const float* A_log     = (const float*)d_in[8];
    const float* D_param   = (const float*)d_in[9];
    const float* out_proj_w= (const float*)d_in[10];
    float* out = (float*)d_out;

    // workspace layout (float units)
    float* ws = (float*)d_ws;
    float*          xz    = ws;                   // 2048*4096 f32
    float*          u     = ws + 8388608;         // 2048*2048 f32
    float*          delta = ws + 12582912;        // 2048*2048 f32
    float*          dbc   = ws + 16777216;        // 2048*96 f32
    unsigned short* xnb   = (unsigned short*)(ws + 16973824); // 2048*1024 bf16
    unsigned short* wib   = (unsigned short*)(ws + 18022400); // 4096*1024 bf16
    unsigned short* wob   = (unsigned short*)(ws + 20119552); // 1024*2048 bf16
    unsigned short* yb    = (unsigned short*)(ws + 21168128); // 2048*2048 bf16
    float*          Pbuf  = ws + 23265280;        // 32768*16 f32
    float*          Hbuf  = ws + 23789568;        // 32768*16 f32
    // total: 24,313,856 floats = 97.3 MB

    hipMemsetAsync(dbc, 0, (size_t)NTOK * XPROJ_OUT * sizeof(float), stream);

    // 0. weight casts f32 -> bf16
    k_cast<<<(4096 * 1024) / 2048, 256, 0, stream>>>(in_proj_w, (unsigned*)wib);
    k_cast<<<(1024 * 2048) / 2048, 256, 0, stream>>>(out_proj_w, (unsigned*)wob);
    // 1. RMSNorm -> bf16
    k_rmsnorm<<<NTOK, 256, 0, stream>>>(x, norm_w, xnb);
    // 2. xz = xn @ in_proj_w^T  (2048 x 4096 x 1024), MFMA bf16
    gemm_bf16<128, 2, 0><<<dim3(NTOK / 128, 4096 / 128), 256, 0, stream>>>(
        xnb, wib, xz, 2 * D_INNER, D_MODEL, nullptr);
    // 3. depthwise conv + SiLU -> u
    k_conv<<<(NTOK * D_INNER) / 256, 256, 0, stream>>>(xz, conv_w, conv_b, u);
    // 4. x_dbc = u @ x_proj_w^T  (2048 x 96 x 2048)
    k_xproj<<<dim3(NTOK, 4), 128, 0, stream>>>(u, x_proj_w, dbc);
    // 5. delta = softplus(dt_raw @ dt_proj_w^T + b)  (2048 x 2048 x 64), f32
    gemm_nt_sp<<<dim3(NTOK / 64, D_INNER / 64), 256, 0, stream>>>(
        dbc, XPROJ_OUT, dt_proj_w, DT_RANK, delta, D_INNER, DT_RANK, dt_proj_b);
    // 6. chunked selective scan -> yb (bf16)
    k_scan1<<<(B_SZ * NCHUNK * D_INNER) / 16, 256, 0, stream>>>(delta, u, dbc, A_log, Pbuf, Hbuf);
    k_scan2<<<(B_SZ * D_INNER * D_STATE) / 256, 256, 0, stream>>>(Pbuf, Hbuf);
    k_scan3<<<(B_SZ * NCHUNK * D_INNER) / 16, 256, 0, stream>>>(delta, u, dbc, xz, A_log, D_param,
                                                                Hbuf, yb);
    // 7. out = y @ out_proj_w^T + x  (2048 x 1024 x 2048), MFMA bf16, 128x64 tile
    gemm_bf16<64, 1, 2><<<dim3(NTOK / 128, 1024 / 64), 256, 0, stream>>>(
        yb, wob, out, D_MODEL, D_INNER, x);

    (void)in_sizes; (void)n_in; (void)out_size; (void)ws_size;
}

// Round 4
// 351.012 us; speedup vs baseline: 3.6960x; 1.4841x over previous
//
#include <hip/hip_runtime.h>
#include <math.h>

#define B_SZ 2
#define T_LEN 1024
#define D_MODEL 1024
#define D_STATE 16
#define D_INNER 2048
#define DT_RANK 64
#define NTOK (B_SZ * T_LEN)               // 2048 tokens
#define XPROJ_OUT 96
#define XPROJ_LD 128                      // padded leading dim for dbc
#define NCHUNK 8
#define CHUNK_L (T_LEN / NCHUNK)          // 128
#define NSPLIT 16                         // split-K for x_proj

typedef __attribute__((ext_vector_type(8))) short bf16x8;
typedef __attribute__((ext_vector_type(4))) float f32x4;

__device__ __forceinline__ float sigmoidf_(float x) { return 1.f / (1.f + __expf(-x)); }

__device__ __forceinline__ unsigned f2bf_u(float f) {  // RNE f32->bf16 bits
    unsigned u = __float_as_uint(f);
    return (u + 0x7FFFu + ((u >> 16) & 1u)) >> 16;
}

__device__ __forceinline__ void gload_lds16(const void* g, void* l) {
    __builtin_amdgcn_global_load_lds((const __attribute__((address_space(1))) unsigned*)g,
                                     (__attribute__((address_space(3))) unsigned*)l,
                                     16, 0, 0);
}

// ---------------- f32 -> bf16 cast (8 elems/thread) ----------------
__global__ __launch_bounds__(256) void k_cast(const float* __restrict__ in,
                                              unsigned* __restrict__ out) {
    int idx = blockIdx.x * 256 + threadIdx.x;
    float4 a = ((const float4*)in)[idx * 2];
    float4 b = ((const float4*)in)[idx * 2 + 1];
    uint4 o;
    o.x = f2bf_u(a.x) | (f2bf_u(a.y) << 16);
    o.y = f2bf_u(a.z) | (f2bf_u(a.w) << 16);
    o.z = f2bf_u(b.x) | (f2bf_u(b.y) << 16);
    o.w = f2bf_u(b.z) | (f2bf_u(b.w) << 16);
    ((uint4*)out)[idx] = o;
}

// ---------------- RMSNorm: 2048 rows x 1024, bf16 output ----------------
__global__ __launch_bounds__(256) void k_rmsnorm(const float* __restrict__ x,
                                                 const float* __restrict__ w,
                                                 unsigned short* __restrict__ xn) {
    int row = blockIdx.x;
    const float* xr = x + (size_t)row * D_MODEL;
    int i = threadIdx.x * 4;
    float4 xv = *(const float4*)(xr + i);
    float s = xv.x * xv.x + xv.y * xv.y + xv.z * xv.z + xv.w * xv.w;
#pragma unroll
    for (int m = 1; m <= 32; m <<= 1) s += __shfl_xor(s, m);
    __shared__ float red[4];
    if ((threadIdx.x & 63) == 0) red[threadIdx.x >> 6] = s;
    __syncthreads();
    float tot = red[0] + red[1] + red[2] + red[3];
    float scale = rsqrtf(tot * (1.f / D_MODEL) + 1.1920929e-07f);
    float4 wv = *(const float4*)(w + i);
    uint2 o;
    o.x = f2bf_u(xv.x * scale * wv.x) | (f2bf_u(xv.y * scale * wv.y) << 16);
    o.y = f2bf_u(xv.z * scale * wv.z) | (f2bf_u(xv.w * scale * wv.w) << 16);
    *(uint2*)(xn + (size_t)row * D_MODEL + i) = o;
}

// ---------------- bf16 MFMA GEMM: C(MxN,f32) = A(MxK) * B(NxK)^T ----------------
template <int BN, int CW, int EPI>
__global__ __launch_bounds__(256) void gemm_bf16(const unsigned short* __restrict__ A,
                                                 const unsigned short* __restrict__ B,
                                                 float* __restrict__ C, int ldc, int K,
                                                 const float* __restrict__ res) {
    constexpr int RW = 4 / CW;
    constexpr int MI = (128 / RW) / 16;
    constexpr int NJ = (BN / CW) / 16;
    __shared__ __align__(16) unsigned short As[128 * 32];
    __shared__ __align__(16) unsigned short Bs[BN * 32];
    int tid = threadIdx.x;
    int lane = tid & 63, wv = tid >> 6;
    int wr = wv / CW, wc = wv % CW;
    int lm = lane & 15, q = lane >> 4;
    int m0 = blockIdx.x * 128, n0 = blockIdx.y * BN;
    f32x4 acc[MI][NJ] = {};
    for (int k0 = 0; k0 < K; k0 += 32) {
#pragma unroll
        for (int it = 0; it < 2; ++it) {
            int chunk = it * 256 + tid;
            const unsigned short* g = A + (size_t)(m0 + (chunk >> 2)) * K + k0 + (chunk & 3) * 8;
            char* l = (char*)As + (it * 256 + wv * 64) * 16 + lane * 16;
            gload_lds16(g, l);
        }
#pragma unroll
        for (int it = 0; it < BN / 64; ++it) {
            int chunk = it * 256 + tid;
            const unsigned short* g = B + (size_t)(n0 + (chunk >> 2)) * K + k0 + (chunk & 3) * 8;
            char* l = (char*)Bs + (it * 256 + wv * 64) * 16 + lane * 16;
            gload_lds16(g, l);
        }
        __syncthreads();
        bf16x8 af[MI], bfr[NJ];
#pragma unroll
        for (int i = 0; i < MI; ++i)
            af[i] = *(const bf16x8*)(As + (wr * MI * 16 + i * 16 + lm) * 32 + q * 8);
#pragma unroll
        for (int j = 0; j < NJ; ++j)
            bfr[j] = *(const bf16x8*)(Bs + (wc * NJ * 16 + j * 16 + lm) * 32 + q * 8);
#pragma unroll
        for (int i = 0; i < MI; ++i)
#pragma unroll
            for (int j = 0; j < NJ; ++j)
                acc[i][j] = __builtin_amdgcn_mfma_f32_16x16x32_bf16(af[i], bfr[j], acc[i][j], 0, 0, 0);
        __syncthreads();
    }
#pragma unroll
    for (int i = 0; i < MI; ++i) {
#pragma unroll
        for (int j = 0; j < NJ; ++j) {
#pragma unroll
            for (int r = 0; r < 4; ++r) {
                int row = m0 + wr * MI * 16 + i * 16 + q * 4 + r;
                int col = n0 + wc * NJ * 16 + j * 16 + lm;
                float v = acc[i][j][r];
                if (EPI == 2) v += res[(size_t)row * ldc + col];
                C[(size_t)row * ldc + col] = v;
            }
        }
    }
}

// ---------------- x_proj split-K MFMA GEMM: part[s] = u[*,ks] @ wxb^T ----------------
// A: ub (2048 x 2048 bf16), B: wxb (128 x 2048 bf16, rows 96.. zeroed)
// grid (M/128=16, NSPLIT=16); each block does K-slab of 128.
__global__ __launch_bounds__(256) void xproj_gemm(const unsigned short* __restrict__ A,
                                                  const unsigned short* __restrict__ B,
                                                  float* __restrict__ part) {
    constexpr int MI = 4, NJ = 4;  // CW=2
    __shared__ __align__(16) unsigned short As[128 * 32];
    __shared__ __align__(16) unsigned short Bs[128 * 32];
    int tid = threadIdx.x;
    int lane = tid & 63, wv = tid >> 6;
    int wr = wv >> 1, wc = wv & 1;
    int lm = lane & 15, q = lane >> 4;
    int m0 = blockIdx.x * 128;
    int kbase = blockIdx.y * (D_INNER / NSPLIT);  // 128-wide K slab
    f32x4 acc[MI][NJ] = {};
#pragma unroll
    for (int ki = 0; ki < (D_INNER / NSPLIT) / 32; ++ki) {
        int k0 = kbase + ki * 32;
#pragma unroll
        for (int it = 0; it < 2; ++it) {
            int chunk = it * 256 + tid;
            const unsigned short* g = A + (size_t)(m0 + (chunk >> 2)) * D_INNER + k0 + (chunk & 3) * 8;
            char* l = (char*)As + (it * 256 + wv * 64) * 16 + lane * 16;
            gload_lds16(g, l);
        }
#pragma unroll
        for (int it = 0; it < 2; ++it) {
            int chunk = it * 256 + tid;
            const unsigned short* g = B + (size_t)(chunk >> 2) * D_INNER + k0 + (chunk & 3) * 8;
            char* l = (char*)Bs + (it * 256 + wv * 64) * 16 + lane * 16;
            gload_lds16(g, l);
        }
        __syncthreads();
        bf16x8 af[MI], bfr[NJ];
#pragma unroll
        for (int i = 0; i < MI; ++i)
            af[i] = *(const bf16x8*)(As + (wr * 64 + i * 16 + lm) * 32 + q * 8);
#pragma unroll
        for (int j = 0; j < NJ; ++j)
            bfr[j] = *(const bf16x8*)(Bs + (wc * 64 + j * 16 + lm) * 32 + q * 8);
#pragma unroll
        for (int i = 0; i < MI; ++i)
#pragma unroll
            for (int j = 0; j < NJ; ++j)
                acc[i][j] = __builtin_amdgcn_mfma_f32_16x16x32_bf16(af[i], bfr[j], acc[i][j], 0, 0, 0);
        __syncthreads();
    }
    float* dst = part + (size_t)blockIdx.y * (NTOK * XPROJ_LD);
#pragma unroll
    for (int i = 0; i < MI; ++i)
#pragma unroll
        for (int j = 0; j < NJ; ++j)
#pragma unroll
            for (int r = 0; r < 4; ++r) {
                int row = m0 + wr * 64 + i * 16 + q * 4 + r;
                int col = wc * 64 + j * 16 + lm;
                dst[(size_t)row * XPROJ_LD + col] = acc[i][j][r];
            }
}

// ---------------- reduce split-K partials: dbc = sum_s part[s] ----------------
__global__ __launch_bounds__(256) void k_xred(const float* __restrict__ part,
                                              float* __restrict__ dbc) {
    int idx = blockIdx.x * 256 + threadIdx.x;  // 0 .. 2048*128-1
    float s = 0.f;
#pragma unroll
    for (int sp = 0; sp < NSPLIT; ++sp) s += part[(size_t)sp * (NTOK * XPROJ_LD) + idx];
    dbc[idx] = s;
}

// ---------------- f32 tiled GEMM (dt_proj): softplus(A*B^T + bias) ----------------
__global__ __launch_bounds__(256) void gemm_nt_sp(const float* __restrict__ A, int lda,
                                                  const float* __restrict__ B, int ldb,
                                                  float* __restrict__ C, int ldc, int K,
                                                  const float* __restrict__ bias) {
    constexpr int BM = 64, BN = 64, BK = 16, TM = 4, TN = 4;
    __shared__ float As[BK][BM];
    __shared__ float Bs[BK][BN];
    int tid = threadIdx.x;
    int tx = tid & 15, ty = tid >> 4;
    int m0 = blockIdx.x * BM, n0 = blockIdx.y * BN;
    float acc[TM][TN] = {};
    for (int k0 = 0; k0 < K; k0 += BK) {
#pragma unroll
        for (int i = 0; i < 4; ++i) {
            int idx = tid + i * 256;
            As[idx & 15][idx >> 4] = A[(size_t)(m0 + (idx >> 4)) * lda + k0 + (idx & 15)];
        }
#pragma unroll
        for (int i = 0; i < 4; ++i) {
            int idx = tid + i * 256;
            Bs[idx & 15][idx >> 4] = B[(size_t)(n0 + (idx >> 4)) * ldb + k0 + (idx & 15)];
        }
        __syncthreads();
#pragma unroll
        for (int k = 0; k < BK; ++k) {
            float4 av = *(const float4*)&As[k][ty * TM];
            float4 bv = *(const float4*)&Bs[k][tx * TN];
            float a[TM] = {av.x, av.y, av.z, av.w};
            float b[TN] = {bv.x, bv.y, bv.z, bv.w};
#pragma unroll
            for (int i = 0; i < TM; ++i)
#pragma unroll
                for (int j = 0; j < TN; ++j) acc[i][j] = fmaf(a[i], b[j], acc[i][j]);
        }
        __syncthreads();
    }
#pragma unroll
    for (int i = 0; i < TM; ++i) {
        int m = m0 + ty * TM + i;
#pragma unroll
        for (int j = 0; j < TN; ++j) {
            int n = n0 + tx * TN + j;
            float v = acc[i][j] + bias[n];
            v = (v > 20.f) ? v : log1pf(__expf(v));
            C[(size_t)m * ldc + n] = v;
        }
    }
}

// ---------------- depthwise causal conv (k=4) + SiLU; emits f32 u and bf16 ub ----------------
__global__ __launch_bounds__(256) void k_conv(const float* __restrict__ xz,
                                              const float* __restrict__ cw,
                                              const float* __restrict__ cb,
                                              float* __restrict__ u,
                                              unsigned short* __restrict__ ub) {
    int idx = blockIdx.x * 256 + threadIdx.x;
    int c = idx & (D_INNER - 1);
    int t = (idx >> 11) & (T_LEN - 1);
    int b = idx >> 21;
    const float* xs = xz + (size_t)b * T_LEN * 2 * D_INNER + c;
    float4 wv = *(const float4*)(cw + c * 4);
    float s = cb[c];
    if (t >= 3) s = fmaf(xs[(size_t)(t - 3) * 2 * D_INNER], wv.x, s);
    if (t >= 2) s = fmaf(xs[(size_t)(t - 2) * 2 * D_INNER], wv.y, s);
    if (t >= 1) s = fmaf(xs[(size_t)(t - 1) * 2 * D_INNER], wv.z, s);
    s = fmaf(xs[(size_t)t * 2 * D_INNER], wv.w, s);
    float v = s * sigmoidf_(s);
    u[idx] = v;
    ub[idx] = (unsigned short)f2bf_u(v);
}

// ---------------- chunked selective scan ----------------
__global__ __launch_bounds__(256) void k_scan1(const float* __restrict__ delta,
                                               const float* __restrict__ u,
                                               const float* __restrict__ dbc,
                                               const float* __restrict__ A_log,
                                               float* __restrict__ Pbuf,
                                               float* __restrict__ Hbuf) {
    int lane = threadIdx.x & 63;
    int s = lane & 15, ci = lane >> 4;
    int unit = blockIdx.x * 16 + (threadIdx.x >> 6) * 4 + ci;  // 0..32767
    int c = unit & (D_INNER - 1);
    int chunk = (unit >> 11) & (NCHUNK - 1);
    int b = unit >> 14;
    int t0 = chunk * CHUNK_L;
    float A = -__expf(A_log[c * D_STATE + s]);
    const float* dptr = delta + ((size_t)b * T_LEN + t0) * D_INNER + c;
    const float* uptr = u + ((size_t)b * T_LEN + t0) * D_INNER + c;
    const float* bptr = dbc + ((size_t)b * T_LEN + t0) * XPROJ_LD + DT_RANK + s;
    float h = 0.f, P = 1.f;
    float dv = dptr[0], uv = uptr[0], Bv = bptr[0];
    for (int t = 0; t < CHUNK_L; ++t) {
        float dn = 0.f, un = 0.f, Bn = 0.f;
        if (t + 1 < CHUNK_L) {
            dn = dptr[(size_t)(t + 1) * D_INNER];
            un = uptr[(size_t)(t + 1) * D_INNER];
            Bn = bptr[(size_t)(t + 1) * XPROJ_LD];
        }
        float da = __expf(dv * A);
        P *= da;
        h = fmaf(da, h, dv * uv * Bv);
        dv = dn; uv = un; Bv = Bn;
    }
    size_t o = (size_t)unit * 16 + s;
    Pbuf[o] = P;
    Hbuf[o] = h;
}

__global__ __launch_bounds__(256) void k_scan2(const float* __restrict__ Pbuf,
                                               float* __restrict__ Hbuf) {
    int idx = blockIdx.x * 256 + threadIdx.x;  // 0..65535 = (b, c, s)
    int b = idx >> 15, r = idx & 32767;
    size_t base = (size_t)b * NCHUNK * (D_INNER * 16) + r;
    float h = 0.f;
#pragma unroll
    for (int ch = 0; ch < NCHUNK; ++ch) {
        size_t o = base + (size_t)ch * (D_INNER * 16);
        float hl = Hbuf[o];
        float P = Pbuf[o];
        Hbuf[o] = h;
        h = fmaf(P, h, hl);
    }
}

__global__ __launch_bounds__(256) void k_scan3(const float* __restrict__ delta,
                                               const float* __restrict__ u,
                                               const float* __restrict__ dbc,
                                               const float* __restrict__ xz,
                                               const float* __restrict__ A_log,
                                               const float* __restrict__ Dp,
                                               const float* __restrict__ Hbuf,
                                               unsigned short* __restrict__ yb) {
    int lane = threadIdx.x & 63;
    int s = lane & 15, ci = lane >> 4;
    int unit = blockIdx.x * 16 + (threadIdx.x >> 6) * 4 + ci;
    int c = unit & (D_INNER - 1);
    int chunk = (unit >> 11) & (NCHUNK - 1);
    int b = unit >> 14;
    int t0 = chunk * CHUNK_L;
    float A = -__expf(A_log[c * D_STATE + s]);
    float Dc = Dp[c];
    const float* dptr = delta + ((size_t)b * T_LEN + t0) * D_INNER + c;
    const float* uptr = u + ((size_t)b * T_LEN + t0) * D_INNER + c;
    const float* bptr = dbc + ((size_t)b * T_LEN + t0) * XPROJ_LD + DT_RANK + s;
    const float* cptr = bptr + D_STATE;
    const float* zptr = xz + ((size_t)b * T_LEN + t0) * 2 * D_INNER + D_INNER + c;
    unsigned short* yptr = yb + ((size_t)b * T_LEN + t0) * D_INNER + c;
    float h = Hbuf[(size_t)unit * 16 + s];
    float dv = dptr[0], uv = uptr[0], Bv = bptr[0], Cv = cptr[0], zv = zptr[0];
    for (int t = 0; t < CHUNK_L; ++t) {
        float dn = 0.f, un = 0.f, Bn = 0.f, Cn = 0.f, zn = 0.f;
        if (t + 1 < CHUNK_L) {
            int o = t + 1;
            dn = dptr[(size_t)o * D_INNER];
            un = uptr[(size_t)o * D_INNER];
            Bn = bptr[(size_t)o * XPROJ_LD];
            Cn = cptr[(size_t)o * XPROJ_LD];
            zn = zptr[(size_t)o * 2 * D_INNER];
        }
        float da = __expf(dv * A);
        h = fmaf(da, h, dv * uv * Bv);
        float p = h * Cv;
        p += __shfl_xor(p, 1);
        p += __shfl_xor(p, 2);
        p += __shfl_xor(p, 4);
        p += __shfl_xor(p, 8);
        if (s == 0) {
            float sz = zv * sigmoidf_(zv);
            yptr[(size_t)t * D_INNER] = (unsigned short)f2bf_u((p + Dc * uv) * sz);
        }
        dv = dn; uv = un; Bv = Bn; Cv = Cn; zv = zn;
    }
}

extern "C" void kernel_launch(void* const* d_in, const int* in_sizes, int n_in,
                              void* d_out, int out_size, void* d_ws, size_t ws_size,
                              hipStream_t stream) {
    const float* x         = (const float*)d_in[0];
    const float* norm_w    = (const float*)d_in[1];
    const float* in_proj_w = (const float*)d_in[2];
    const float* conv_w    = (const float*)d_in[3];
    const float* conv_b    = (const float*)d_in[4];
    const float* x_proj_w  = (const float*)d_in[5];
    const float* dt_proj_w = (const float*)d_in[6];
    const float* dt_proj_b = (const float*)d_in[7];
    const float* A_log     = (const float*)d_in[8];
    const float* D_param   = (const float*)d_in[9];
    const float* out_proj_w= (const float*)d_in[10];
    float* out = (float*)d_out;

    // workspace layout (float units), with liveness overlaps; total 23,461,888 f = 93.9 MB
    float* ws = (float*)d_ws;
    float*          xz    = ws;                    // 2048*4096
    float*          u     = ws + 8388608;          // 2048*2048
    float*          delta = ws + 12582912;         // 2048*2048  (part overlaps: dead before delta written)
    float*          part  = delta;                 // 16*2048*128 = 4194304
    float*          dbc   = ws + 16777216;         // 2048*128
    unsigned short* xnb   = (unsigned short*)(ws + 17039360); // 2048*1024 bf16 (dead after in_proj)
    float*          Pbuf  = ws + 17039360;         // 32768*16 (overlaps xnb)
    float*          Hbuf  = ws + 17563648;         // 32768*16
    unsigned short* wib   = (unsigned short*)(ws + 18087936); // 4096*1024 bf16
    unsigned short* wob   = (unsigned short*)(ws + 20185088); // 1024*2048 bf16
    unsigned short* wxb   = (unsigned short*)(ws + 21233664); // 128*2048 bf16
    unsigned short* ub    = (unsigned short*)(ws + 21364736); // 2048*2048 bf16 (dead after xproj)
    unsigned short* yb    = ub;                    // scan3 writes after ub consumed

    // 0. weight casts f32 -> bf16 (+ zero the wxb pad rows 96..127)
    k_cast<<<(4096 * 1024) / 2048, 256, 0, stream>>>(in_proj_w, (unsigned*)wib);
    k_cast<<<(1024 * 2048) / 2048, 256, 0, stream>>>(out_proj_w, (unsigned*)wob);
    k_cast<<<(96 * 2048) / 2048, 256, 0, stream>>>(x_proj_w, (unsigned*)wxb);
    hipMemsetAsync(wxb + 96 * 2048, 0, 32 * 2048 * sizeof(unsigned short), stream);

    // 1. RMSNorm -> bf16
    k_rmsnorm<<<NTOK, 256, 0, stream>>>(x, norm_w, xnb);
    // 2. xz = xn @ in_proj_w^T  (2048 x 4096 x 1024), MFMA bf16
    gemm_bf16<128, 2, 0><<<dim3(NTOK / 128, 4096 / 128), 256, 0, stream>>>(
        xnb, wib, xz, 2 * D_INNER, D_MODEL, nullptr);
    // 3. depthwise conv + SiLU -> u (f32) + ub (bf16)
    k_conv<<<(NTOK * D_INNER) / 256, 256, 0, stream>>>(xz, conv_w, conv_b, u, ub);
    // 4. x_dbc: split-K MFMA GEMM + reduce  (2048 x 128 x 2048)
    xproj_gemm<<<dim3(NTOK / 128, NSPLIT), 256, 0, stream>>>(ub, wxb, part);
    k_xred<<<(NTOK * XPROJ_LD) / 256, 256, 0, stream>>>(part, dbc);
    // 5. delta = softplus(dt_raw @ dt_proj_w^T + b)  (2048 x 2048 x 64), f32
    gemm_nt_sp<<<dim3(NTOK / 64, D_INNER / 64), 256, 0, stream>>>(
        dbc, XPROJ_LD, dt_proj_w, DT_RANK, delta, D_INNER, DT_RANK, dt_proj_b);
    // 6. chunked selective scan -> yb (bf16)
    k_scan1<<<(B_SZ * NCHUNK * D_INNER) / 16, 256, 0, stream>>>(delta, u, dbc, A_log, Pbuf, Hbuf);
    k_scan2<<<(B_SZ * D_INNER * D_STATE) / 256, 256, 0, stream>>>(Pbuf, Hbuf);
    k_scan3<<<(B_SZ * NCHUNK * D_INNER) / 16, 256, 0, stream>>>(delta, u, dbc, xz, A_log, D_param,
                                                                Hbuf, yb);
    // 7. out = y @ out_proj_w^T + x  (2048 x 1024 x 2048), MFMA bf16, 128x64 tile
    gemm_bf16<64, 1, 2><<<dim3(NTOK / 128, 1024 / 64), 256, 0, stream>>>(
        yb, wob, out, D_MODEL, D_INNER, x);

    (void)in_sizes; (void)n_in; (void)out_size; (void)ws_size;
}

// Round 5
// 288.876 us; speedup vs baseline: 4.4910x; 1.2151x over previous
//
#include <hip/hip_runtime.h>
#include <math.h>

#define B_SZ 2
#define T_LEN 1024
#define D_MODEL 1024
#define D_STATE 16
#define D_INNER 2048
#define DT_RANK 64
#define NTOK (B_SZ * T_LEN)               // 2048 tokens
#define XPROJ_OUT 96
#define XPROJ_LD 128                      // padded leading dim for dbc
#define NCHUNK 32
#define CHUNK_L (T_LEN / NCHUNK)          // 32
#define NSPLIT 16                         // split-K for x_proj

typedef __attribute__((ext_vector_type(8))) short bf16x8;
typedef __attribute__((ext_vector_type(4))) float f32x4;

__device__ __forceinline__ float sigmoidf_(float x) { return 1.f / (1.f + __expf(-x)); }

__device__ __forceinline__ unsigned f2bf_u(float f) {  // RNE f32->bf16 bits
    unsigned u = __float_as_uint(f);
    return (u + 0x7FFFu + ((u >> 16) & 1u)) >> 16;
}

__device__ __forceinline__ void gload_lds16(const void* g, void* l) {
    __builtin_amdgcn_global_load_lds((const __attribute__((address_space(1))) unsigned*)g,
                                     (__attribute__((address_space(3))) unsigned*)l,
                                     16, 0, 0);
}

// ---------------- f32 -> bf16 cast (8 elems/thread) ----------------
__global__ __launch_bounds__(256) void k_cast(const float* __restrict__ in,
                                              unsigned* __restrict__ out) {
    int idx = blockIdx.x * 256 + threadIdx.x;
    float4 a = ((const float4*)in)[idx * 2];
    float4 b = ((const float4*)in)[idx * 2 + 1];
    uint4 o;
    o.x = f2bf_u(a.x) | (f2bf_u(a.y) << 16);
    o.y = f2bf_u(a.z) | (f2bf_u(a.w) << 16);
    o.z = f2bf_u(b.x) | (f2bf_u(b.y) << 16);
    o.w = f2bf_u(b.z) | (f2bf_u(b.w) << 16);
    ((uint4*)out)[idx] = o;
}

// ---------------- RMSNorm: 2048 rows x 1024, bf16 output ----------------
__global__ __launch_bounds__(256) void k_rmsnorm(const float* __restrict__ x,
                                                 const float* __restrict__ w,
                                                 unsigned short* __restrict__ xn) {
    int row = blockIdx.x;
    const float* xr = x + (size_t)row * D_MODEL;
    int i = threadIdx.x * 4;
    float4 xv = *(const float4*)(xr + i);
    float s = xv.x * xv.x + xv.y * xv.y + xv.z * xv.z + xv.w * xv.w;
#pragma unroll
    for (int m = 1; m <= 32; m <<= 1) s += __shfl_xor(s, m);
    __shared__ float red[4];
    if ((threadIdx.x & 63) == 0) red[threadIdx.x >> 6] = s;
    __syncthreads();
    float tot = red[0] + red[1] + red[2] + red[3];
    float scale = rsqrtf(tot * (1.f / D_MODEL) + 1.1920929e-07f);
    float4 wv = *(const float4*)(w + i);
    uint2 o;
    o.x = f2bf_u(xv.x * scale * wv.x) | (f2bf_u(xv.y * scale * wv.y) << 16);
    o.y = f2bf_u(xv.z * scale * wv.z) | (f2bf_u(xv.w * scale * wv.w) << 16);
    *(uint2*)(xn + (size_t)row * D_MODEL + i) = o;
}

// ---------------- bf16 MFMA GEMM: C(MxN,f32) = A(MxK) * B(NxK)^T ----------------
template <int BN, int CW, int EPI>
__global__ __launch_bounds__(256) void gemm_bf16(const unsigned short* __restrict__ A,
                                                 const unsigned short* __restrict__ B,
                                                 float* __restrict__ C, int ldc, int K,
                                                 const float* __restrict__ res) {
    constexpr int RW = 4 / CW;
    constexpr int MI = (128 / RW) / 16;
    constexpr int NJ = (BN / CW) / 16;
    __shared__ __align__(16) unsigned short As[128 * 32];
    __shared__ __align__(16) unsigned short Bs[BN * 32];
    int tid = threadIdx.x;
    int lane = tid & 63, wv = tid >> 6;
    int wr = wv / CW, wc = wv % CW;
    int lm = lane & 15, q = lane >> 4;
    int m0 = blockIdx.x * 128, n0 = blockIdx.y * BN;
    f32x4 acc[MI][NJ] = {};
    for (int k0 = 0; k0 < K; k0 += 32) {
#pragma unroll
        for (int it = 0; it < 2; ++it) {
            int chunk = it * 256 + tid;
            const unsigned short* g = A + (size_t)(m0 + (chunk >> 2)) * K + k0 + (chunk & 3) * 8;
            char* l = (char*)As + (it * 256 + wv * 64) * 16 + lane * 16;
            gload_lds16(g, l);
        }
#pragma unroll
        for (int it = 0; it < BN / 64; ++it) {
            int chunk = it * 256 + tid;
            const unsigned short* g = B + (size_t)(n0 + (chunk >> 2)) * K + k0 + (chunk & 3) * 8;
            char* l = (char*)Bs + (it * 256 + wv * 64) * 16 + lane * 16;
            gload_lds16(g, l);
        }
        __syncthreads();
        bf16x8 af[MI], bfr[NJ];
#pragma unroll
        for (int i = 0; i < MI; ++i)
            af[i] = *(const bf16x8*)(As + (wr * MI * 16 + i * 16 + lm) * 32 + q * 8);
#pragma unroll
        for (int j = 0; j < NJ; ++j)
            bfr[j] = *(const bf16x8*)(Bs + (wc * NJ * 16 + j * 16 + lm) * 32 + q * 8);
#pragma unroll
        for (int i = 0; i < MI; ++i)
#pragma unroll
            for (int j = 0; j < NJ; ++j)
                acc[i][j] = __builtin_amdgcn_mfma_f32_16x16x32_bf16(af[i], bfr[j], acc[i][j], 0, 0, 0);
        __syncthreads();
    }
#pragma unroll
    for (int i = 0; i < MI; ++i) {
#pragma unroll
        for (int j = 0; j < NJ; ++j) {
#pragma unroll
            for (int r = 0; r < 4; ++r) {
                int row = m0 + wr * MI * 16 + i * 16 + q * 4 + r;
                int col = n0 + wc * NJ * 16 + j * 16 + lm;
                float v = acc[i][j][r];
                if (EPI == 2) v += res[(size_t)row * ldc + col];
                C[(size_t)row * ldc + col] = v;
            }
        }
    }
}

// ---------------- x_proj split-K MFMA GEMM ----------------
__global__ __launch_bounds__(256) void xproj_gemm(const unsigned short* __restrict__ A,
                                                  const unsigned short* __restrict__ B,
                                                  float* __restrict__ part) {
    constexpr int MI = 4, NJ = 4;
    __shared__ __align__(16) unsigned short As[128 * 32];
    __shared__ __align__(16) unsigned short Bs[128 * 32];
    int tid = threadIdx.x;
    int lane = tid & 63, wv = tid >> 6;
    int wr = wv >> 1, wc = wv & 1;
    int lm = lane & 15, q = lane >> 4;
    int m0 = blockIdx.x * 128;
    int kbase = blockIdx.y * (D_INNER / NSPLIT);
    f32x4 acc[MI][NJ] = {};
#pragma unroll
    for (int ki = 0; ki < (D_INNER / NSPLIT) / 32; ++ki) {
        int k0 = kbase + ki * 32;
#pragma unroll
        for (int it = 0; it < 2; ++it) {
            int chunk = it * 256 + tid;
            const unsigned short* g = A + (size_t)(m0 + (chunk >> 2)) * D_INNER + k0 + (chunk & 3) * 8;
            char* l = (char*)As + (it * 256 + wv * 64) * 16 + lane * 16;
            gload_lds16(g, l);
        }
#pragma unroll
        for (int it = 0; it < 2; ++it) {
            int chunk = it * 256 + tid;
            const unsigned short* g = B + (size_t)(chunk >> 2) * D_INNER + k0 + (chunk & 3) * 8;
            char* l = (char*)Bs + (it * 256 + wv * 64) * 16 + lane * 16;
            gload_lds16(g, l);
        }
        __syncthreads();
        bf16x8 af[MI], bfr[NJ];
#pragma unroll
        for (int i = 0; i < MI; ++i)
            af[i] = *(const bf16x8*)(As + (wr * 64 + i * 16 + lm) * 32 + q * 8);
#pragma unroll
        for (int j = 0; j < NJ; ++j)
            bfr[j] = *(const bf16x8*)(Bs + (wc * 64 + j * 16 + lm) * 32 + q * 8);
#pragma unroll
        for (int i = 0; i < MI; ++i)
#pragma unroll
            for (int j = 0; j < NJ; ++j)
                acc[i][j] = __builtin_amdgcn_mfma_f32_16x16x32_bf16(af[i], bfr[j], acc[i][j], 0, 0, 0);
        __syncthreads();
    }
    float* dst = part + (size_t)blockIdx.y * (NTOK * XPROJ_LD);
#pragma unroll
    for (int i = 0; i < MI; ++i)
#pragma unroll
        for (int j = 0; j < NJ; ++j)
#pragma unroll
            for (int r = 0; r < 4; ++r) {
                int row = m0 + wr * 64 + i * 16 + q * 4 + r;
                int col = wc * 64 + j * 16 + lm;
                dst[(size_t)row * XPROJ_LD + col] = acc[i][j][r];
            }
}

// ---------------- reduce split-K partials ----------------
__global__ __launch_bounds__(256) void k_xred(const float* __restrict__ part,
                                              float* __restrict__ dbc) {
    int idx = blockIdx.x * 256 + threadIdx.x;
    float s = 0.f;
#pragma unroll
    for (int sp = 0; sp < NSPLIT; ++sp) s += part[(size_t)sp * (NTOK * XPROJ_LD) + idx];
    dbc[idx] = s;
}

// ---------------- f32 tiled GEMM (dt_proj): softplus(A*B^T + bias) ----------------
__global__ __launch_bounds__(256) void gemm_nt_sp(const float* __restrict__ A, int lda,
                                                  const float* __restrict__ B, int ldb,
                                                  float* __restrict__ C, int ldc, int K,
                                                  const float* __restrict__ bias) {
    constexpr int BM = 64, BN = 64, BK = 16, TM = 4, TN = 4;
    __shared__ float As[BK][BM];
    __shared__ float Bs[BK][BN];
    int tid = threadIdx.x;
    int tx = tid & 15, ty = tid >> 4;
    int m0 = blockIdx.x * BM, n0 = blockIdx.y * BN;
    float acc[TM][TN] = {};
    for (int k0 = 0; k0 < K; k0 += BK) {
#pragma unroll
        for (int i = 0; i < 4; ++i) {
            int idx = tid + i * 256;
            As[idx & 15][idx >> 4] = A[(size_t)(m0 + (idx >> 4)) * lda + k0 + (idx & 15)];
        }
#pragma unroll
        for (int i = 0; i < 4; ++i) {
            int idx = tid + i * 256;
            Bs[idx & 15][idx >> 4] = B[(size_t)(n0 + (idx >> 4)) * ldb + k0 + (idx & 15)];
        }
        __syncthreads();
#pragma unroll
        for (int k = 0; k < BK; ++k) {
            float4 av = *(const float4*)&As[k][ty * TM];
            float4 bv = *(const float4*)&Bs[k][tx * TN];
            float a[TM] = {av.x, av.y, av.z, av.w};
            float b[TN] = {bv.x, bv.y, bv.z, bv.w};
#pragma unroll
            for (int i = 0; i < TM; ++i)
#pragma unroll
                for (int j = 0; j < TN; ++j) acc[i][j] = fmaf(a[i], b[j], acc[i][j]);
        }
        __syncthreads();
    }
#pragma unroll
    for (int i = 0; i < TM; ++i) {
        int m = m0 + ty * TM + i;
#pragma unroll
        for (int j = 0; j < TN; ++j) {
            int n = n0 + tx * TN + j;
            float v = acc[i][j] + bias[n];
            v = (v > 20.f) ? v : log1pf(__expf(v));
            C[(size_t)m * ldc + n] = v;
        }
    }
}

// ---------------- depthwise causal conv (k=4) + SiLU; emits f32 u and bf16 ub ----------------
__global__ __launch_bounds__(256) void k_conv(const float* __restrict__ xz,
                                              const float* __restrict__ cw,
                                              const float* __restrict__ cb,
                                              float* __restrict__ u,
                                              unsigned short* __restrict__ ub) {
    int idx = blockIdx.x * 256 + threadIdx.x;
    int c = idx & (D_INNER - 1);
    int t = (idx >> 11) & (T_LEN - 1);
    int b = idx >> 21;
    const float* xs = xz + (size_t)b * T_LEN * 2 * D_INNER + c;
    float4 wv = *(const float4*)(cw + c * 4);
    float s = cb[c];
    if (t >= 3) s = fmaf(xs[(size_t)(t - 3) * 2 * D_INNER], wv.x, s);
    if (t >= 2) s = fmaf(xs[(size_t)(t - 2) * 2 * D_INNER], wv.y, s);
    if (t >= 1) s = fmaf(xs[(size_t)(t - 1) * 2 * D_INNER], wv.z, s);
    s = fmaf(xs[(size_t)t * 2 * D_INNER], wv.w, s);
    float v = s * sigmoidf_(s);
    u[idx] = v;
    ub[idx] = (unsigned short)f2bf_u(v);
}

// ---------------- chunked selective scan, lane-per-channel ----------------
// block = 256 threads = 256 channels for one (b, chunk); 16 states in registers.
// grid (D_INNER/256 = 8, B_SZ*NCHUNK = 64).
// Pass 1: local scan from h=0; P = exp(A_s * sum(delta)) [= prod exp(delta*A), exact].
__global__ __launch_bounds__(256) void k_scan1(const float* __restrict__ delta,
                                               const float* __restrict__ u,
                                               const float* __restrict__ dbc,
                                               const float* __restrict__ A_log,
                                               float* __restrict__ Pbuf,
                                               float* __restrict__ Hbuf) {
    int tid = threadIdx.x;
    int c = blockIdx.x * 256 + tid;
    int b = blockIdx.y >> 5, chunk = blockIdx.y & 31;
    int t0 = chunk * CHUNK_L;
    __shared__ float bc[CHUNK_L][32];  // [t][0:16]=B, [t][16:32]=C
    {
        int t = tid >> 3, col = (tid & 7) * 4;
        const float* src = dbc + ((size_t)b * T_LEN + t0 + t) * XPROJ_LD + DT_RANK + col;
        *(float4*)&bc[t][col] = *(const float4*)src;
    }
    __syncthreads();
    float A[16];
#pragma unroll
    for (int s4 = 0; s4 < 4; ++s4) {
        float4 av = *(const float4*)(A_log + (size_t)c * D_STATE + s4 * 4);
        A[s4 * 4 + 0] = -__expf(av.x);
        A[s4 * 4 + 1] = -__expf(av.y);
        A[s4 * 4 + 2] = -__expf(av.z);
        A[s4 * 4 + 3] = -__expf(av.w);
    }
    const float* dp = delta + ((size_t)b * T_LEN + t0) * D_INNER + c;
    const float* up = u + ((size_t)b * T_LEN + t0) * D_INNER + c;
    float h[16] = {};
    float sumd = 0.f;
#pragma unroll 4
    for (int t = 0; t < CHUNK_L; ++t) {
        float dv = dp[(size_t)t * D_INNER];
        float uv = up[(size_t)t * D_INNER];
        float du = dv * uv;
        sumd += dv;
#pragma unroll
        for (int s = 0; s < 16; ++s) {
            float da = __expf(dv * A[s]);
            h[s] = fmaf(da, h[s], du * bc[t][s]);
        }
    }
    size_t o = ((size_t)((b * NCHUNK + chunk) * D_INNER) + c) * 16;
#pragma unroll
    for (int s4 = 0; s4 < 4; ++s4) {
        float4 hv = {h[s4 * 4], h[s4 * 4 + 1], h[s4 * 4 + 2], h[s4 * 4 + 3]};
        *(float4*)(Hbuf + o + s4 * 4) = hv;
        float4 pv = {__expf(A[s4 * 4] * sumd), __expf(A[s4 * 4 + 1] * sumd),
                     __expf(A[s4 * 4 + 2] * sumd), __expf(A[s4 * 4 + 3] * sumd)};
        *(float4*)(Pbuf + o + s4 * 4) = pv;
    }
}

// Pass 2: sequential over NCHUNK chunk summaries; Hbuf becomes h_start per chunk.
__global__ __launch_bounds__(256) void k_scan2(const float* __restrict__ Pbuf,
                                               float* __restrict__ Hbuf) {
    int idx = blockIdx.x * 256 + threadIdx.x;  // 0..65535 = (b, c*16+s)
    int b = idx >> 15, r = idx & 32767;
    size_t base = (size_t)b * NCHUNK * (D_INNER * 16) + r;
    float h = 0.f;
#pragma unroll
    for (int ch = 0; ch < NCHUNK; ++ch) {
        size_t o = base + (size_t)ch * (D_INNER * 16);
        float hl = Hbuf[o];
        float P = Pbuf[o];
        Hbuf[o] = h;
        h = fmaf(P, h, hl);
    }
}

// Pass 3: redo recurrence from exact h_start; fuse C-proj, D*u, silu(z); emit bf16 y.
__global__ __launch_bounds__(256) void k_scan3(const float* __restrict__ delta,
                                               const float* __restrict__ u,
                                               const float* __restrict__ dbc,
                                               const float* __restrict__ xz,
                                               const float* __restrict__ A_log,
                                               const float* __restrict__ Dp,
                                               const float* __restrict__ Hbuf,
                                               unsigned short* __restrict__ yb) {
    int tid = threadIdx.x;
    int c = blockIdx.x * 256 + tid;
    int b = blockIdx.y >> 5, chunk = blockIdx.y & 31;
    int t0 = chunk * CHUNK_L;
    __shared__ float bc[CHUNK_L][32];
    {
        int t = tid >> 3, col = (tid & 7) * 4;
        const float* src = dbc + ((size_t)b * T_LEN + t0 + t) * XPROJ_LD + DT_RANK + col;
        *(float4*)&bc[t][col] = *(const float4*)src;
    }
    __syncthreads();
    float A[16];
#pragma unroll
    for (int s4 = 0; s4 < 4; ++s4) {
        float4 av = *(const float4*)(A_log + (size_t)c * D_STATE + s4 * 4);
        A[s4 * 4 + 0] = -__expf(av.x);
        A[s4 * 4 + 1] = -__expf(av.y);
        A[s4 * 4 + 2] = -__expf(av.z);
        A[s4 * 4 + 3] = -__expf(av.w);
    }
    float Dc = Dp[c];
    float h[16];
    size_t ho = ((size_t)((b * NCHUNK + chunk) * D_INNER) + c) * 16;
#pragma unroll
    for (int s4 = 0; s4 < 4; ++s4) {
        float4 hv = *(const float4*)(Hbuf + ho + s4 * 4);
        h[s4 * 4] = hv.x; h[s4 * 4 + 1] = hv.y; h[s4 * 4 + 2] = hv.z; h[s4 * 4 + 3] = hv.w;
    }
    const float* dp = delta + ((size_t)b * T_LEN + t0) * D_INNER + c;
    const float* up = u + ((size_t)b * T_LEN + t0) * D_INNER + c;
    const float* zp = xz + ((size_t)b * T_LEN + t0) * 2 * D_INNER + D_INNER + c;
    unsigned short* yp = yb + ((size_t)b * T_LEN + t0) * D_INNER + c;
#pragma unroll 2
    for (int t = 0; t < CHUNK_L; ++t) {
        float dv = dp[(size_t)t * D_INNER];
        float uv = up[(size_t)t * D_INNER];
        float zv = zp[(size_t)t * 2 * D_INNER];
        float du = dv * uv;
        float y = Dc * uv;
#pragma unroll
        for (int s = 0; s < 16; ++s) {
            float da = __expf(dv * A[s]);
            h[s] = fmaf(da, h[s], du * bc[t][s]);
            y = fmaf(h[s], bc[t][16 + s], y);
        }
        float sz = zv * sigmoidf_(zv);
        yp[(size_t)t * D_INNER] = (unsigned short)f2bf_u(y * sz);
    }
}

extern "C" void kernel_launch(void* const* d_in, const int* in_sizes, int n_in,
                              void* d_out, int out_size, void* d_ws, size_t ws_size,
                              hipStream_t stream) {
    const float* x         = (const float*)d_in[0];
    const float* norm_w    = (const float*)d_in[1];
    const float* in_proj_w = (const float*)d_in[2];
    const float* conv_w    = (const float*)d_in[3];
    const float* conv_b    = (const float*)d_in[4];
    const float* x_proj_w  = (const float*)d_in[5];
    const float* dt_proj_w = (const float*)d_in[6];
    const float* dt_proj_b = (const float*)d_in[7];
    const float* A_log     = (const float*)d_in[8];
    const float* D_param   = (const float*)d_in[9];
    const float* out_proj_w= (const float*)d_in[10];
    float* out = (float*)d_out;

    // workspace layout (float units), liveness overlaps; total 24,510,464 f = 98.0 MB
    float* ws = (float*)d_ws;
    float*          xz    = ws;                    // 2048*4096
    float*          u     = ws + 8388608;          // 2048*2048
    float*          delta = ws + 12582912;         // 2048*2048
    float*          part  = delta;                 // 16*2048*128 (dead before delta written)
    float*          dbc   = ws + 16777216;         // 2048*128 -> ends 17039360
    unsigned short* xnb   = (unsigned short*)(ws + 17039360); // 2048*1024 bf16 (dead after step 2)
    float*          Hbuf  = ws + 17039360;         // 131072*16 (overlaps dead xnb) -> 19136512
    unsigned short* wob   = (unsigned short*)(ws + 19136512); // 1024*2048 bf16 -> 20185088
    unsigned short* wxb   = (unsigned short*)(ws + 20185088); // 128*2048 bf16 -> 20316160
    unsigned short* ub    = (unsigned short*)(ws + 20316160); // 2048*2048 bf16 (dead after step 4)
    unsigned short* yb    = ub;                    // scan3 writes after ub consumed
    unsigned short* wib   = (unsigned short*)(ws + 22413312); // 4096*1024 bf16 (dead after step 2)
    float*          Pbuf  = ws + 22413312;         // 131072*16 (overlaps dead wib) -> 24510464

    // 0. weight casts f32 -> bf16 (+ zero the wxb pad rows 96..127)
    k_cast<<<(4096 * 1024) / 2048, 256, 0, stream>>>(in_proj_w, (unsigned*)wib);
    k_cast<<<(1024 * 2048) / 2048, 256, 0, stream>>>(out_proj_w, (unsigned*)wob);
    k_cast<<<(96 * 2048) / 2048, 256, 0, stream>>>(x_proj_w, (unsigned*)wxb);
    hipMemsetAsync(wxb + 96 * 2048, 0, 32 * 2048 * sizeof(unsigned short), stream);

    // 1. RMSNorm -> bf16
    k_rmsnorm<<<NTOK, 256, 0, stream>>>(x, norm_w, xnb);
    // 2. xz = xn @ in_proj_w^T  (2048 x 4096 x 1024), MFMA bf16
    gemm_bf16<128, 2, 0><<<dim3(NTOK / 128, 4096 / 128), 256, 0, stream>>>(
        xnb, wib, xz, 2 * D_INNER, D_MODEL, nullptr);
    // 3. depthwise conv + SiLU -> u (f32) + ub (bf16)
    k_conv<<<(NTOK * D_INNER) / 256, 256, 0, stream>>>(xz, conv_w, conv_b, u, ub);
    // 4. x_dbc: split-K MFMA GEMM + reduce  (2048 x 128 x 2048)
    xproj_gemm<<<dim3(NTOK / 128, NSPLIT), 256, 0, stream>>>(ub, wxb, part);
    k_xred<<<(NTOK * XPROJ_LD) / 256, 256, 0, stream>>>(part, dbc);
    // 5. delta = softplus(dt_raw @ dt_proj_w^T + b)  (2048 x 2048 x 64), f32
    gemm_nt_sp<<<dim3(NTOK / 64, D_INNER / 64), 256, 0, stream>>>(
        dbc, XPROJ_LD, dt_proj_w, DT_RANK, delta, D_INNER, DT_RANK, dt_proj_b);
    // 6. chunked selective scan (lane-per-channel) -> yb (bf16)
    k_scan1<<<dim3(D_INNER / 256, B_SZ * NCHUNK), 256, 0, stream>>>(delta, u, dbc, A_log, Pbuf, Hbuf);
    k_scan2<<<(B_SZ * D_INNER * D_STATE) / 256, 256, 0, stream>>>(Pbuf, Hbuf);
    k_scan3<<<dim3(D_INNER / 256, B_SZ * NCHUNK), 256, 0, stream>>>(delta, u, dbc, xz, A_log,
                                                                    D_param, Hbuf, yb);
    // 7. out = y @ out_proj_w^T + x  (2048 x 1024 x 2048), MFMA bf16, 128x64 tile
    gemm_bf16<64, 1, 2><<<dim3(NTOK / 128, 1024 / 64), 256, 0, stream>>>(
        yb, wob, out, D_MODEL, D_INNER, x);

    (void)in_sizes; (void)n_in; (void)out_size; (void)ws_size;
}

// Round 6
// 284.122 us; speedup vs baseline: 4.5662x; 1.0167x over previous
//
#include <hip/hip_runtime.h>
#include <math.h>

#define B_SZ 2
#define T_LEN 1024
#define D_MODEL 1024
#define D_STATE 16
#define D_INNER 2048
#define DT_RANK 64
#define NTOK (B_SZ * T_LEN)               // 2048 tokens
#define XPROJ_OUT 96
#define XPROJ_LD 128                      // padded leading dim for dbc
#define NCHUNK 32
#define CHUNK_L (T_LEN / NCHUNK)          // 32
#define NSPLIT 16                         // split-K for x_proj

typedef __attribute__((ext_vector_type(8))) short bf16x8;
typedef __attribute__((ext_vector_type(4))) float f32x4;

__device__ __forceinline__ float sigmoidf_(float x) { return 1.f / (1.f + __expf(-x)); }

__device__ __forceinline__ unsigned f2bf_u(float f) {  // RNE f32->bf16 bits
    unsigned u = __float_as_uint(f);
    return (u + 0x7FFFu + ((u >> 16) & 1u)) >> 16;
}
__device__ __forceinline__ float bf2f(unsigned short u) {
    return __uint_as_float((unsigned)u << 16);
}

__device__ __forceinline__ void gload_lds16(const void* g, void* l) {
    __builtin_amdgcn_global_load_lds((const __attribute__((address_space(1))) unsigned*)g,
                                     (__attribute__((address_space(3))) unsigned*)l,
                                     16, 0, 0);
}

// ---------------- fused weight casts f32 -> bf16 (one launch) ----------------
// segments (2048 bf16 elems per block, 8 per thread):
//   [0,2048)    : in_proj_w  -> wib   (4096x1024)
//   [2048,3072) : out_proj_w -> wob   (1024x2048)
//   [3072,3200) : x_proj_w   -> wxb   (padded 128x2048; rows >=96 zeroed)
//   [3200,3264) : dt_proj_w  -> wdtb  (2048x64)
__global__ __launch_bounds__(256) void k_cast_all(const float* __restrict__ w_in,
                                                  const float* __restrict__ w_out,
                                                  const float* __restrict__ w_x,
                                                  const float* __restrict__ w_dt,
                                                  unsigned* __restrict__ wib,
                                                  unsigned* __restrict__ wob,
                                                  unsigned* __restrict__ wxb,
                                                  unsigned* __restrict__ wdtb) {
    int blk = blockIdx.x;
    const float* src;
    unsigned* dst;
    int lidx;  // index in units of 8 elems
    if (blk < 2048) {
        src = w_in; dst = wib; lidx = blk * 256 + threadIdx.x;
    } else if (blk < 3072) {
        src = w_out; dst = wob; lidx = (blk - 2048) * 256 + threadIdx.x;
    } else if (blk < 3200) {
        dst = wxb; lidx = (blk - 3072) * 256 + threadIdx.x;
        int e = lidx * 8, row = e >> 11, col = e & 2047;
        if (row >= 96) {
            uint4 z = {0, 0, 0, 0};
            ((uint4*)dst)[lidx] = z;
            return;
        }
        src = w_x + ((size_t)row * 2048 + col) - (size_t)lidx * 8;  // so src+lidx*8 = row,col
    } else {
        src = w_dt; dst = wdtb; lidx = (blk - 3200) * 256 + threadIdx.x;
    }
    float4 a = ((const float4*)(src))[lidx * 2];
    float4 b = ((const float4*)(src))[lidx * 2 + 1];
    uint4 o;
    o.x = f2bf_u(a.x) | (f2bf_u(a.y) << 16);
    o.y = f2bf_u(a.z) | (f2bf_u(a.w) << 16);
    o.z = f2bf_u(b.x) | (f2bf_u(b.y) << 16);
    o.w = f2bf_u(b.z) | (f2bf_u(b.w) << 16);
    ((uint4*)dst)[lidx] = o;
}

// ---------------- RMSNorm: 2048 rows x 1024, bf16 output ----------------
__global__ __launch_bounds__(256) void k_rmsnorm(const float* __restrict__ x,
                                                 const float* __restrict__ w,
                                                 unsigned short* __restrict__ xn) {
    int row = blockIdx.x;
    const float* xr = x + (size_t)row * D_MODEL;
    int i = threadIdx.x * 4;
    float4 xv = *(const float4*)(xr + i);
    float s = xv.x * xv.x + xv.y * xv.y + xv.z * xv.z + xv.w * xv.w;
#pragma unroll
    for (int m = 1; m <= 32; m <<= 1) s += __shfl_xor(s, m);
    __shared__ float red[4];
    if ((threadIdx.x & 63) == 0) red[threadIdx.x >> 6] = s;
    __syncthreads();
    float tot = red[0] + red[1] + red[2] + red[3];
    float scale = rsqrtf(tot * (1.f / D_MODEL) + 1.1920929e-07f);
    float4 wv = *(const float4*)(w + i);
    uint2 o;
    o.x = f2bf_u(xv.x * scale * wv.x) | (f2bf_u(xv.y * scale * wv.y) << 16);
    o.y = f2bf_u(xv.z * scale * wv.z) | (f2bf_u(xv.w * scale * wv.w) << 16);
    *(uint2*)(xn + (size_t)row * D_MODEL + i) = o;
}

// ---------------- bf16 MFMA GEMM: C(MxN,f32) = A(MxK) * B(NxK)^T ----------------
// EPI: 0 = none, 1 = softplus(v + res[col]), 2 = v + res[row*ldc+col]
template <int BN, int CW, int EPI>
__global__ __launch_bounds__(256) void gemm_bf16(const unsigned short* __restrict__ A,
                                                 const unsigned short* __restrict__ B,
                                                 float* __restrict__ C, int ldc, int K,
                                                 const float* __restrict__ res) {
    constexpr int RW = 4 / CW;
    constexpr int MI = (128 / RW) / 16;
    constexpr int NJ = (BN / CW) / 16;
    __shared__ __align__(16) unsigned short As[128 * 32];
    __shared__ __align__(16) unsigned short Bs[BN * 32];
    int tid = threadIdx.x;
    int lane = tid & 63, wv = tid >> 6;
    int wr = wv / CW, wc = wv % CW;
    int lm = lane & 15, q = lane >> 4;
    int m0 = blockIdx.x * 128, n0 = blockIdx.y * BN;
    f32x4 acc[MI][NJ] = {};
    for (int k0 = 0; k0 < K; k0 += 32) {
#pragma unroll
        for (int it = 0; it < 2; ++it) {
            int chunk = it * 256 + tid;
            const unsigned short* g = A + (size_t)(m0 + (chunk >> 2)) * K + k0 + (chunk & 3) * 8;
            char* l = (char*)As + (it * 256 + wv * 64) * 16 + lane * 16;
            gload_lds16(g, l);
        }
#pragma unroll
        for (int it = 0; it < BN / 64; ++it) {
            int chunk = it * 256 + tid;
            const unsigned short* g = B + (size_t)(n0 + (chunk >> 2)) * K + k0 + (chunk & 3) * 8;
            char* l = (char*)Bs + (it * 256 + wv * 64) * 16 + lane * 16;
            gload_lds16(g, l);
        }
        __syncthreads();
        bf16x8 af[MI], bfr[NJ];
#pragma unroll
        for (int i = 0; i < MI; ++i)
            af[i] = *(const bf16x8*)(As + (wr * MI * 16 + i * 16 + lm) * 32 + q * 8);
#pragma unroll
        for (int j = 0; j < NJ; ++j)
            bfr[j] = *(const bf16x8*)(Bs + (wc * NJ * 16 + j * 16 + lm) * 32 + q * 8);
#pragma unroll
        for (int i = 0; i < MI; ++i)
#pragma unroll
            for (int j = 0; j < NJ; ++j)
                acc[i][j] = __builtin_amdgcn_mfma_f32_16x16x32_bf16(af[i], bfr[j], acc[i][j], 0, 0, 0);
        __syncthreads();
    }
#pragma unroll
    for (int i = 0; i < MI; ++i) {
#pragma unroll
        for (int j = 0; j < NJ; ++j) {
#pragma unroll
            for (int r = 0; r < 4; ++r) {
                int row = m0 + wr * MI * 16 + i * 16 + q * 4 + r;
                int col = n0 + wc * NJ * 16 + j * 16 + lm;
                float v = acc[i][j][r];
                if (EPI == 1) {
                    v += res[col];
                    v = (v > 20.f) ? v : log1pf(__expf(v));
                } else if (EPI == 2) {
                    v += res[(size_t)row * ldc + col];
                }
                C[(size_t)row * ldc + col] = v;
            }
        }
    }
}

// ---------------- x_proj split-K MFMA GEMM ----------------
__global__ __launch_bounds__(256) void xproj_gemm(const unsigned short* __restrict__ A,
                                                  const unsigned short* __restrict__ B,
                                                  float* __restrict__ part) {
    constexpr int MI = 4, NJ = 4;
    __shared__ __align__(16) unsigned short As[128 * 32];
    __shared__ __align__(16) unsigned short Bs[128 * 32];
    int tid = threadIdx.x;
    int lane = tid & 63, wv = tid >> 6;
    int wr = wv >> 1, wc = wv & 1;
    int lm = lane & 15, q = lane >> 4;
    int m0 = blockIdx.x * 128;
    int kbase = blockIdx.y * (D_INNER / NSPLIT);
    f32x4 acc[MI][NJ] = {};
#pragma unroll
    for (int ki = 0; ki < (D_INNER / NSPLIT) / 32; ++ki) {
        int k0 = kbase + ki * 32;
#pragma unroll
        for (int it = 0; it < 2; ++it) {
            int chunk = it * 256 + tid;
            const unsigned short* g = A + (size_t)(m0 + (chunk >> 2)) * D_INNER + k0 + (chunk & 3) * 8;
            char* l = (char*)As + (it * 256 + wv * 64) * 16 + lane * 16;
            gload_lds16(g, l);
        }
#pragma unroll
        for (int it = 0; it < 2; ++it) {
            int chunk = it * 256 + tid;
            const unsigned short* g = B + (size_t)(chunk >> 2) * D_INNER + k0 + (chunk & 3) * 8;
            char* l = (char*)Bs + (it * 256 + wv * 64) * 16 + lane * 16;
            gload_lds16(g, l);
        }
        __syncthreads();
        bf16x8 af[MI], bfr[NJ];
#pragma unroll
        for (int i = 0; i < MI; ++i)
            af[i] = *(const bf16x8*)(As + (wr * 64 + i * 16 + lm) * 32 + q * 8);
#pragma unroll
        for (int j = 0; j < NJ; ++j)
            bfr[j] = *(const bf16x8*)(Bs + (wc * 64 + j * 16 + lm) * 32 + q * 8);
#pragma unroll
        for (int i = 0; i < MI; ++i)
#pragma unroll
            for (int j = 0; j < NJ; ++j)
                acc[i][j] = __builtin_amdgcn_mfma_f32_16x16x32_bf16(af[i], bfr[j], acc[i][j], 0, 0, 0);
        __syncthreads();
    }
    float* dst = part + (size_t)blockIdx.y * (NTOK * XPROJ_LD);
#pragma unroll
    for (int i = 0; i < MI; ++i)
#pragma unroll
        for (int j = 0; j < NJ; ++j)
#pragma unroll
            for (int r = 0; r < 4; ++r) {
                int row = m0 + wr * 64 + i * 16 + q * 4 + r;
                int col = wc * 64 + j * 16 + lm;
                dst[(size_t)row * XPROJ_LD + col] = acc[i][j][r];
            }
}

// ---------------- reduce split-K partials; also emit dt_raw as bf16 ----------------
__global__ __launch_bounds__(256) void k_xred(const float* __restrict__ part,
                                              float* __restrict__ dbc,
                                              unsigned short* __restrict__ dtrawb) {
    int idx = blockIdx.x * 256 + threadIdx.x;  // 0 .. 2048*128-1
    float s = 0.f;
#pragma unroll
    for (int sp = 0; sp < NSPLIT; ++sp) s += part[(size_t)sp * (NTOK * XPROJ_LD) + idx];
    dbc[idx] = s;
    int col = idx & (XPROJ_LD - 1);
    if (col < DT_RANK) {
        int row = idx >> 7;
        dtrawb[(size_t)row * DT_RANK + col] = (unsigned short)f2bf_u(s);
    }
}

// ---------------- depthwise causal conv (k=4) + SiLU -> ub; silu(z) -> szb ----------------
__global__ __launch_bounds__(256) void k_conv(const float* __restrict__ xz,
                                              const float* __restrict__ cw,
                                              const float* __restrict__ cb,
                                              unsigned short* __restrict__ ub,
                                              unsigned short* __restrict__ szb) {
    int idx = blockIdx.x * 256 + threadIdx.x;
    int c = idx & (D_INNER - 1);
    int t = (idx >> 11) & (T_LEN - 1);
    int b = idx >> 21;
    const float* xs = xz + (size_t)b * T_LEN * 2 * D_INNER + c;
    float4 wv = *(const float4*)(cw + c * 4);
    float s = cb[c];
    if (t >= 3) s = fmaf(xs[(size_t)(t - 3) * 2 * D_INNER], wv.x, s);
    if (t >= 2) s = fmaf(xs[(size_t)(t - 2) * 2 * D_INNER], wv.y, s);
    if (t >= 1) s = fmaf(xs[(size_t)(t - 1) * 2 * D_INNER], wv.z, s);
    s = fmaf(xs[(size_t)t * 2 * D_INNER], wv.w, s);
    float v = s * sigmoidf_(s);
    ub[idx] = (unsigned short)f2bf_u(v);
    float zv = xs[(size_t)t * 2 * D_INNER + D_INNER];
    szb[idx] = (unsigned short)f2bf_u(zv * sigmoidf_(zv));
}

// ---------------- chunked selective scan, lane-per-channel ----------------
// Pass 1: local scan from h=0; P = exp(A_s * sum(delta)).
__global__ __launch_bounds__(256) void k_scan1(const float* __restrict__ delta,
                                               const unsigned short* __restrict__ ub,
                                               const float* __restrict__ dbc,
                                               const float* __restrict__ A_log,
                                               float* __restrict__ Pbuf,
                                               float* __restrict__ Hbuf) {
    int tid = threadIdx.x;
    int c = blockIdx.x * 256 + tid;
    int b = blockIdx.y >> 5, chunk = blockIdx.y & 31;
    int t0 = chunk * CHUNK_L;
    __shared__ float bc[CHUNK_L][32];  // [t][0:16]=B, [t][16:32]=C
    {
        int t = tid >> 3, col = (tid & 7) * 4;
        const float* src = dbc + ((size_t)b * T_LEN + t0 + t) * XPROJ_LD + DT_RANK + col;
        *(float4*)&bc[t][col] = *(const float4*)src;
    }
    __syncthreads();
    float A[16];
#pragma unroll
    for (int s4 = 0; s4 < 4; ++s4) {
        float4 av = *(const float4*)(A_log + (size_t)c * D_STATE + s4 * 4);
        A[s4 * 4 + 0] = -__expf(av.x);
        A[s4 * 4 + 1] = -__expf(av.y);
        A[s4 * 4 + 2] = -__expf(av.z);
        A[s4 * 4 + 3] = -__expf(av.w);
    }
    const float* dp = delta + ((size_t)b * T_LEN + t0) * D_INNER + c;
    const unsigned short* up = ub + ((size_t)b * T_LEN + t0) * D_INNER + c;
    float h[16] = {};
    float sumd = 0.f;
#pragma unroll 4
    for (int t = 0; t < CHUNK_L; ++t) {
        float dv = dp[(size_t)t * D_INNER];
        float uv = bf2f(up[(size_t)t * D_INNER]);
        float du = dv * uv;
        sumd += dv;
#pragma unroll
        for (int s = 0; s < 16; ++s) {
            float da = __expf(dv * A[s]);
            h[s] = fmaf(da, h[s], du * bc[t][s]);
        }
    }
    size_t o = ((size_t)((b * NCHUNK + chunk) * D_INNER) + c) * 16;
#pragma unroll
    for (int s4 = 0; s4 < 4; ++s4) {
        float4 hv = {h[s4 * 4], h[s4 * 4 + 1], h[s4 * 4 + 2], h[s4 * 4 + 3]};
        *(float4*)(Hbuf + o + s4 * 4) = hv;
        float4 pv = {__expf(A[s4 * 4] * sumd), __expf(A[s4 * 4 + 1] * sumd),
                     __expf(A[s4 * 4 + 2] * sumd), __expf(A[s4 * 4 + 3] * sumd)};
        *(float4*)(Pbuf + o + s4 * 4) = pv;
    }
}

// Pass 2: sequential over NCHUNK chunk summaries; Hbuf becomes h_start per chunk.
__global__ __launch_bounds__(256) void k_scan2(const float* __restrict__ Pbuf,
                                               float* __restrict__ Hbuf) {
    int idx = blockIdx.x * 256 + threadIdx.x;  // 0..65535 = (b, c*16+s)
    int b = idx >> 15, r = idx & 32767;
    size_t base = (size_t)b * NCHUNK * (D_INNER * 16) + r;
    float h = 0.f;
#pragma unroll
    for (int ch = 0; ch < NCHUNK; ++ch) {
        size_t o = base + (size_t)ch * (D_INNER * 16);
        float hl = Hbuf[o];
        float P = Pbuf[o];
        Hbuf[o] = h;
        h = fmaf(P, h, hl);
    }
}

// Pass 3: redo recurrence from exact h_start; fuse C-proj, D*u, silu(z); emit bf16 y.
__global__ __launch_bounds__(256) void k_scan3(const float* __restrict__ delta,
                                               const unsigned short* __restrict__ ub,
                                               const float* __restrict__ dbc,
                                               const unsigned short* __restrict__ szb,
                                               const float* __restrict__ A_log,
                                               const float* __restrict__ Dp,
                                               const float* __restrict__ Hbuf,
                                               unsigned short* __restrict__ yb) {
    int tid = threadIdx.x;
    int c = blockIdx.x * 256 + tid;
    int b = blockIdx.y >> 5, chunk = blockIdx.y & 31;
    int t0 = chunk * CHUNK_L;
    __shared__ float bc[CHUNK_L][32];
    {
        int t = tid >> 3, col = (tid & 7) * 4;
        const float* src = dbc + ((size_t)b * T_LEN + t0 + t) * XPROJ_LD + DT_RANK + col;
        *(float4*)&bc[t][col] = *(const float4*)src;
    }
    __syncthreads();
    float A[16];
#pragma unroll
    for (int s4 = 0; s4 < 4; ++s4) {
        float4 av = *(const float4*)(A_log + (size_t)c * D_STATE + s4 * 4);
        A[s4 * 4 + 0] = -__expf(av.x);
        A[s4 * 4 + 1] = -__expf(av.y);
        A[s4 * 4 + 2] = -__expf(av.z);
        A[s4 * 4 + 3] = -__expf(av.w);
    }
    float Dc = Dp[c];
    float h[16];
    size_t ho = ((size_t)((b * NCHUNK + chunk) * D_INNER) + c) * 16;
#pragma unroll
    for (int s4 = 0; s4 < 4; ++s4) {
        float4 hv = *(const float4*)(Hbuf + ho + s4 * 4);
        h[s4 * 4] = hv.x; h[s4 * 4 + 1] = hv.y; h[s4 * 4 + 2] = hv.z; h[s4 * 4 + 3] = hv.w;
    }
    const float* dp = delta + ((size_t)b * T_LEN + t0) * D_INNER + c;
    const unsigned short* up = ub + ((size_t)b * T_LEN + t0) * D_INNER + c;
    const unsigned short* szp = szb + ((size_t)b * T_LEN + t0) * D_INNER + c;
    unsigned short* yp = yb + ((size_t)b * T_LEN + t0) * D_INNER + c;
#pragma unroll 2
    for (int t = 0; t < CHUNK_L; ++t) {
        float dv = dp[(size_t)t * D_INNER];
        float uv = bf2f(up[(size_t)t * D_INNER]);
        float sz = bf2f(szp[(size_t)t * D_INNER]);
        float du = dv * uv;
        float y = Dc * uv;
#pragma unroll
        for (int s = 0; s < 16; ++s) {
            float da = __expf(dv * A[s]);
            h[s] = fmaf(da, h[s], du * bc[t][s]);
            y = fmaf(h[s], bc[t][16 + s], y);
        }
        yp[(size_t)t * D_INNER] = (unsigned short)f2bf_u(y * sz);
    }
}

extern "C" void kernel_launch(void* const* d_in, const int* in_sizes, int n_in,
                              void* d_out, int out_size, void* d_ws, size_t ws_size,
                              hipStream_t stream) {
    const float* x         = (const float*)d_in[0];
    const float* norm_w    = (const float*)d_in[1];
    const float* in_proj_w = (const float*)d_in[2];
    const float* conv_w    = (const float*)d_in[3];
    const float* conv_b    = (const float*)d_in[4];
    const float* x_proj_w  = (const float*)d_in[5];
    const float* dt_proj_w = (const float*)d_in[6];
    const float* dt_proj_b = (const float*)d_in[7];
    const float* A_log     = (const float*)d_in[8];
    const float* D_param   = (const float*)d_in[9];
    const float* out_proj_w= (const float*)d_in[10];
    float* out = (float*)d_out;

    // workspace layout (float units), flat; total 26,738,688 floats = 107.0 MB
    float* ws = (float*)d_ws;
    float*          xz     = ws;                    // 2048*4096
    float*          delta  = ws + 8388608;          // 2048*2048
    float*          part   = delta;                 // 16*2048*128 (dead before delta written)
    float*          dbc    = ws + 12582912;         // 2048*128
    float*          Hbuf   = ws + 12845056;         // 2*32*2048*16
    float*          Pbuf   = ws + 14942208;         // 2*32*2048*16
    unsigned short* wib    = (unsigned short*)(ws + 17039360); // 4096*1024 bf16
    unsigned short* wob    = (unsigned short*)(ws + 19136512); // 1024*2048 bf16
    unsigned short* wxb    = (unsigned short*)(ws + 20185088); // 128*2048 bf16
    unsigned short* wdtb   = (unsigned short*)(ws + 20316160); // 2048*64 bf16
    unsigned short* dtrawb = (unsigned short*)(ws + 20381696); // 2048*64 bf16
    unsigned short* xnb    = (unsigned short*)(ws + 20447232); // 2048*1024 bf16
    unsigned short* ub     = (unsigned short*)(ws + 21495808); // 2048*2048 bf16
    unsigned short* szb    = (unsigned short*)(ws + 23592960); // 2048*2048 bf16
    unsigned short* yb     = (unsigned short*)(ws + 25690112); // 2048*2048 bf16

    // 0. all weight casts f32 -> bf16 in one launch (incl. wxb pad-zero)
    k_cast_all<<<3264, 256, 0, stream>>>(in_proj_w, out_proj_w, x_proj_w, dt_proj_w,
                                         (unsigned*)wib, (unsigned*)wob, (unsigned*)wxb,
                                         (unsigned*)wdtb);
    // 1. RMSNorm -> bf16
    k_rmsnorm<<<NTOK, 256, 0, stream>>>(x, norm_w, xnb);
    // 2. xz = xn @ in_proj_w^T  (2048 x 4096 x 1024), MFMA bf16
    gemm_bf16<128, 2, 0><<<dim3(NTOK / 128, 4096 / 128), 256, 0, stream>>>(
        xnb, wib, xz, 2 * D_INNER, D_MODEL, nullptr);
    // 3. depthwise conv + SiLU -> ub (bf16); silu(z) -> szb (bf16)
    k_conv<<<(NTOK * D_INNER) / 256, 256, 0, stream>>>(xz, conv_w, conv_b, ub, szb);
    // 4. x_dbc: split-K MFMA GEMM + reduce (also emits dt_raw bf16)
    xproj_gemm<<<dim3(NTOK / 128, NSPLIT), 256, 0, stream>>>(ub, wxb, part);
    k_xred<<<(NTOK * XPROJ_LD) / 256, 256, 0, stream>>>(part, dbc, dtrawb);
    // 5. delta = softplus(dt_raw @ dt_proj_w^T + b)  (2048 x 2048 x 64), MFMA bf16
    gemm_bf16<128, 2, 1><<<dim3(NTOK / 128, D_INNER / 128), 256, 0, stream>>>(
        dtrawb, wdtb, delta, D_INNER, DT_RANK, dt_proj_b);
    // 6. chunked selective scan (lane-per-channel) -> yb (bf16)
    k_scan1<<<dim3(D_INNER / 256, B_SZ * NCHUNK), 256, 0, stream>>>(delta, ub, dbc, A_log, Pbuf, Hbuf);
    k_scan2<<<(B_SZ * D_INNER * D_STATE) / 256, 256, 0, stream>>>(Pbuf, Hbuf);
    k_scan3<<<dim3(D_INNER / 256, B_SZ * NCHUNK), 256, 0, stream>>>(delta, ub, dbc, szb, A_log,
                                                                    D_param, Hbuf, yb);
    // 7. out = y @ out_proj_w^T + x  (2048 x 1024 x 2048), MFMA bf16, 128x64 tile
    gemm_bf16<64, 1, 2><<<dim3(NTOK / 128, 1024 / 64), 256, 0, stream>>>(
        yb, wob, out, D_MODEL, D_INNER, x);

    (void)in_sizes; (void)n_in; (void)out_size; (void)ws_size;
}

// Round 7
// 273.533 us; speedup vs baseline: 4.7429x; 1.0387x over previous
//
#include <hip/hip_runtime.h>
#include <math.h>

#define B_SZ 2
#define T_LEN 1024
#define D_MODEL 1024
#define D_STATE 16
#define D_INNER 2048
#define DT_RANK 64
#define NTOK (B_SZ * T_LEN)               // 2048 tokens
#define XPROJ_OUT 96
#define XPROJ_LD 128                      // padded leading dim for dbc
#define NCHUNK 32
#define CHUNK_L (T_LEN / NCHUNK)          // 32
#define NSPLIT 16                         // split-K for x_proj

typedef __attribute__((ext_vector_type(8))) short bf16x8;
typedef __attribute__((ext_vector_type(4))) float f32x4;

__device__ __forceinline__ float sigmoidf_(float x) { return 1.f / (1.f + __expf(-x)); }

__device__ __forceinline__ unsigned f2bf_u(float f) {  // RNE f32->bf16 bits
    unsigned u = __float_as_uint(f);
    return (u + 0x7FFFu + ((u >> 16) & 1u)) >> 16;
}
__device__ __forceinline__ float bf2f(unsigned short u) {
    return __uint_as_float((unsigned)u << 16);
}

__device__ __forceinline__ void gload_lds16(const void* g, void* l) {
    __builtin_amdgcn_global_load_lds((const __attribute__((address_space(1))) unsigned*)g,
                                     (__attribute__((address_space(3))) unsigned*)l,
                                     16, 0, 0);
}

// ---------------- fused prep: RMSNorm + all weight casts, one launch ----------------
// blocks [0,2048): rmsnorm rows; [2048,4096): in_proj cast; [4096,5120): out_proj;
// [5120,5248): x_proj (padded 128 rows); [5248,5312): dt_proj.
__global__ __launch_bounds__(256) void k_prep(const float* __restrict__ x,
                                              const float* __restrict__ norm_w,
                                              const float* __restrict__ w_in,
                                              const float* __restrict__ w_out,
                                              const float* __restrict__ w_x,
                                              const float* __restrict__ w_dt,
                                              unsigned short* __restrict__ xn,
                                              unsigned* __restrict__ wib,
                                              unsigned* __restrict__ wob,
                                              unsigned* __restrict__ wxb,
                                              unsigned* __restrict__ wdtb) {
    __shared__ float red[4];
    int blk = blockIdx.x;
    if (blk < 2048) {  // RMSNorm row
        const float* xr = x + (size_t)blk * D_MODEL;
        int i = threadIdx.x * 4;
        float4 xv = *(const float4*)(xr + i);
        float s = xv.x * xv.x + xv.y * xv.y + xv.z * xv.z + xv.w * xv.w;
#pragma unroll
        for (int m = 1; m <= 32; m <<= 1) s += __shfl_xor(s, m);
        if ((threadIdx.x & 63) == 0) red[threadIdx.x >> 6] = s;
        __syncthreads();
        float tot = red[0] + red[1] + red[2] + red[3];
        float scale = rsqrtf(tot * (1.f / D_MODEL) + 1.1920929e-07f);
        float4 wv = *(const float4*)(norm_w + i);
        uint2 o;
        o.x = f2bf_u(xv.x * scale * wv.x) | (f2bf_u(xv.y * scale * wv.y) << 16);
        o.y = f2bf_u(xv.z * scale * wv.z) | (f2bf_u(xv.w * scale * wv.w) << 16);
        *(uint2*)(xn + (size_t)blk * D_MODEL + i) = o;
        return;
    }
    blk -= 2048;
    const float* src;
    unsigned* dst;
    int lidx;  // index in units of 8 elems
    if (blk < 2048) {
        src = w_in; dst = wib; lidx = blk * 256 + threadIdx.x;
    } else if (blk < 3072) {
        src = w_out; dst = wob; lidx = (blk - 2048) * 256 + threadIdx.x;
    } else if (blk < 3200) {
        dst = wxb; lidx = (blk - 3072) * 256 + threadIdx.x;
        if (lidx * 8 >= 96 * 2048) {  // pad rows 96..127 with zeros
            uint4 z = {0, 0, 0, 0};
            ((uint4*)dst)[lidx] = z;
            return;
        }
        src = w_x;
    } else {
        src = w_dt; dst = wdtb; lidx = (blk - 3200) * 256 + threadIdx.x;
    }
    float4 a = ((const float4*)src)[lidx * 2];
    float4 b = ((const float4*)src)[lidx * 2 + 1];
    uint4 o;
    o.x = f2bf_u(a.x) | (f2bf_u(a.y) << 16);
    o.y = f2bf_u(a.z) | (f2bf_u(a.w) << 16);
    o.z = f2bf_u(b.x) | (f2bf_u(b.y) << 16);
    o.w = f2bf_u(b.z) | (f2bf_u(b.w) << 16);
    ((uint4*)dst)[lidx] = o;
}

// ---------------- bf16 MFMA GEMM: C(MxN) = A(MxK) * B(NxK)^T ----------------
// EPI: 0 = none, 1 = softplus(v + res[col]), 2 = v + res[row*ldc+col]
// BF16OUT: write bf16 (ushort) instead of f32.
template <int BN, int CW, int EPI, bool BF16OUT>
__global__ __launch_bounds__(256) void gemm_bf16(const unsigned short* __restrict__ A,
                                                 const unsigned short* __restrict__ B,
                                                 void* __restrict__ Cv, int ldc, int K,
                                                 const float* __restrict__ res) {
    constexpr int RW = 4 / CW;
    constexpr int MI = (128 / RW) / 16;
    constexpr int NJ = (BN / CW) / 16;
    __shared__ __align__(16) unsigned short As[128 * 32];
    __shared__ __align__(16) unsigned short Bs[BN * 32];
    int tid = threadIdx.x;
    int lane = tid & 63, wv = tid >> 6;
    int wr = wv / CW, wc = wv % CW;
    int lm = lane & 15, q = lane >> 4;
    int m0 = blockIdx.x * 128, n0 = blockIdx.y * BN;
    f32x4 acc[MI][NJ] = {};
    for (int k0 = 0; k0 < K; k0 += 32) {
#pragma unroll
        for (int it = 0; it < 2; ++it) {
            int chunk = it * 256 + tid;
            const unsigned short* g = A + (size_t)(m0 + (chunk >> 2)) * K + k0 + (chunk & 3) * 8;
            char* l = (char*)As + (it * 256 + wv * 64) * 16 + lane * 16;
            gload_lds16(g, l);
        }
#pragma unroll
        for (int it = 0; it < BN / 64; ++it) {
            int chunk = it * 256 + tid;
            const unsigned short* g = B + (size_t)(n0 + (chunk >> 2)) * K + k0 + (chunk & 3) * 8;
            char* l = (char*)Bs + (it * 256 + wv * 64) * 16 + lane * 16;
            gload_lds16(g, l);
        }
        __syncthreads();
        bf16x8 af[MI], bfr[NJ];
#pragma unroll
        for (int i = 0; i < MI; ++i)
            af[i] = *(const bf16x8*)(As + (wr * MI * 16 + i * 16 + lm) * 32 + q * 8);
#pragma unroll
        for (int j = 0; j < NJ; ++j)
            bfr[j] = *(const bf16x8*)(Bs + (wc * NJ * 16 + j * 16 + lm) * 32 + q * 8);
#pragma unroll
        for (int i = 0; i < MI; ++i)
#pragma unroll
            for (int j = 0; j < NJ; ++j)
                acc[i][j] = __builtin_amdgcn_mfma_f32_16x16x32_bf16(af[i], bfr[j], acc[i][j], 0, 0, 0);
        __syncthreads();
    }
#pragma unroll
    for (int i = 0; i < MI; ++i) {
#pragma unroll
        for (int j = 0; j < NJ; ++j) {
#pragma unroll
            for (int r = 0; r < 4; ++r) {
                int row = m0 + wr * MI * 16 + i * 16 + q * 4 + r;
                int col = n0 + wc * NJ * 16 + j * 16 + lm;
                float v = acc[i][j][r];
                if (EPI == 1) {
                    v += res[col];
                    v = (v > 20.f) ? v : log1pf(__expf(v));
                } else if (EPI == 2) {
                    v += res[(size_t)row * ldc + col];
                }
                if (BF16OUT)
                    ((unsigned short*)Cv)[(size_t)row * ldc + col] = (unsigned short)f2bf_u(v);
                else
                    ((float*)Cv)[(size_t)row * ldc + col] = v;
            }
        }
    }
}

// ---------------- x_proj split-K MFMA GEMM -> bf16 partials ----------------
__global__ __launch_bounds__(256) void xproj_gemm(const unsigned short* __restrict__ A,
                                                  const unsigned short* __restrict__ B,
                                                  unsigned short* __restrict__ part) {
    constexpr int MI = 4, NJ = 4;
    __shared__ __align__(16) unsigned short As[128 * 32];
    __shared__ __align__(16) unsigned short Bs[128 * 32];
    int tid = threadIdx.x;
    int lane = tid & 63, wv = tid >> 6;
    int wr = wv >> 1, wc = wv & 1;
    int lm = lane & 15, q = lane >> 4;
    int m0 = blockIdx.x * 128;
    int kbase = blockIdx.y * (D_INNER / NSPLIT);
    f32x4 acc[MI][NJ] = {};
#pragma unroll
    for (int ki = 0; ki < (D_INNER / NSPLIT) / 32; ++ki) {
        int k0 = kbase + ki * 32;
#pragma unroll
        for (int it = 0; it < 2; ++it) {
            int chunk = it * 256 + tid;
            const unsigned short* g = A + (size_t)(m0 + (chunk >> 2)) * D_INNER + k0 + (chunk & 3) * 8;
            char* l = (char*)As + (it * 256 + wv * 64) * 16 + lane * 16;
            gload_lds16(g, l);
        }
#pragma unroll
        for (int it = 0; it < 2; ++it) {
            int chunk = it * 256 + tid;
            const unsigned short* g = B + (size_t)(chunk >> 2) * D_INNER + k0 + (chunk & 3) * 8;
            char* l = (char*)Bs + (it * 256 + wv * 64) * 16 + lane * 16;
            gload_lds16(g, l);
        }
        __syncthreads();
        bf16x8 af[MI], bfr[NJ];
#pragma unroll
        for (int i = 0; i < MI; ++i)
            af[i] = *(const bf16x8*)(As + (wr * 64 + i * 16 + lm) * 32 + q * 8);
#pragma unroll
        for (int j = 0; j < NJ; ++j)
            bfr[j] = *(const bf16x8*)(Bs + (wc * 64 + j * 16 + lm) * 32 + q * 8);
#pragma unroll
        for (int i = 0; i < MI; ++i)
#pragma unroll
            for (int j = 0; j < NJ; ++j)
                acc[i][j] = __builtin_amdgcn_mfma_f32_16x16x32_bf16(af[i], bfr[j], acc[i][j], 0, 0, 0);
        __syncthreads();
    }
    unsigned short* dst = part + (size_t)blockIdx.y * (NTOK * XPROJ_LD);
#pragma unroll
    for (int i = 0; i < MI; ++i)
#pragma unroll
        for (int j = 0; j < NJ; ++j)
#pragma unroll
            for (int r = 0; r < 4; ++r) {
                int row = m0 + wr * 64 + i * 16 + q * 4 + r;
                int col = wc * 64 + j * 16 + lm;
                dst[(size_t)row * XPROJ_LD + col] = (unsigned short)f2bf_u(acc[i][j][r]);
            }
}

// ---------------- reduce split-K partials; emit dbc f32 + dt_raw bf16 ----------------
__global__ __launch_bounds__(256) void k_xred(const unsigned short* __restrict__ part,
                                              float* __restrict__ dbc,
                                              unsigned short* __restrict__ dtrawb) {
    int idx = blockIdx.x * 256 + threadIdx.x;  // 0 .. 2048*128-1
    float s = 0.f;
#pragma unroll
    for (int sp = 0; sp < NSPLIT; ++sp) s += bf2f(part[(size_t)sp * (NTOK * XPROJ_LD) + idx]);
    dbc[idx] = s;
    int col = idx & (XPROJ_LD - 1);
    if (col < DT_RANK) {
        int row = idx >> 7;
        dtrawb[(size_t)row * DT_RANK + col] = (unsigned short)f2bf_u(s);
    }
}

// ---------------- depthwise causal conv (k=4, bf16 in) + SiLU -> ub; silu(z) -> szb ----------------
__global__ __launch_bounds__(256) void k_conv(const unsigned short* __restrict__ xz,
                                              const float* __restrict__ cw,
                                              const float* __restrict__ cb,
                                              unsigned short* __restrict__ ub,
                                              unsigned short* __restrict__ szb) {
    int idx = blockIdx.x * 256 + threadIdx.x;
    int c = idx & (D_INNER - 1);
    int t = (idx >> 11) & (T_LEN - 1);
    int b = idx >> 21;
    const unsigned short* xs = xz + (size_t)b * T_LEN * 2 * D_INNER + c;
    float4 wv = *(const float4*)(cw + c * 4);
    float s = cb[c];
    if (t >= 3) s = fmaf(bf2f(xs[(size_t)(t - 3) * 2 * D_INNER]), wv.x, s);
    if (t >= 2) s = fmaf(bf2f(xs[(size_t)(t - 2) * 2 * D_INNER]), wv.y, s);
    if (t >= 1) s = fmaf(bf2f(xs[(size_t)(t - 1) * 2 * D_INNER]), wv.z, s);
    s = fmaf(bf2f(xs[(size_t)t * 2 * D_INNER]), wv.w, s);
    float v = s * sigmoidf_(s);
    ub[idx] = (unsigned short)f2bf_u(v);
    float zv = bf2f(xs[(size_t)t * 2 * D_INNER + D_INNER]);
    szb[idx] = (unsigned short)f2bf_u(zv * sigmoidf_(zv));
}

// ---------------- chunked selective scan, lane-per-channel ----------------
// Pass 1: local scan from h=0; P = exp(A_s * sum(delta)).
__global__ __launch_bounds__(256) void k_scan1(const unsigned short* __restrict__ delta,
                                               const unsigned short* __restrict__ ub,
                                               const float* __restrict__ dbc,
                                               const float* __restrict__ A_log,
                                               float* __restrict__ Pbuf,
                                               float* __restrict__ Hbuf) {
    int tid = threadIdx.x;
    int c = blockIdx.x * 256 + tid;
    int b = blockIdx.y >> 5, chunk = blockIdx.y & 31;
    int t0 = chunk * CHUNK_L;
    __shared__ float bc[CHUNK_L][32];  // [t][0:16]=B, [t][16:32]=C
    {
        int t = tid >> 3, col = (tid & 7) * 4;
        const float* src = dbc + ((size_t)b * T_LEN + t0 + t) * XPROJ_LD + DT_RANK + col;
        *(float4*)&bc[t][col] = *(const float4*)src;
    }
    __syncthreads();
    float A[16];
#pragma unroll
    for (int s4 = 0; s4 < 4; ++s4) {
        float4 av = *(const float4*)(A_log + (size_t)c * D_STATE + s4 * 4);
        A[s4 * 4 + 0] = -__expf(av.x);
        A[s4 * 4 + 1] = -__expf(av.y);
        A[s4 * 4 + 2] = -__expf(av.z);
        A[s4 * 4 + 3] = -__expf(av.w);
    }
    const unsigned short* dp = delta + ((size_t)b * T_LEN + t0) * D_INNER + c;
    const unsigned short* up = ub + ((size_t)b * T_LEN + t0) * D_INNER + c;
    float h[16] = {};
    float sumd = 0.f;
#pragma unroll 4
    for (int t = 0; t < CHUNK_L; ++t) {
        float dv = bf2f(dp[(size_t)t * D_INNER]);
        float uv = bf2f(up[(size_t)t * D_INNER]);
        float du = dv * uv;
        sumd += dv;
#pragma unroll
        for (int s = 0; s < 16; ++s) {
            float da = __expf(dv * A[s]);
            h[s] = fmaf(da, h[s], du * bc[t][s]);
        }
    }
    size_t o = ((size_t)((b * NCHUNK + chunk) * D_INNER) + c) * 16;
#pragma unroll
    for (int s4 = 0; s4 < 4; ++s4) {
        float4 hv = {h[s4 * 4], h[s4 * 4 + 1], h[s4 * 4 + 2], h[s4 * 4 + 3]};
        *(float4*)(Hbuf + o + s4 * 4) = hv;
        float4 pv = {__expf(A[s4 * 4] * sumd), __expf(A[s4 * 4 + 1] * sumd),
                     __expf(A[s4 * 4 + 2] * sumd), __expf(A[s4 * 4 + 3] * sumd)};
        *(float4*)(Pbuf + o + s4 * 4) = pv;
    }
}

// Pass 2: register-pipelined chunk-summary scan; writes h_start to Sbuf.
__global__ __launch_bounds__(256) void k_scan2(const float* __restrict__ Pbuf,
                                               const float* __restrict__ Hbuf,
                                               float* __restrict__ Sbuf) {
    int idx = blockIdx.x * 256 + threadIdx.x;  // 0..65535 = (b, c*16+s)
    int b = idx >> 15, r = idx & 32767;
    size_t base = (size_t)b * NCHUNK * (D_INNER * 16) + r;
    float p[NCHUNK], hl[NCHUNK];
#pragma unroll
    for (int ch = 0; ch < NCHUNK; ++ch) {
        size_t o = base + (size_t)ch * (D_INNER * 16);
        p[ch] = Pbuf[o];
        hl[ch] = Hbuf[o];
    }
    float h = 0.f;
#pragma unroll
    for (int ch = 0; ch < NCHUNK; ++ch) {
        Sbuf[base + (size_t)ch * (D_INNER * 16)] = h;
        h = fmaf(p[ch], h, hl[ch]);
    }
}

// Pass 3: redo recurrence from exact h_start; fuse C-proj, D*u, silu(z); emit bf16 y.
__global__ __launch_bounds__(256) void k_scan3(const unsigned short* __restrict__ delta,
                                               const unsigned short* __restrict__ ub,
                                               const float* __restrict__ dbc,
                                               const unsigned short* __restrict__ szb,
                                               const float* __restrict__ A_log,
                                               const float* __restrict__ Dp,
                                               const float* __restrict__ Sbuf,
                                               unsigned short* __restrict__ yb) {
    int tid = threadIdx.x;
    int c = blockIdx.x * 256 + tid;
    int b = blockIdx.y >> 5, chunk = blockIdx.y & 31;
    int t0 = chunk * CHUNK_L;
    __shared__ float bc[CHUNK_L][32];
    {
        int t = tid >> 3, col = (tid & 7) * 4;
        const float* src = dbc + ((size_t)b * T_LEN + t0 + t) * XPROJ_LD + DT_RANK + col;
        *(float4*)&bc[t][col] = *(const float4*)src;
    }
    __syncthreads();
    float A[16];
#pragma unroll
    for (int s4 = 0; s4 < 4; ++s4) {
        float4 av = *(const float4*)(A_log + (size_t)c * D_STATE + s4 * 4);
        A[s4 * 4 + 0] = -__expf(av.x);
        A[s4 * 4 + 1] = -__expf(av.y);
        A[s4 * 4 + 2] = -__expf(av.z);
        A[s4 * 4 + 3] = -__expf(av.w);
    }
    float Dc = Dp[c];
    float h[16];
    size_t ho = ((size_t)((b * NCHUNK + chunk) * D_INNER) + c) * 16;
#pragma unroll
    for (int s4 = 0; s4 < 4; ++s4) {
        float4 hv = *(const float4*)(Sbuf + ho + s4 * 4);
        h[s4 * 4] = hv.x; h[s4 * 4 + 1] = hv.y; h[s4 * 4 + 2] = hv.z; h[s4 * 4 + 3] = hv.w;
    }
    const unsigned short* dp = delta + ((size_t)b * T_LEN + t0) * D_INNER + c;
    const unsigned short* up = ub + ((size_t)b * T_LEN + t0) * D_INNER + c;
    const unsigned short* szp = szb + ((size_t)b * T_LEN + t0) * D_INNER + c;
    unsigned short* yp = yb + ((size_t)b * T_LEN + t0) * D_INNER + c;
#pragma unroll 2
    for (int t = 0; t < CHUNK_L; ++t) {
        float dv = bf2f(dp[(size_t)t * D_INNER]);
        float uv = bf2f(up[(size_t)t * D_INNER]);
        float sz = bf2f(szp[(size_t)t * D_INNER]);
        float du = dv * uv;
        float y = Dc * uv;
#pragma unroll
        for (int s = 0; s < 16; ++s) {
            float da = __expf(dv * A[s]);
            h[s] = fmaf(da, h[s], du * bc[t][s]);
            y = fmaf(h[s], bc[t][16 + s], y);
        }
        yp[(size_t)t * D_INNER] = (unsigned short)f2bf_u(y * sz);
    }
}

extern "C" void kernel_launch(void* const* d_in, const int* in_sizes, int n_in,
                              void* d_out, int out_size, void* d_ws, size_t ws_size,
                              hipStream_t stream) {
    const float* x         = (const float*)d_in[0];
    const float* norm_w    = (const float*)d_in[1];
    const float* in_proj_w = (const float*)d_in[2];
    const float* conv_w    = (const float*)d_in[3];
    const float* conv_b    = (const float*)d_in[4];
    const float* x_proj_w  = (const float*)d_in[5];
    const float* dt_proj_w = (const float*)d_in[6];
    const float* dt_proj_b = (const float*)d_in[7];
    const float* A_log     = (const float*)d_in[8];
    const float* D_param   = (const float*)d_in[9];
    const float* out_proj_w= (const float*)d_in[10];
    float* out = (float*)d_out;

    // workspace layout (float units), flat; total 25,690,112 floats = 102.8 MB
    float* ws = (float*)d_ws;
    unsigned short* xzb    = (unsigned short*)(ws);            // 2048*4096 bf16
    unsigned short* ub     = (unsigned short*)(ws + 4194304);  // 2048*2048 bf16
    unsigned short* szb    = (unsigned short*)(ws + 6291456);  // 2048*2048 bf16
    unsigned short* yb     = (unsigned short*)(ws + 8388608);  // 2048*2048 bf16
    unsigned short* partb  = (unsigned short*)(ws + 10485760); // 16*2048*128 bf16
    float*          dbc    = ws + 12582912;                    // 2048*128 f32
    unsigned short* deltab = (unsigned short*)(ws + 12845056); // 2048*2048 bf16
    float*          Pbuf   = ws + 14942208;                    // 2*32*2048*16 f32
    float*          Hbuf   = ws + 17039360;                    // 2*32*2048*16 f32
    float*          Sbuf   = ws + 19136512;                    // 2*32*2048*16 f32
    unsigned short* wib    = (unsigned short*)(ws + 21233664); // 4096*1024 bf16
    unsigned short* wob    = (unsigned short*)(ws + 23330816); // 1024*2048 bf16
    unsigned short* wxb    = (unsigned short*)(ws + 24379392); // 128*2048 bf16
    unsigned short* wdtb   = (unsigned short*)(ws + 24510464); // 2048*64 bf16
    unsigned short* dtrawb = (unsigned short*)(ws + 24576000); // 2048*64 bf16
    unsigned short* xnb    = (unsigned short*)(ws + 24641536); // 2048*1024 bf16

    // 0. fused RMSNorm + all weight casts (one launch)
    k_prep<<<5312, 256, 0, stream>>>(x, norm_w, in_proj_w, out_proj_w, x_proj_w, dt_proj_w,
                                     xnb, (unsigned*)wib, (unsigned*)wob, (unsigned*)wxb,
                                     (unsigned*)wdtb);
    // 1. xz = xn @ in_proj_w^T  (2048 x 4096 x 1024), MFMA bf16 -> bf16
    gemm_bf16<128, 2, 0, true><<<dim3(NTOK / 128, 4096 / 128), 256, 0, stream>>>(
        xnb, wib, xzb, 2 * D_INNER, D_MODEL, nullptr);
    // 2. depthwise conv + SiLU -> ub; silu(z) -> szb
    k_conv<<<(NTOK * D_INNER) / 256, 256, 0, stream>>>(xzb, conv_w, conv_b, ub, szb);
    // 3. x_dbc: split-K MFMA GEMM (bf16 partials) + reduce
    xproj_gemm<<<dim3(NTOK / 128, NSPLIT), 256, 0, stream>>>(ub, wxb, partb);
    k_xred<<<(NTOK * XPROJ_LD) / 256, 256, 0, stream>>>(partb, dbc, dtrawb);
    // 4. delta = softplus(dt_raw @ dt_proj_w^T + b) -> bf16  (2048 x 2048 x 64)
    gemm_bf16<128, 2, 1, true><<<dim3(NTOK / 128, D_INNER / 128), 256, 0, stream>>>(
        dtrawb, wdtb, deltab, D_INNER, DT_RANK, dt_proj_b);
    // 5. chunked selective scan -> yb (bf16)
    k_scan1<<<dim3(D_INNER / 256, B_SZ * NCHUNK), 256, 0, stream>>>(deltab, ub, dbc, A_log,
                                                                    Pbuf, Hbuf);
    k_scan2<<<(B_SZ * D_INNER * D_STATE) / 256, 256, 0, stream>>>(Pbuf, Hbuf, Sbuf);
    k_scan3<<<dim3(D_INNER / 256, B_SZ * NCHUNK), 256, 0, stream>>>(deltab, ub, dbc, szb, A_log,
                                                                    D_param, Sbuf, yb);
    // 6. out = y @ out_proj_w^T + x  (2048 x 1024 x 2048), MFMA bf16, f32 out
    gemm_bf16<64, 1, 2, false><<<dim3(NTOK / 128, 1024 / 64), 256, 0, stream>>>(
        yb, wob, out, D_MODEL, D_INNER, x);

    (void)in_sizes; (void)n_in; (void)out_size; (void)ws_size;
}

// Round 8
// 269.331 us; speedup vs baseline: 4.8169x; 1.0156x over previous
//
#include <hip/hip_runtime.h>
#include <math.h>

#define B_SZ 2
#define T_LEN 1024
#define D_MODEL 1024
#define D_STATE 16
#define D_INNER 2048
#define DT_RANK 64
#define NTOK (B_SZ * T_LEN)               // 2048 tokens
#define XPROJ_OUT 96
#define XPROJ_LD 128                      // padded leading dim for dbc
#define NCHUNK 32
#define CHUNK_L (T_LEN / NCHUNK)          // 32
#define NSPLIT 16                         // split-K for x_proj

typedef __attribute__((ext_vector_type(8))) short bf16x8;
typedef __attribute__((ext_vector_type(4))) float f32x4;

__device__ __forceinline__ float sigmoidf_(float x) { return 1.f / (1.f + __expf(-x)); }

__device__ __forceinline__ unsigned f2bf_u(float f) {  // RNE f32->bf16 bits
    unsigned u = __float_as_uint(f);
    return (u + 0x7FFFu + ((u >> 16) & 1u)) >> 16;
}
__device__ __forceinline__ float bf2f(unsigned short u) {
    return __uint_as_float((unsigned)u << 16);
}

__device__ __forceinline__ void gload_lds16(const void* g, void* l) {
    __builtin_amdgcn_global_load_lds((const __attribute__((address_space(1))) unsigned*)g,
                                     (__attribute__((address_space(3))) unsigned*)l,
                                     16, 0, 0);
}

// ---------------- fused prep: RMSNorm + all weight casts, one launch ----------------
__global__ __launch_bounds__(256) void k_prep(const float* __restrict__ x,
                                              const float* __restrict__ norm_w,
                                              const float* __restrict__ w_in,
                                              const float* __restrict__ w_out,
                                              const float* __restrict__ w_x,
                                              const float* __restrict__ w_dt,
                                              unsigned short* __restrict__ xn,
                                              unsigned* __restrict__ wib,
                                              unsigned* __restrict__ wob,
                                              unsigned* __restrict__ wxb,
                                              unsigned* __restrict__ wdtb) {
    __shared__ float red[4];
    int blk = blockIdx.x;
    if (blk < 2048) {  // RMSNorm row
        const float* xr = x + (size_t)blk * D_MODEL;
        int i = threadIdx.x * 4;
        float4 xv = *(const float4*)(xr + i);
        float s = xv.x * xv.x + xv.y * xv.y + xv.z * xv.z + xv.w * xv.w;
#pragma unroll
        for (int m = 1; m <= 32; m <<= 1) s += __shfl_xor(s, m);
        if ((threadIdx.x & 63) == 0) red[threadIdx.x >> 6] = s;
        __syncthreads();
        float tot = red[0] + red[1] + red[2] + red[3];
        float scale = rsqrtf(tot * (1.f / D_MODEL) + 1.1920929e-07f);
        float4 wv = *(const float4*)(norm_w + i);
        uint2 o;
        o.x = f2bf_u(xv.x * scale * wv.x) | (f2bf_u(xv.y * scale * wv.y) << 16);
        o.y = f2bf_u(xv.z * scale * wv.z) | (f2bf_u(xv.w * scale * wv.w) << 16);
        *(uint2*)(xn + (size_t)blk * D_MODEL + i) = o;
        return;
    }
    blk -= 2048;
    const float* src;
    unsigned* dst;
    int lidx;  // index in units of 8 elems
    if (blk < 2048) {
        src = w_in; dst = wib; lidx = blk * 256 + threadIdx.x;
    } else if (blk < 3072) {
        src = w_out; dst = wob; lidx = (blk - 2048) * 256 + threadIdx.x;
    } else if (blk < 3200) {
        dst = wxb; lidx = (blk - 3072) * 256 + threadIdx.x;
        if (lidx * 8 >= 96 * 2048) {  // pad rows 96..127 with zeros
            uint4 z = {0, 0, 0, 0};
            ((uint4*)dst)[lidx] = z;
            return;
        }
        src = w_x;
    } else {
        src = w_dt; dst = wdtb; lidx = (blk - 3200) * 256 + threadIdx.x;
    }
    float4 a = ((const float4*)src)[lidx * 2];
    float4 b = ((const float4*)src)[lidx * 2 + 1];
    uint4 o;
    o.x = f2bf_u(a.x) | (f2bf_u(a.y) << 16);
    o.y = f2bf_u(a.z) | (f2bf_u(a.w) << 16);
    o.z = f2bf_u(b.x) | (f2bf_u(b.y) << 16);
    o.w = f2bf_u(b.z) | (f2bf_u(b.w) << 16);
    ((uint4*)dst)[lidx] = o;
}

// ---------------- bf16 MFMA GEMM, BK=64: C(MxN) = A(MxK) * B(NxK)^T ----------------
// K must be a multiple of 64. BM=128 fixed.
// EPI: 0 = f32 out; 1 = softplus(v + res[col]) bf16 out; 2 = v + res[row*ldc+col] f32 out;
//      3 = bf16 out, silu applied when n0 >= D_INNER (in_proj fused z-gate prep).
template <int BN, int CW, int EPI>
__global__ __launch_bounds__(256) void gemm_bf16(const unsigned short* __restrict__ A,
                                                 const unsigned short* __restrict__ B,
                                                 void* __restrict__ Cv, int ldc, int K,
                                                 const float* __restrict__ res) {
    constexpr int RW = 4 / CW;
    constexpr int MI = (128 / RW) / 16;
    constexpr int NJ = (BN / CW) / 16;
    __shared__ __align__(16) unsigned short As[128 * 64];
    __shared__ __align__(16) unsigned short Bs[BN * 64];
    int tid = threadIdx.x;
    int lane = tid & 63, wv = tid >> 6;
    int wr = wv / CW, wc = wv % CW;
    int lm = lane & 15, q = lane >> 4;
    int m0 = blockIdx.x * 128, n0 = blockIdx.y * BN;
    f32x4 acc[MI][NJ] = {};
    for (int k0 = 0; k0 < K; k0 += 64) {
        // A tile: 128 rows x 64 cols bf16 = 1024 x 16B chunks; chunk = row*8 + kc
#pragma unroll
        for (int it = 0; it < 4; ++it) {
            int chunk = it * 256 + tid;
            const unsigned short* g = A + (size_t)(m0 + (chunk >> 3)) * K + k0 + (chunk & 7) * 8;
            char* l = (char*)As + (it * 256 + wv * 64) * 16 + lane * 16;
            gload_lds16(g, l);
        }
        // B tile: BN rows x 64 cols = BN*8 chunks
#pragma unroll
        for (int it = 0; it < BN / 32; ++it) {
            int chunk = it * 256 + tid;
            const unsigned short* g = B + (size_t)(n0 + (chunk >> 3)) * K + k0 + (chunk & 7) * 8;
            char* l = (char*)Bs + (it * 256 + wv * 64) * 16 + lane * 16;
            gload_lds16(g, l);
        }
        __syncthreads();
#pragma unroll
        for (int h = 0; h < 2; ++h) {
            bf16x8 af[MI], bfr[NJ];
#pragma unroll
            for (int i = 0; i < MI; ++i)
                af[i] = *(const bf16x8*)(As + (wr * MI * 16 + i * 16 + lm) * 64 + h * 32 + q * 8);
#pragma unroll
            for (int j = 0; j < NJ; ++j)
                bfr[j] = *(const bf16x8*)(Bs + (wc * NJ * 16 + j * 16 + lm) * 64 + h * 32 + q * 8);
#pragma unroll
            for (int i = 0; i < MI; ++i)
#pragma unroll
                for (int j = 0; j < NJ; ++j)
                    acc[i][j] = __builtin_amdgcn_mfma_f32_16x16x32_bf16(af[i], bfr[j], acc[i][j], 0, 0, 0);
        }
        __syncthreads();
    }
#pragma unroll
    for (int i = 0; i < MI; ++i) {
#pragma unroll
        for (int j = 0; j < NJ; ++j) {
#pragma unroll
            for (int r = 0; r < 4; ++r) {
                int row = m0 + wr * MI * 16 + i * 16 + q * 4 + r;
                int col = n0 + wc * NJ * 16 + j * 16 + lm;
                float v = acc[i][j][r];
                if (EPI == 1) {
                    v += res[col];
                    v = (v > 20.f) ? v : log1pf(__expf(v));
                    ((unsigned short*)Cv)[(size_t)row * ldc + col] = (unsigned short)f2bf_u(v);
                } else if (EPI == 2) {
                    v += res[(size_t)row * ldc + col];
                    ((float*)Cv)[(size_t)row * ldc + col] = v;
                } else if (EPI == 3) {
                    if (n0 >= D_INNER) v = v * sigmoidf_(v);  // fused silu(z)
                    ((unsigned short*)Cv)[(size_t)row * ldc + col] = (unsigned short)f2bf_u(v);
                } else {
                    ((float*)Cv)[(size_t)row * ldc + col] = v;
                }
            }
        }
    }
}

// ---------------- x_proj split-K MFMA GEMM (BK=64) -> bf16 partials ----------------
__global__ __launch_bounds__(256) void xproj_gemm(const unsigned short* __restrict__ A,
                                                  const unsigned short* __restrict__ B,
                                                  unsigned short* __restrict__ part) {
    constexpr int MI = 4, NJ = 4;
    __shared__ __align__(16) unsigned short As[128 * 64];
    __shared__ __align__(16) unsigned short Bs[128 * 64];
    int tid = threadIdx.x;
    int lane = tid & 63, wv = tid >> 6;
    int wr = wv >> 1, wc = wv & 1;
    int lm = lane & 15, q = lane >> 4;
    int m0 = blockIdx.x * 128;
    int kbase = blockIdx.y * (D_INNER / NSPLIT);
    f32x4 acc[MI][NJ] = {};
#pragma unroll
    for (int ki = 0; ki < (D_INNER / NSPLIT) / 64; ++ki) {
        int k0 = kbase + ki * 64;
#pragma unroll
        for (int it = 0; it < 4; ++it) {
            int chunk = it * 256 + tid;
            const unsigned short* g = A + (size_t)(m0 + (chunk >> 3)) * D_INNER + k0 + (chunk & 7) * 8;
            char* l = (char*)As + (it * 256 + wv * 64) * 16 + lane * 16;
            gload_lds16(g, l);
        }
#pragma unroll
        for (int it = 0; it < 4; ++it) {
            int chunk = it * 256 + tid;
            const unsigned short* g = B + (size_t)(chunk >> 3) * D_INNER + k0 + (chunk & 7) * 8;
            char* l = (char*)Bs + (it * 256 + wv * 64) * 16 + lane * 16;
            gload_lds16(g, l);
        }
        __syncthreads();
#pragma unroll
        for (int h = 0; h < 2; ++h) {
            bf16x8 af[MI], bfr[NJ];
#pragma unroll
            for (int i = 0; i < MI; ++i)
                af[i] = *(const bf16x8*)(As + (wr * 64 + i * 16 + lm) * 64 + h * 32 + q * 8);
#pragma unroll
            for (int j = 0; j < NJ; ++j)
                bfr[j] = *(const bf16x8*)(Bs + (wc * 64 + j * 16 + lm) * 64 + h * 32 + q * 8);
#pragma unroll
            for (int i = 0; i < MI; ++i)
#pragma unroll
                for (int j = 0; j < NJ; ++j)
                    acc[i][j] = __builtin_amdgcn_mfma_f32_16x16x32_bf16(af[i], bfr[j], acc[i][j], 0, 0, 0);
        }
        __syncthreads();
    }
    unsigned short* dst = part + (size_t)blockIdx.y * (NTOK * XPROJ_LD);
#pragma unroll
    for (int i = 0; i < MI; ++i)
#pragma unroll
        for (int j = 0; j < NJ; ++j)
#pragma unroll
            for (int r = 0; r < 4; ++r) {
                int row = m0 + wr * 64 + i * 16 + q * 4 + r;
                int col = wc * 64 + j * 16 + lm;
                dst[(size_t)row * XPROJ_LD + col] = (unsigned short)f2bf_u(acc[i][j][r]);
            }
}

// ---------------- reduce split-K partials; emit dbc f32 + dt_raw bf16 ----------------
__global__ __launch_bounds__(256) void k_xred(const unsigned short* __restrict__ part,
                                              float* __restrict__ dbc,
                                              unsigned short* __restrict__ dtrawb) {
    int idx = blockIdx.x * 256 + threadIdx.x;  // 0 .. 2048*128-1
    float s = 0.f;
#pragma unroll
    for (int sp = 0; sp < NSPLIT; ++sp) s += bf2f(part[(size_t)sp * (NTOK * XPROJ_LD) + idx]);
    dbc[idx] = s;
    int col = idx & (XPROJ_LD - 1);
    if (col < DT_RANK) {
        int row = idx >> 7;
        dtrawb[(size_t)row * DT_RANK + col] = (unsigned short)f2bf_u(s);
    }
}

// ---------------- depthwise causal conv (k=4, bf16 in) + SiLU -> ub ----------------
__global__ __launch_bounds__(256) void k_conv(const unsigned short* __restrict__ xz,
                                              const float* __restrict__ cw,
                                              const float* __restrict__ cb,
                                              unsigned short* __restrict__ ub) {
    int idx = blockIdx.x * 256 + threadIdx.x;
    int c = idx & (D_INNER - 1);
    int t = (idx >> 11) & (T_LEN - 1);
    int b = idx >> 21;
    const unsigned short* xs = xz + (size_t)b * T_LEN * 2 * D_INNER + c;
    float4 wv = *(const float4*)(cw + c * 4);
    float s = cb[c];
    if (t >= 3) s = fmaf(bf2f(xs[(size_t)(t - 3) * 2 * D_INNER]), wv.x, s);
    if (t >= 2) s = fmaf(bf2f(xs[(size_t)(t - 2) * 2 * D_INNER]), wv.y, s);
    if (t >= 1) s = fmaf(bf2f(xs[(size_t)(t - 1) * 2 * D_INNER]), wv.z, s);
    s = fmaf(bf2f(xs[(size_t)t * 2 * D_INNER]), wv.w, s);
    float v = s * sigmoidf_(s);
    ub[idx] = (unsigned short)f2bf_u(v);
}

// ---------------- chunked selective scan, lane-per-channel ----------------
// Pass 1: local scan from h=0; P = exp(A_s * sum(delta)).
__global__ __launch_bounds__(256) void k_scan1(const unsigned short* __restrict__ delta,
                                               const unsigned short* __restrict__ ub,
                                               const float* __restrict__ dbc,
                                               const float* __restrict__ A_log,
                                               float* __restrict__ Pbuf,
                                               float* __restrict__ Hbuf) {
    int tid = threadIdx.x;
    int c = blockIdx.x * 256 + tid;
    int b = blockIdx.y >> 5, chunk = blockIdx.y & 31;
    int t0 = chunk * CHUNK_L;
    __shared__ float bc[CHUNK_L][32];  // [t][0:16]=B, [t][16:32]=C
    {
        int t = tid >> 3, col = (tid & 7) * 4;
        const float* src = dbc + ((size_t)b * T_LEN + t0 + t) * XPROJ_LD + DT_RANK + col;
        *(float4*)&bc[t][col] = *(const float4*)src;
    }
    __syncthreads();
    float A[16];
#pragma unroll
    for (int s4 = 0; s4 < 4; ++s4) {
        float4 av = *(const float4*)(A_log + (size_t)c * D_STATE + s4 * 4);
        A[s4 * 4 + 0] = -__expf(av.x);
        A[s4 * 4 + 1] = -__expf(av.y);
        A[s4 * 4 + 2] = -__expf(av.z);
        A[s4 * 4 + 3] = -__expf(av.w);
    }
    const unsigned short* dp = delta + ((size_t)b * T_LEN + t0) * D_INNER + c;
    const unsigned short* up = ub + ((size_t)b * T_LEN + t0) * D_INNER + c;
    float h[16] = {};
    float sumd = 0.f;
#pragma unroll 4
    for (int t = 0; t < CHUNK_L; ++t) {
        float dv = bf2f(dp[(size_t)t * D_INNER]);
        float uv = bf2f(up[(size_t)t * D_INNER]);
        float du = dv * uv;
        sumd += dv;
#pragma unroll
        for (int s = 0; s < 16; ++s) {
            float da = __expf(dv * A[s]);
            h[s] = fmaf(da, h[s], du * bc[t][s]);
        }
    }
    size_t o = ((size_t)((b * NCHUNK + chunk) * D_INNER) + c) * 16;
#pragma unroll
    for (int s4 = 0; s4 < 4; ++s4) {
        float4 hv = {h[s4 * 4], h[s4 * 4 + 1], h[s4 * 4 + 2], h[s4 * 4 + 3]};
        *(float4*)(Hbuf + o + s4 * 4) = hv;
        float4 pv = {__expf(A[s4 * 4] * sumd), __expf(A[s4 * 4 + 1] * sumd),
                     __expf(A[s4 * 4 + 2] * sumd), __expf(A[s4 * 4 + 3] * sumd)};
        *(float4*)(Pbuf + o + s4 * 4) = pv;
    }
}

// Pass 2: register-pipelined chunk-summary scan; writes h_start to Sbuf.
__global__ __launch_bounds__(256) void k_scan2(const float* __restrict__ Pbuf,
                                               const float* __restrict__ Hbuf,
                                               float* __restrict__ Sbuf) {
    int idx = blockIdx.x * 256 + threadIdx.x;  // 0..65535 = (b, c*16+s)
    int b = idx >> 15, r = idx & 32767;
    size_t base = (size_t)b * NCHUNK * (D_INNER * 16) + r;
    float p[NCHUNK], hl[NCHUNK];
#pragma unroll
    for (int ch = 0; ch < NCHUNK; ++ch) {
        size_t o = base + (size_t)ch * (D_INNER * 16);
        p[ch] = Pbuf[o];
        hl[ch] = Hbuf[o];
    }
    float h = 0.f;
#pragma unroll
    for (int ch = 0; ch < NCHUNK; ++ch) {
        Sbuf[base + (size_t)ch * (D_INNER * 16)] = h;
        h = fmaf(p[ch], h, hl[ch]);
    }
}

// Pass 3: recurrence from exact h_start; fuse C-proj, D*u, pre-gated silu(z); emit bf16 y.
__global__ __launch_bounds__(256) void k_scan3(const unsigned short* __restrict__ delta,
                                               const unsigned short* __restrict__ ub,
                                               const float* __restrict__ dbc,
                                               const unsigned short* __restrict__ xz,  // z-half pre-silu'd
                                               const float* __restrict__ A_log,
                                               const float* __restrict__ Dp,
                                               const float* __restrict__ Sbuf,
                                               unsigned short* __restrict__ yb) {
    int tid = threadIdx.x;
    int c = blockIdx.x * 256 + tid;
    int b = blockIdx.y >> 5, chunk = blockIdx.y & 31;
    int t0 = chunk * CHUNK_L;
    __shared__ float bc[CHUNK_L][32];
    {
        int t = tid >> 3, col = (tid & 7) * 4;
        const float* src = dbc + ((size_t)b * T_LEN + t0 + t) * XPROJ_LD + DT_RANK + col;
        *(float4*)&bc[t][col] = *(const float4*)src;
    }
    __syncthreads();
    float A[16];
#pragma unroll
    for (int s4 = 0; s4 < 4; ++s4) {
        float4 av = *(const float4*)(A_log + (size_t)c * D_STATE + s4 * 4);
        A[s4 * 4 + 0] = -__expf(av.x);
        A[s4 * 4 + 1] = -__expf(av.y);
        A[s4 * 4 + 2] = -__expf(av.z);
        A[s4 * 4 + 3] = -__expf(av.w);
    }
    float Dc = Dp[c];
    float h[16];
    size_t ho = ((size_t)((b * NCHUNK + chunk) * D_INNER) + c) * 16;
#pragma unroll
    for (int s4 = 0; s4 < 4; ++s4) {
        float4 hv = *(const float4*)(Sbuf + ho + s4 * 4);
        h[s4 * 4] = hv.x; h[s4 * 4 + 1] = hv.y; h[s4 * 4 + 2] = hv.z; h[s4 * 4 + 3] = hv.w;
    }
    const unsigned short* dp = delta + ((size_t)b * T_LEN + t0) * D_INNER + c;
    const unsigned short* up = ub + ((size_t)b * T_LEN + t0) * D_INNER + c;
    const unsigned short* zp = xz + ((size_t)b * T_LEN + t0) * 2 * D_INNER + D_INNER + c;
    unsigned short* yp = yb + ((size_t)b * T_LEN + t0) * D_INNER + c;
#pragma unroll 2
    for (int t = 0; t < CHUNK_L; ++t) {
        float dv = bf2f(dp[(size_t)t * D_INNER]);
        float uv = bf2f(up[(size_t)t * D_INNER]);
        float sz = bf2f(zp[(size_t)t * 2 * D_INNER]);  // already silu(z)
        float du = dv * uv;
        float y = Dc * uv;
#pragma unroll
        for (int s = 0; s < 16; ++s) {
            float da = __expf(dv * A[s]);
            h[s] = fmaf(da, h[s], du * bc[t][s]);
            y = fmaf(h[s], bc[t][16 + s], y);
        }
        yp[(size_t)t * D_INNER] = (unsigned short)f2bf_u(y * sz);
    }
}

extern "C" void kernel_launch(void* const* d_in, const int* in_sizes, int n_in,
                              void* d_out, int out_size, void* d_ws, size_t ws_size,
                              hipStream_t stream) {
    const float* x         = (const float*)d_in[0];
    const float* norm_w    = (const float*)d_in[1];
    const float* in_proj_w = (const float*)d_in[2];
    const float* conv_w    = (const float*)d_in[3];
    const float* conv_b    = (const float*)d_in[4];
    const float* x_proj_w  = (const float*)d_in[5];
    const float* dt_proj_w = (const float*)d_in[6];
    const float* dt_proj_b = (const float*)d_in[7];
    const float* A_log     = (const float*)d_in[8];
    const float* D_param   = (const float*)d_in[9];
    const float* out_proj_w= (const float*)d_in[10];
    float* out = (float*)d_out;

    // workspace layout (float units), flat; total 23,592,960 floats = 94.4 MB
    float* ws = (float*)d_ws;
    unsigned short* xzb    = (unsigned short*)(ws);            // 2048*4096 bf16 (z-half silu'd)
    unsigned short* ub     = (unsigned short*)(ws + 4194304);  // 2048*2048 bf16
    unsigned short* yb     = (unsigned short*)(ws + 6291456);  // 2048*2048 bf16
    unsigned short* partb  = (unsigned short*)(ws + 8388608);  // 16*2048*128 bf16
    float*          dbc    = ws + 10485760;                    // 2048*128 f32
    unsigned short* deltab = (unsigned short*)(ws + 10747904); // 2048*2048 bf16
    float*          Pbuf   = ws + 12845056;                    // 2*32*2048*16 f32
    float*          Hbuf   = ws + 14942208;                    // 2*32*2048*16 f32
    float*          Sbuf   = ws + 17039360;                    // 2*32*2048*16 f32
    unsigned short* wib    = (unsigned short*)(ws + 19136512); // 4096*1024 bf16
    unsigned short* wob    = (unsigned short*)(ws + 21233664); // 1024*2048 bf16
    unsigned short* wxb    = (unsigned short*)(ws + 22282240); // 128*2048 bf16
    unsigned short* wdtb   = (unsigned short*)(ws + 22413312); // 2048*64 bf16
    unsigned short* dtrawb = (unsigned short*)(ws + 22478848); // 2048*64 bf16
    unsigned short* xnb    = (unsigned short*)(ws + 22544384); // 2048*1024 bf16

    // 0. fused RMSNorm + all weight casts (one launch)
    k_prep<<<5312, 256, 0, stream>>>(x, norm_w, in_proj_w, out_proj_w, x_proj_w, dt_proj_w,
                                     xnb, (unsigned*)wib, (unsigned*)wob, (unsigned*)wxb,
                                     (unsigned*)wdtb);
    // 1. xz = xn @ in_proj_w^T (2048x4096x1024) -> bf16; z-half fused silu
    gemm_bf16<128, 2, 3><<<dim3(NTOK / 128, 4096 / 128), 256, 0, stream>>>(
        xnb, wib, xzb, 2 * D_INNER, D_MODEL, nullptr);
    // 2. depthwise conv + SiLU -> ub
    k_conv<<<(NTOK * D_INNER) / 256, 256, 0, stream>>>(xzb, conv_w, conv_b, ub);
    // 3. x_dbc: split-K MFMA GEMM (bf16 partials) + reduce
    xproj_gemm<<<dim3(NTOK / 128, NSPLIT), 256, 0, stream>>>(ub, wxb, partb);
    k_xred<<<(NTOK * XPROJ_LD) / 256, 256, 0, stream>>>(partb, dbc, dtrawb);
    // 4. delta = softplus(dt_raw @ dt_proj_w^T + b) -> bf16 (2048x2048x64, single K-stage)
    gemm_bf16<128, 2, 1><<<dim3(NTOK / 128, D_INNER / 128), 256, 0, stream>>>(
        dtrawb, wdtb, deltab, D_INNER, DT_RANK, dt_proj_b);
    // 5. chunked selective scan -> yb (bf16)
    k_scan1<<<dim3(D_INNER / 256, B_SZ * NCHUNK), 256, 0, stream>>>(deltab, ub, dbc, A_log,
                                                                    Pbuf, Hbuf);
    k_scan2<<<(B_SZ * D_INNER * D_STATE) / 256, 256, 0, stream>>>(Pbuf, Hbuf, Sbuf);
    k_scan3<<<dim3(D_INNER / 256, B_SZ * NCHUNK), 256, 0, stream>>>(deltab, ub, dbc, xzb, A_log,
                                                                    D_param, Sbuf, yb);
    // 6. out = y @ out_proj_w^T + x (2048x1024x2048), f32 out + residual
    gemm_bf16<64, 1, 2><<<dim3(NTOK / 128, 1024 / 64), 256, 0, stream>>>(
        yb, wob, out, D_MODEL, D_INNER, x);

    (void)in_sizes; (void)n_in; (void)out_size; (void)ws_size;
}

// Round 9
// 257.788 us; speedup vs baseline: 5.0326x; 1.0448x over previous
//
#include <hip/hip_runtime.h>
#include <math.h>

#define B_SZ 2
#define T_LEN 1024
#define D_MODEL 1024
#define D_STATE 16
#define D_INNER 2048
#define DT_RANK 64
#define NTOK (B_SZ * T_LEN)               // 2048 tokens
#define XPROJ_OUT 96
#define XPROJ_LD 128                      // padded leading dim for dbc
#define NCHUNK 32
#define CHUNK_L (T_LEN / NCHUNK)          // 32
#define NSPLIT 32                         // split-K for x_proj (K-slab 64)

typedef __attribute__((ext_vector_type(8))) short bf16x8;
typedef __attribute__((ext_vector_type(4))) float f32x4;

__device__ __forceinline__ float sigmoidf_(float x) { return 1.f / (1.f + __expf(-x)); }

__device__ __forceinline__ unsigned f2bf_u(float f) {  // RNE f32->bf16 bits
    unsigned u = __float_as_uint(f);
    return (u + 0x7FFFu + ((u >> 16) & 1u)) >> 16;
}
__device__ __forceinline__ float bf2f(unsigned short u) {
    return __uint_as_float((unsigned)u << 16);
}

__device__ __forceinline__ void gload_lds16(const void* g, void* l) {
    __builtin_amdgcn_global_load_lds((const __attribute__((address_space(1))) unsigned*)g,
                                     (__attribute__((address_space(3))) unsigned*)l,
                                     16, 0, 0);
}

// ---------------- fused prep: RMSNorm + all weight casts, one launch ----------------
__global__ __launch_bounds__(256) void k_prep(const float* __restrict__ x,
                                              const float* __restrict__ norm_w,
                                              const float* __restrict__ w_in,
                                              const float* __restrict__ w_out,
                                              const float* __restrict__ w_x,
                                              const float* __restrict__ w_dt,
                                              unsigned short* __restrict__ xn,
                                              unsigned* __restrict__ wib,
                                              unsigned* __restrict__ wob,
                                              unsigned* __restrict__ wxb,
                                              unsigned* __restrict__ wdtb) {
    __shared__ float red[4];
    int blk = blockIdx.x;
    if (blk < 2048) {  // RMSNorm row
        const float* xr = x + (size_t)blk * D_MODEL;
        int i = threadIdx.x * 4;
        float4 xv = *(const float4*)(xr + i);
        float s = xv.x * xv.x + xv.y * xv.y + xv.z * xv.z + xv.w * xv.w;
#pragma unroll
        for (int m = 1; m <= 32; m <<= 1) s += __shfl_xor(s, m);
        if ((threadIdx.x & 63) == 0) red[threadIdx.x >> 6] = s;
        __syncthreads();
        float tot = red[0] + red[1] + red[2] + red[3];
        float scale = rsqrtf(tot * (1.f / D_MODEL) + 1.1920929e-07f);
        float4 wv = *(const float4*)(norm_w + i);
        uint2 o;
        o.x = f2bf_u(xv.x * scale * wv.x) | (f2bf_u(xv.y * scale * wv.y) << 16);
        o.y = f2bf_u(xv.z * scale * wv.z) | (f2bf_u(xv.w * scale * wv.w) << 16);
        *(uint2*)(xn + (size_t)blk * D_MODEL + i) = o;
        return;
    }
    blk -= 2048;
    const float* src;
    unsigned* dst;
    int lidx;  // index in units of 8 elems
    if (blk < 2048) {
        src = w_in; dst = wib; lidx = blk * 256 + threadIdx.x;
    } else if (blk < 3072) {
        src = w_out; dst = wob; lidx = (blk - 2048) * 256 + threadIdx.x;
    } else if (blk < 3200) {
        dst = wxb; lidx = (blk - 3072) * 256 + threadIdx.x;
        if (lidx * 8 >= 96 * 2048) {  // pad rows 96..127 with zeros
            uint4 z = {0, 0, 0, 0};
            ((uint4*)dst)[lidx] = z;
            return;
        }
        src = w_x;
    } else {
        src = w_dt; dst = wdtb; lidx = (blk - 3200) * 256 + threadIdx.x;
    }
    float4 a = ((const float4*)src)[lidx * 2];
    float4 b = ((const float4*)src)[lidx * 2 + 1];
    uint4 o;
    o.x = f2bf_u(a.x) | (f2bf_u(a.y) << 16);
    o.y = f2bf_u(a.z) | (f2bf_u(a.w) << 16);
    o.z = f2bf_u(b.x) | (f2bf_u(b.y) << 16);
    o.w = f2bf_u(b.z) | (f2bf_u(b.w) << 16);
    ((uint4*)dst)[lidx] = o;
}

// ---------------- bf16 MFMA GEMM, BM=128, BK=64: C = A(MxK) * B(NxK)^T ----------------
// EPI: 1 = softplus(v + res[col]) bf16 out; 3 = bf16 out, silu when n0 >= D_INNER.
template <int BN, int CW, int EPI>
__global__ __launch_bounds__(256) void gemm_bf16(const unsigned short* __restrict__ A,
                                                 const unsigned short* __restrict__ B,
                                                 void* __restrict__ Cv, int ldc, int K,
                                                 const float* __restrict__ res) {
    constexpr int RW = 4 / CW;
    constexpr int MI = (128 / RW) / 16;
    constexpr int NJ = (BN / CW) / 16;
    __shared__ __align__(16) unsigned short As[128 * 64];
    __shared__ __align__(16) unsigned short Bs[BN * 64];
    int tid = threadIdx.x;
    int lane = tid & 63, wv = tid >> 6;
    int wr = wv / CW, wc = wv % CW;
    int lm = lane & 15, q = lane >> 4;
    int m0 = blockIdx.x * 128, n0 = blockIdx.y * BN;
    f32x4 acc[MI][NJ] = {};
    for (int k0 = 0; k0 < K; k0 += 64) {
#pragma unroll
        for (int it = 0; it < 4; ++it) {
            int chunk = it * 256 + tid;
            const unsigned short* g = A + (size_t)(m0 + (chunk >> 3)) * K + k0 + (chunk & 7) * 8;
            char* l = (char*)As + (it * 256 + wv * 64) * 16 + lane * 16;
            gload_lds16(g, l);
        }
#pragma unroll
        for (int it = 0; it < BN / 32; ++it) {
            int chunk = it * 256 + tid;
            const unsigned short* g = B + (size_t)(n0 + (chunk >> 3)) * K + k0 + (chunk & 7) * 8;
            char* l = (char*)Bs + (it * 256 + wv * 64) * 16 + lane * 16;
            gload_lds16(g, l);
        }
        __syncthreads();
#pragma unroll
        for (int h = 0; h < 2; ++h) {
            bf16x8 af[MI], bfr[NJ];
#pragma unroll
            for (int i = 0; i < MI; ++i)
                af[i] = *(const bf16x8*)(As + (wr * MI * 16 + i * 16 + lm) * 64 + h * 32 + q * 8);
#pragma unroll
            for (int j = 0; j < NJ; ++j)
                bfr[j] = *(const bf16x8*)(Bs + (wc * NJ * 16 + j * 16 + lm) * 64 + h * 32 + q * 8);
#pragma unroll
            for (int i = 0; i < MI; ++i)
#pragma unroll
                for (int j = 0; j < NJ; ++j)
                    acc[i][j] = __builtin_amdgcn_mfma_f32_16x16x32_bf16(af[i], bfr[j], acc[i][j], 0, 0, 0);
        }
        __syncthreads();
    }
#pragma unroll
    for (int i = 0; i < MI; ++i) {
#pragma unroll
        for (int j = 0; j < NJ; ++j) {
#pragma unroll
            for (int r = 0; r < 4; ++r) {
                int row = m0 + wr * MI * 16 + i * 16 + q * 4 + r;
                int col = n0 + wc * NJ * 16 + j * 16 + lm;
                float v = acc[i][j][r];
                if (EPI == 1) {
                    v += res[col];
                    v = (v > 20.f) ? v : log1pf(__expf(v));
                    ((unsigned short*)Cv)[(size_t)row * ldc + col] = (unsigned short)f2bf_u(v);
                } else {  // EPI == 3
                    if (n0 >= D_INNER) v = v * sigmoidf_(v);  // fused silu(z)
                    ((unsigned short*)Cv)[(size_t)row * ldc + col] = (unsigned short)f2bf_u(v);
                }
            }
        }
    }
}

// ---------------- 64x64-tile bf16 MFMA GEMM (out_proj): C = A*B^T + res, f32 out ----------------
// 4 waves in 2x2; wave tile 32x32 (MI=NJ=2). grid (M/64, N/64).
__global__ __launch_bounds__(256) void gemm_sq64(const unsigned short* __restrict__ A,
                                                 const unsigned short* __restrict__ B,
                                                 float* __restrict__ C, int ldc, int K,
                                                 const float* __restrict__ res) {
    __shared__ __align__(16) unsigned short As[64 * 64];
    __shared__ __align__(16) unsigned short Bs[64 * 64];
    int tid = threadIdx.x;
    int lane = tid & 63, wv = tid >> 6;
    int wr = wv >> 1, wc = wv & 1;
    int lm = lane & 15, q = lane >> 4;
    int m0 = blockIdx.x * 64, n0 = blockIdx.y * 64;
    f32x4 acc[2][2] = {};
    for (int k0 = 0; k0 < K; k0 += 64) {
#pragma unroll
        for (int it = 0; it < 2; ++it) {
            int chunk = it * 256 + tid;
            const unsigned short* g = A + (size_t)(m0 + (chunk >> 3)) * K + k0 + (chunk & 7) * 8;
            char* l = (char*)As + (it * 256 + wv * 64) * 16 + lane * 16;
            gload_lds16(g, l);
        }
#pragma unroll
        for (int it = 0; it < 2; ++it) {
            int chunk = it * 256 + tid;
            const unsigned short* g = B + (size_t)(n0 + (chunk >> 3)) * K + k0 + (chunk & 7) * 8;
            char* l = (char*)Bs + (it * 256 + wv * 64) * 16 + lane * 16;
            gload_lds16(g, l);
        }
        __syncthreads();
#pragma unroll
        for (int h = 0; h < 2; ++h) {
            bf16x8 af[2], bfr[2];
#pragma unroll
            for (int i = 0; i < 2; ++i)
                af[i] = *(const bf16x8*)(As + (wr * 32 + i * 16 + lm) * 64 + h * 32 + q * 8);
#pragma unroll
            for (int j = 0; j < 2; ++j)
                bfr[j] = *(const bf16x8*)(Bs + (wc * 32 + j * 16 + lm) * 64 + h * 32 + q * 8);
#pragma unroll
            for (int i = 0; i < 2; ++i)
#pragma unroll
                for (int j = 0; j < 2; ++j)
                    acc[i][j] = __builtin_amdgcn_mfma_f32_16x16x32_bf16(af[i], bfr[j], acc[i][j], 0, 0, 0);
        }
        __syncthreads();
    }
#pragma unroll
    for (int i = 0; i < 2; ++i)
#pragma unroll
        for (int j = 0; j < 2; ++j)
#pragma unroll
            for (int r = 0; r < 4; ++r) {
                int row = m0 + wr * 32 + i * 16 + q * 4 + r;
                int col = n0 + wc * 32 + j * 16 + lm;
                C[(size_t)row * ldc + col] = acc[i][j][r] + res[(size_t)row * ldc + col];
            }
}

// ---------------- x_proj split-K MFMA GEMM (K-slab 64, single stage) -> bf16 partials ----------------
__global__ __launch_bounds__(256) void xproj_gemm(const unsigned short* __restrict__ A,
                                                  const unsigned short* __restrict__ B,
                                                  unsigned short* __restrict__ part) {
    constexpr int MI = 4, NJ = 4;
    __shared__ __align__(16) unsigned short As[128 * 64];
    __shared__ __align__(16) unsigned short Bs[128 * 64];
    int tid = threadIdx.x;
    int lane = tid & 63, wv = tid >> 6;
    int wr = wv >> 1, wc = wv & 1;
    int lm = lane & 15, q = lane >> 4;
    int m0 = blockIdx.x * 128;
    int k0 = blockIdx.y * 64;
    f32x4 acc[MI][NJ] = {};
#pragma unroll
    for (int it = 0; it < 4; ++it) {
        int chunk = it * 256 + tid;
        const unsigned short* g = A + (size_t)(m0 + (chunk >> 3)) * D_INNER + k0 + (chunk & 7) * 8;
        char* l = (char*)As + (it * 256 + wv * 64) * 16 + lane * 16;
        gload_lds16(g, l);
    }
#pragma unroll
    for (int it = 0; it < 4; ++it) {
        int chunk = it * 256 + tid;
        const unsigned short* g = B + (size_t)(chunk >> 3) * D_INNER + k0 + (chunk & 7) * 8;
        char* l = (char*)Bs + (it * 256 + wv * 64) * 16 + lane * 16;
        gload_lds16(g, l);
    }
    __syncthreads();
#pragma unroll
    for (int h = 0; h < 2; ++h) {
        bf16x8 af[MI], bfr[NJ];
#pragma unroll
        for (int i = 0; i < MI; ++i)
            af[i] = *(const bf16x8*)(As + (wr * 64 + i * 16 + lm) * 64 + h * 32 + q * 8);
#pragma unroll
        for (int j = 0; j < NJ; ++j)
            bfr[j] = *(const bf16x8*)(Bs + (wc * 64 + j * 16 + lm) * 64 + h * 32 + q * 8);
#pragma unroll
        for (int i = 0; i < MI; ++i)
#pragma unroll
            for (int j = 0; j < NJ; ++j)
                acc[i][j] = __builtin_amdgcn_mfma_f32_16x16x32_bf16(af[i], bfr[j], acc[i][j], 0, 0, 0);
    }
    unsigned short* dst = part + (size_t)blockIdx.y * (NTOK * XPROJ_LD);
#pragma unroll
    for (int i = 0; i < MI; ++i)
#pragma unroll
        for (int j = 0; j < NJ; ++j)
#pragma unroll
            for (int r = 0; r < 4; ++r) {
                int row = m0 + wr * 64 + i * 16 + q * 4 + r;
                int col = wc * 64 + j * 16 + lm;
                dst[(size_t)row * XPROJ_LD + col] = (unsigned short)f2bf_u(acc[i][j][r]);
            }
}

// ---------------- reduce split-K partials; emit dbc f32 + dt_raw bf16 ----------------
__global__ __launch_bounds__(256) void k_xred(const unsigned short* __restrict__ part,
                                              float* __restrict__ dbc,
                                              unsigned short* __restrict__ dtrawb) {
    int idx = blockIdx.x * 256 + threadIdx.x;  // 0 .. 2048*128-1
    float s = 0.f;
#pragma unroll
    for (int sp = 0; sp < NSPLIT; ++sp) s += bf2f(part[(size_t)sp * (NTOK * XPROJ_LD) + idx]);
    dbc[idx] = s;
    int col = idx & (XPROJ_LD - 1);
    if (col < DT_RANK) {
        int row = idx >> 7;
        dtrawb[(size_t)row * DT_RANK + col] = (unsigned short)f2bf_u(s);
    }
}

// ---------------- depthwise causal conv (k=4, bf16 in) + SiLU -> ub ----------------
__global__ __launch_bounds__(256) void k_conv(const unsigned short* __restrict__ xz,
                                              const float* __restrict__ cw,
                                              const float* __restrict__ cb,
                                              unsigned short* __restrict__ ub) {
    int idx = blockIdx.x * 256 + threadIdx.x;
    int c = idx & (D_INNER - 1);
    int t = (idx >> 11) & (T_LEN - 1);
    int b = idx >> 21;
    const unsigned short* xs = xz + (size_t)b * T_LEN * 2 * D_INNER + c;
    float4 wv = *(const float4*)(cw + c * 4);
    float s = cb[c];
    if (t >= 3) s = fmaf(bf2f(xs[(size_t)(t - 3) * 2 * D_INNER]), wv.x, s);
    if (t >= 2) s = fmaf(bf2f(xs[(size_t)(t - 2) * 2 * D_INNER]), wv.y, s);
    if (t >= 1) s = fmaf(bf2f(xs[(size_t)(t - 1) * 2 * D_INNER]), wv.z, s);
    s = fmaf(bf2f(xs[(size_t)t * 2 * D_INNER]), wv.w, s);
    float v = s * sigmoidf_(s);
    ub[idx] = (unsigned short)f2bf_u(v);
}

// ---------------- chunked selective scan, lane-per-channel ----------------
__global__ __launch_bounds__(256) void k_scan1(const unsigned short* __restrict__ delta,
                                               const unsigned short* __restrict__ ub,
                                               const float* __restrict__ dbc,
                                               const float* __restrict__ A_log,
                                               float* __restrict__ Pbuf,
                                               float* __restrict__ Hbuf) {
    int tid = threadIdx.x;
    int c = blockIdx.x * 256 + tid;
    int b = blockIdx.y >> 5, chunk = blockIdx.y & 31;
    int t0 = chunk * CHUNK_L;
    __shared__ float bc[CHUNK_L][32];  // [t][0:16]=B, [t][16:32]=C
    {
        int t = tid >> 3, col = (tid & 7) * 4;
        const float* src = dbc + ((size_t)b * T_LEN + t0 + t) * XPROJ_LD + DT_RANK + col;
        *(float4*)&bc[t][col] = *(const float4*)src;
    }
    __syncthreads();
    float A[16];
#pragma unroll
    for (int s4 = 0; s4 < 4; ++s4) {
        float4 av = *(const float4*)(A_log + (size_t)c * D_STATE + s4 * 4);
        A[s4 * 4 + 0] = -__expf(av.x);
        A[s4 * 4 + 1] = -__expf(av.y);
        A[s4 * 4 + 2] = -__expf(av.z);
        A[s4 * 4 + 3] = -__expf(av.w);
    }
    const unsigned short* dp = delta + ((size_t)b * T_LEN + t0) * D_INNER + c;
    const unsigned short* up = ub + ((size_t)b * T_LEN + t0) * D_INNER + c;
    float h[16] = {};
    float sumd = 0.f;
#pragma unroll 4
    for (int t = 0; t < CHUNK_L; ++t) {
        float dv = bf2f(dp[(size_t)t * D_INNER]);
        float uv = bf2f(up[(size_t)t * D_INNER]);
        float du = dv * uv;
        sumd += dv;
#pragma unroll
        for (int s = 0; s < 16; ++s) {
            float da = __expf(dv * A[s]);
            h[s] = fmaf(da, h[s], du * bc[t][s]);
        }
    }
    size_t o = ((size_t)((b * NCHUNK + chunk) * D_INNER) + c) * 16;
#pragma unroll
    for (int s4 = 0; s4 < 4; ++s4) {
        float4 hv = {h[s4 * 4], h[s4 * 4 + 1], h[s4 * 4 + 2], h[s4 * 4 + 3]};
        *(float4*)(Hbuf + o + s4 * 4) = hv;
        float4 pv = {__expf(A[s4 * 4] * sumd), __expf(A[s4 * 4 + 1] * sumd),
                     __expf(A[s4 * 4 + 2] * sumd), __expf(A[s4 * 4 + 3] * sumd)};
        *(float4*)(Pbuf + o + s4 * 4) = pv;
    }
}

__global__ __launch_bounds__(256) void k_scan2(const float* __restrict__ Pbuf,
                                               const float* __restrict__ Hbuf,
                                               float* __restrict__ Sbuf) {
    int idx = blockIdx.x * 256 + threadIdx.x;  // 0..65535 = (b, c*16+s)
    int b = idx >> 15, r = idx & 32767;
    size_t base = (size_t)b * NCHUNK * (D_INNER * 16) + r;
    float p[NCHUNK], hl[NCHUNK];
#pragma unroll
    for (int ch = 0; ch < NCHUNK; ++ch) {
        size_t o = base + (size_t)ch * (D_INNER * 16);
        p[ch] = Pbuf[o];
        hl[ch] = Hbuf[o];
    }
    float h = 0.f;
#pragma unroll
    for (int ch = 0; ch < NCHUNK; ++ch) {
        Sbuf[base + (size_t)ch * (D_INNER * 16)] = h;
        h = fmaf(p[ch], h, hl[ch]);
    }
}

__global__ __launch_bounds__(256) void k_scan3(const unsigned short* __restrict__ delta,
                                               const unsigned short* __restrict__ ub,
                                               const float* __restrict__ dbc,
                                               const unsigned short* __restrict__ xz,  // z-half pre-silu'd
                                               const float* __restrict__ A_log,
                                               const float* __restrict__ Dp,
                                               const float* __restrict__ Sbuf,
                                               unsigned short* __restrict__ yb) {
    int tid = threadIdx.x;
    int c = blockIdx.x * 256 + tid;
    int b = blockIdx.y >> 5, chunk = blockIdx.y & 31;
    int t0 = chunk * CHUNK_L;
    __shared__ float bc[CHUNK_L][32];
    {
        int t = tid >> 3, col = (tid & 7) * 4;
        const float* src = dbc + ((size_t)b * T_LEN + t0 + t) * XPROJ_LD + DT_RANK + col;
        *(float4*)&bc[t][col] = *(const float4*)src;
    }
    __syncthreads();
    float A[16];
#pragma unroll
    for (int s4 = 0; s4 < 4; ++s4) {
        float4 av = *(const float4*)(A_log + (size_t)c * D_STATE + s4 * 4);
        A[s4 * 4 + 0] = -__expf(av.x);
        A[s4 * 4 + 1] = -__expf(av.y);
        A[s4 * 4 + 2] = -__expf(av.z);
        A[s4 * 4 + 3] = -__expf(av.w);
    }
    float Dc = Dp[c];
    float h[16];
    size_t ho = ((size_t)((b * NCHUNK + chunk) * D_INNER) + c) * 16;
#pragma unroll
    for (int s4 = 0; s4 < 4; ++s4) {
        float4 hv = *(const float4*)(Sbuf + ho + s4 * 4);
        h[s4 * 4] = hv.x; h[s4 * 4 + 1] = hv.y; h[s4 * 4 + 2] = hv.z; h[s4 * 4 + 3] = hv.w;
    }
    const unsigned short* dp = delta + ((size_t)b * T_LEN + t0) * D_INNER + c;
    const unsigned short* up = ub + ((size_t)b * T_LEN + t0) * D_INNER + c;
    const unsigned short* zp = xz + ((size_t)b * T_LEN + t0) * 2 * D_INNER + D_INNER + c;
    unsigned short* yp = yb + ((size_t)b * T_LEN + t0) * D_INNER + c;
#pragma unroll 2
    for (int t = 0; t < CHUNK_L; ++t) {
        float dv = bf2f(dp[(size_t)t * D_INNER]);
        float uv = bf2f(up[(size_t)t * D_INNER]);
        float sz = bf2f(zp[(size_t)t * 2 * D_INNER]);  // already silu(z)
        float du = dv * uv;
        float y = Dc * uv;
#pragma unroll
        for (int s = 0; s < 16; ++s) {
            float da = __expf(dv * A[s]);
            h[s] = fmaf(da, h[s], du * bc[t][s]);
            y = fmaf(h[s], bc[t][16 + s], y);
        }
        yp[(size_t)t * D_INNER] = (unsigned short)f2bf_u(y * sz);
    }
}

extern "C" void kernel_launch(void* const* d_in, const int* in_sizes, int n_in,
                              void* d_out, int out_size, void* d_ws, size_t ws_size,
                              hipStream_t stream) {
    const float* x         = (const float*)d_in[0];
    const float* norm_w    = (const float*)d_in[1];
    const float* in_proj_w = (const float*)d_in[2];
    const float* conv_w    = (const float*)d_in[3];
    const float* conv_b    = (const float*)d_in[4];
    const float* x_proj_w  = (const float*)d_in[5];
    const float* dt_proj_w = (const float*)d_in[6];
    const float* dt_proj_b = (const float*)d_in[7];
    const float* A_log     = (const float*)d_in[8];
    const float* D_param   = (const float*)d_in[9];
    const float* out_proj_w= (const float*)d_in[10];
    float* out = (float*)d_out;

    // workspace layout (float units), flat; total 25,690,112 floats = 102.8 MB
    float* ws = (float*)d_ws;
    unsigned short* xzb    = (unsigned short*)(ws);            // 2048*4096 bf16 (z-half silu'd)
    unsigned short* ub     = (unsigned short*)(ws + 4194304);  // 2048*2048 bf16
    unsigned short* yb     = (unsigned short*)(ws + 6291456);  // 2048*2048 bf16
    unsigned short* partb  = (unsigned short*)(ws + 8388608);  // 32*2048*128 bf16
    float*          dbc    = ws + 12582912;                    // 2048*128 f32
    unsigned short* deltab = (unsigned short*)(ws + 12845056); // 2048*2048 bf16
    float*          Pbuf   = ws + 14942208;                    // 2*32*2048*16 f32
    float*          Hbuf   = ws + 17039360;                    // 2*32*2048*16 f32
    float*          Sbuf   = ws + 19136512;                    // 2*32*2048*16 f32
    unsigned short* wib    = (unsigned short*)(ws + 21233664); // 4096*1024 bf16
    unsigned short* wob    = (unsigned short*)(ws + 23330816); // 1024*2048 bf16
    unsigned short* wxb    = (unsigned short*)(ws + 24379392); // 128*2048 bf16
    unsigned short* wdtb   = (unsigned short*)(ws + 24510464); // 2048*64 bf16
    unsigned short* dtrawb = (unsigned short*)(ws + 24576000); // 2048*64 bf16
    unsigned short* xnb    = (unsigned short*)(ws + 24641536); // 2048*1024 bf16

    // 0. fused RMSNorm + all weight casts (one launch)
    k_prep<<<5312, 256, 0, stream>>>(x, norm_w, in_proj_w, out_proj_w, x_proj_w, dt_proj_w,
                                     xnb, (unsigned*)wib, (unsigned*)wob, (unsigned*)wxb,
                                     (unsigned*)wdtb);
    // 1. xz = xn @ in_proj_w^T (2048x4096x1024) -> bf16; z-half fused silu (512 blocks, 2/CU)
    gemm_bf16<128, 2, 3><<<dim3(NTOK / 128, 4096 / 128), 256, 0, stream>>>(
        xnb, wib, xzb, 2 * D_INNER, D_MODEL, nullptr);
    // 2. depthwise conv + SiLU -> ub
    k_conv<<<(NTOK * D_INNER) / 256, 256, 0, stream>>>(xzb, conv_w, conv_b, ub);
    // 3. x_dbc: split-K MFMA GEMM (32 slabs of K=64, 512 blocks) + reduce
    xproj_gemm<<<dim3(NTOK / 128, NSPLIT), 256, 0, stream>>>(ub, wxb, partb);
    k_xred<<<(NTOK * XPROJ_LD) / 256, 256, 0, stream>>>(partb, dbc, dtrawb);
    // 4. delta = softplus(dt_raw @ dt_proj_w^T + b) -> bf16 (BN=64: 512 blocks, 2/CU)
    gemm_bf16<64, 1, 1><<<dim3(NTOK / 128, D_INNER / 64), 256, 0, stream>>>(
        dtrawb, wdtb, deltab, D_INNER, DT_RANK, dt_proj_b);
    // 5. chunked selective scan -> yb (bf16)
    k_scan1<<<dim3(D_INNER / 256, B_SZ * NCHUNK), 256, 0, stream>>>(deltab, ub, dbc, A_log,
                                                                    Pbuf, Hbuf);
    k_scan2<<<(B_SZ * D_INNER * D_STATE) / 256, 256, 0, stream>>>(Pbuf, Hbuf, Sbuf);
    k_scan3<<<dim3(D_INNER / 256, B_SZ * NCHUNK), 256, 0, stream>>>(deltab, ub, dbc, xzb, A_log,
                                                                    D_param, Sbuf, yb);
    // 6. out = y @ out_proj_w^T + x (2048x1024x2048), 64x64 tiles (512 blocks, 2/CU)
    gemm_sq64<<<dim3(NTOK / 64, D_MODEL / 64), 256, 0, stream>>>(
        yb, wob, out, D_MODEL, D_INNER, x);

    (void)in_sizes; (void)n_in; (void)out_size; (void)ws_size;
}